// Round 8
// baseline (1057.872 us; speedup 1.0000x reference)
//
#include <hip/hip_runtime.h>
#include <math.h>

#define L_SEQ 4096
#define BATCH 32
#define DM 128

typedef short short8 __attribute__((ext_vector_type(8)));
typedef float f32x4 __attribute__((ext_vector_type(4)));

__device__ __forceinline__ float gelu_f(float x) {
    return 0.5f * x * (1.0f + erff(x * 0.70710678118654752f));
}
__device__ __forceinline__ float gelu_fast(float x) {
    float ax = fabsf(x);
    if (ax < 1.0f) {
        float z = x * 0.70710678118654752f;
        float z2 = z * z;
        float p = 1.0f + z2 * (-0.333333333f + z2 * (0.1f + z2 * (-0.0238095238f +
                  z2 * (4.62962963e-3f + z2 * (-7.57575758e-4f)))));
        return 0.5f * x * (1.0f + 1.1283791670955126f * z * p);
    }
    return 0.5f * x * (1.0f + erff(x * 0.70710678118654752f));
}
__device__ __forceinline__ unsigned short f2b(float f) {
    unsigned u = __float_as_uint(f);
    u += 0x7fffu + ((u >> 16) & 1u);
    return (unsigned short)(u >> 16);
}
__device__ __forceinline__ float b2f(unsigned short h) {
    return __uint_as_float(((unsigned)h) << 16);
}

// ---------------- conv1d embedding: LDS-staged, weight-in-register ----------------
__global__ __launch_bounds__(256) void kembed(const float* __restrict__ x,
                                              const float* __restrict__ w,
                                              float* __restrict__ h) {
    __shared__ float xs[130][12];
    __shared__ float wsm[128][37];
    int b = blockIdx.x >> 5;
    int lt = blockIdx.x & 31;
    int l0 = lt * 128;
    int tid = threadIdx.x;
    for (int i = tid; i < 130 * 12; i += 256) {
        int r = i / 12, c = i - r * 12;
        int gl = (l0 - 1 + r + 4096) & 4095;
        xs[r][c] = x[((size_t)b * 4096 + gl) * 12 + c];
    }
    for (int i = tid; i < 128 * 36; i += 256) {
        int o = i / 36, j = i - o * 36;
        wsm[o][j] = w[i];
    }
    __syncthreads();
    int o = tid & 127, lh = tid >> 7;
    float wr[36];
#pragma unroll
    for (int j = 0; j < 36; j++) wr[j] = wsm[o][j];
    int base_r = lh * 64;
    float ring[4][12];
#pragma unroll
    for (int c = 0; c < 12; c++) { ring[0][c] = xs[base_r][c]; ring[1][c] = xs[base_r + 1][c]; }
    float* hp = h + ((size_t)b * 4096 + l0 + lh * 64) * 128 + o;
#pragma unroll 4
    for (int st = 0; st < 64; st++) {
        int s0 = st & 3, s1 = (st + 1) & 3, s2 = (st + 2) & 3;
#pragma unroll
        for (int c = 0; c < 12; c++) ring[s2][c] = xs[base_r + st + 2][c];
        float s = 0.f;
#pragma unroll
        for (int c = 0; c < 12; c++)
            s += wr[c * 3 + 0] * ring[s0][c] + wr[c * 3 + 1] * ring[s1][c] + wr[c * 3 + 2] * ring[s2][c];
        hp[(size_t)st * 128] = s;
    }
}

// ---------------- weight prep: bf16 pre-swizzled images ----------------
__global__ __launch_bounds__(256) void kprepw(const float* __restrict__ w1,
                                              const float* __restrict__ w2,
                                              const float* __restrict__ attn_w,
                                              unsigned short* __restrict__ w1img,
                                              unsigned short* __restrict__ w2img,
                                              unsigned short* __restrict__ qkh,
                                              unsigned short* __restrict__ qkl,
                                              unsigned short* __restrict__ voimg) {
    int t = blockIdx.x * 256 + threadIdx.x;
    if (t < 262144) {
        int layer = t >> 17; int rem = t & 131071;
        if (rem < 65536) {
            int R = rem >> 7, x = rem & 127;
            int g = x >> 3, j = x & 7;
            int srcc = ((g ^ (R & 7)) << 3) + j;
            w1img[(size_t)layer * 65536 + rem] = f2b(w1[(size_t)layer * 65536 + R * 128 + srcc]);
        } else {
            int r2 = rem - 65536;
            int c = r2 >> 13; int D = (r2 >> 6) & 127; int x = r2 & 63;
            int g = x >> 3, j = x & 7;
            int srcf = c * 64 + ((g ^ (D & 7)) << 3) + j;
            w2img[(size_t)layer * 65536 + r2] = f2b(w2[(size_t)layer * 65536 + D * 512 + srcf]);
        }
    } else if (t < 327680) {
        int t2 = t - 262144;
        int layer = t2 >> 15; int rem = t2 & 32767;
        int y = rem >> 14; int rem2 = rem & 16383;
        int r64 = rem2 >> 7; int x = rem2 & 127;
        int r = r64 & 63;
        int g = x >> 3, j = x & 7;
        int srcc = ((g ^ (r & 7)) << 3) + j;
        float v = attn_w[(size_t)layer * 65536 + y * 16384 + r64 * 128 + srcc];
        unsigned short hh = f2b(v);
        qkh[t2] = hh;
        qkl[t2] = f2b(v - b2f(hh));
    } else {
        int t3 = t - 327680;
        int layer = t3 >> 15; int rem = t3 & 32767;
        int mat = rem >> 14; int rem2 = rem & 16383;
        int r = rem2 >> 7; int x = rem2 & 127;
        int g = x >> 3, j = x & 7;
        int srcc = ((g ^ (r & 7)) << 3) + j;
        voimg[t3] = f2b(attn_w[(size_t)layer * 65536 + (2 + mat) * 16384 + r * 128 + srcc]);
    }
}

// ---- q/k projection, bf16x3 MFMA, W from pre-split images, transposed epilogue ----
__global__ __launch_bounds__(256, 2) void kgemm_qk3(const float* __restrict__ A,
                                                    const unsigned short* __restrict__ qkh,
                                                    const unsigned short* __restrict__ qkl,
                                                    const float* __restrict__ ab,
                                                    int half, float* __restrict__ CT) {
    __shared__ __align__(16) char smem[65536];
    short* Ah = (short*)smem;
    short* Al = (short*)(smem + 16384);
    short* Wh = (short*)(smem + 32768);
    short* Wl = (short*)(smem + 49152);
    int y = blockIdx.y;
    const unsigned short* wh = qkh + y * 16384 + half * 8192;
    const unsigned short* wl = qkl + y * 16384 + half * 8192;
    const float* bias = ab + y * 128 + half * 64;
    int row0 = blockIdx.x * 64;
    int tid = threadIdx.x;
#pragma unroll
    for (int u = 0; u < 4; u++) {
        int task = tid + u * 256;
        int r = task >> 4, cg = task & 15;
        int dst = r * 128 + ((cg ^ (r & 7)) << 3);
        const float* src = A + ((size_t)(row0 + r)) * 128 + cg * 8;
        float4 xa = *(const float4*)src, ya = *(const float4*)(src + 4);
        float av[8] = {xa.x, xa.y, xa.z, xa.w, ya.x, ya.y, ya.z, ya.w};
        short8 hi, lo;
#pragma unroll
        for (int j = 0; j < 8; j++) {
            unsigned short h = f2b(av[j]);
            hi[j] = (short)h; lo[j] = (short)f2b(av[j] - b2f(h));
        }
        *(short8*)(Ah + dst) = hi; *(short8*)(Al + dst) = lo;
        int lin = r * 128 + cg * 8;
        *(short8*)(Wh + lin) = *(const short8*)(wh + lin);
        *(short8*)(Wl + lin) = *(const short8*)(wl + lin);
    }
    __syncthreads();
    int l = tid & 63; int w = tid >> 6; int wm = w >> 1, wn = w & 1;
    f32x4 acc[2][2];
#pragma unroll
    for (int i = 0; i < 2; i++)
#pragma unroll
        for (int j = 0; j < 2; j++) acc[i][j] = (f32x4){0.f, 0.f, 0.f, 0.f};
#pragma unroll
    for (int ks = 0; ks < 4; ks++) {
        int cg = ks * 4 + (l >> 4);
        short8 ah[2], al2[2], bh[2], bl[2];
#pragma unroll
        for (int mi = 0; mi < 2; mi++) {
            int rm = wm * 32 + mi * 16 + (l & 15);
            int off = rm * 128 + ((cg ^ (rm & 7)) << 3);
            ah[mi] = *(short8*)(Ah + off); al2[mi] = *(short8*)(Al + off);
        }
#pragma unroll
        for (int ni = 0; ni < 2; ni++) {
            int rn = wn * 32 + ni * 16 + (l & 15);
            int off = rn * 128 + ((cg ^ (rn & 7)) << 3);
            bh[ni] = *(short8*)(Wh + off); bl[ni] = *(short8*)(Wl + off);
        }
#pragma unroll
        for (int mi = 0; mi < 2; mi++)
#pragma unroll
            for (int ni = 0; ni < 2; ni++) {
                acc[mi][ni] = __builtin_amdgcn_mfma_f32_16x16x32_bf16(ah[mi], bh[ni], acc[mi][ni], 0, 0, 0);
                acc[mi][ni] = __builtin_amdgcn_mfma_f32_16x16x32_bf16(ah[mi], bl[ni], acc[mi][ni], 0, 0, 0);
                acc[mi][ni] = __builtin_amdgcn_mfma_f32_16x16x32_bf16(al2[mi], bh[ni], acc[mi][ni], 0, 0, 0);
            }
    }
    __syncthreads();
    float* Dsh = (float*)smem;
#pragma unroll
    for (int mi = 0; mi < 2; mi++)
#pragma unroll
        for (int ni = 0; ni < 2; ni++)
#pragma unroll
            for (int rr = 0; rr < 4; rr++) {
                int m = wm * 32 + mi * 16 + (l >> 4) * 4 + rr;
                int n = wn * 32 + ni * 16 + (l & 15);
                Dsh[n * 68 + m] = acc[mi][ni][rr] + bias[n];
            }
    __syncthreads();
    int b = row0 >> 12; int l0 = row0 & 4095;
    int cbase = y * 64;
#pragma unroll
    for (int u = 0; u < 4; u++) {
        int task = tid + u * 256;
        int c = task >> 4, m4 = (task & 15) * 4;
        float4 v = *(float4*)&Dsh[c * 68 + m4];
        *(float4*)&CT[((size_t)(b * 128 + cbase + c)) * 4096 + l0 + m4] = v;
    }
}

// ---------------- MFMA bf16 GEMM (v-proj / fused agg+o-proj), W from image ----------------
template <int AT, int EPI>
__global__ __launch_bounds__(256, 2) void kgemm_mfma(const void* __restrict__ Ap,
                                                     const unsigned short* __restrict__ Wimg,
                                                     const float* __restrict__ bias,
                                                     const float* __restrict__ res,
                                                     const float* __restrict__ tcb,
                                                     const int* __restrict__ idxb,
                                                     void* __restrict__ outp) {
    __shared__ __align__(16) char smem[65536];
    short* As = (short*)smem;
    short* Ws = (short*)(smem + 32768);
    int tid = threadIdx.x;
    size_t row0 = (size_t)blockIdx.x * 128;
#pragma unroll
    for (int u = 0; u < 8; u++) {
        int g = tid + u * 256;
        int r = g >> 4, cg = g & 15;
        int dsti = r * 128 + ((cg ^ (r & 7)) << 3);
        short8 v;
        if (AT == 0) {
            const float* src = (const float*)Ap + (row0 + r) * 128 + cg * 8;
            float4 x = *(const float4*)src, y = *(const float4*)(src + 4);
            v[0] = f2b(x.x); v[1] = f2b(x.y); v[2] = f2b(x.z); v[3] = f2b(x.w);
            v[4] = f2b(y.x); v[5] = f2b(y.y); v[6] = f2b(y.z); v[7] = f2b(y.w);
        } else {
            const unsigned short* Vb = (const unsigned short*)Ap;
            int b = (int)(row0 >> 12);
            int l0 = (int)(row0 & 4095);
            float accv[8];
#pragma unroll
            for (int j = 0; j < 8; j++) accv[j] = 0.f;
#pragma unroll
            for (int i = 0; i < 8; i++) {
                float wgt = tcb[b * 8 + i];
                int lr = (l0 + r + idxb[i]) & 4095;
                short8 vv = *(const short8*)(Vb + ((size_t)(b * 4096 + lr)) * 128 + cg * 8);
#pragma unroll
                for (int j = 0; j < 8; j++) accv[j] += wgt * b2f((unsigned short)vv[j]);
            }
#pragma unroll
            for (int j = 0; j < 8; j++) v[j] = (short)f2b(accv[j]);
        }
        *(short8*)(As + dsti) = v;
        int lin = r * 128 + cg * 8;
        *(short8*)(Ws + lin) = *(const short8*)(Wimg + lin);
    }
    __syncthreads();
    int l = tid & 63; int w = tid >> 6; int wm = w >> 1, wn = w & 1;
    f32x4 acc[4][4];
#pragma unroll
    for (int i = 0; i < 4; i++)
#pragma unroll
        for (int j = 0; j < 4; j++) acc[i][j] = (f32x4){0.f, 0.f, 0.f, 0.f};
#pragma unroll
    for (int ks = 0; ks < 4; ks++) {
        int cg = ks * 4 + (l >> 4);
        short8 af[4], bf[4];
#pragma unroll
        for (int mi = 0; mi < 4; mi++) {
            int rm = wm * 64 + mi * 16 + (l & 15);
            af[mi] = *(short8*)(As + rm * 128 + ((cg ^ (rm & 7)) << 3));
        }
#pragma unroll
        for (int ni = 0; ni < 4; ni++) {
            int rn = wn * 64 + ni * 16 + (l & 15);
            bf[ni] = *(short8*)(Ws + rn * 128 + ((cg ^ (rn & 7)) << 3));
        }
#pragma unroll
        for (int mi = 0; mi < 4; mi++)
#pragma unroll
            for (int ni = 0; ni < 4; ni++)
                acc[mi][ni] = __builtin_amdgcn_mfma_f32_16x16x32_bf16(af[mi], bf[ni], acc[mi][ni], 0, 0, 0);
    }
    __syncthreads();
    float* Dsh = (float*)smem;
#pragma unroll
    for (int mi = 0; mi < 4; mi++)
#pragma unroll
        for (int ni = 0; ni < 4; ni++)
#pragma unroll
            for (int rr = 0; rr < 4; rr++)
                Dsh[(wm * 64 + mi * 16 + (l >> 4) * 4 + rr) * 128 + wn * 64 + ni * 16 + (l & 15)] = acc[mi][ni][rr];
    __syncthreads();
#pragma unroll
    for (int u = 0; u < 8; u++) {
        int g = tid + u * 256;
        int r = g >> 4, c8 = (g & 15) * 8;
        float vv[8];
#pragma unroll
        for (int j = 0; j < 8; j++) vv[j] = Dsh[r * 128 + c8 + j] + bias[c8 + j];
        if (EPI == 1) {
            const float* rp = res + (row0 + r) * 128 + c8;
#pragma unroll
            for (int j = 0; j < 8; j++) vv[j] += rp[j];
            float* op = (float*)outp + (row0 + r) * 128 + c8;
            *(float4*)op = make_float4(vv[0], vv[1], vv[2], vv[3]);
            *(float4*)(op + 4) = make_float4(vv[4], vv[5], vv[6], vv[7]);
        } else {
            short8 ov;
#pragma unroll
            for (int j = 0; j < 8; j++) ov[j] = (short)f2b(vv[j]);
            *(short8*)((short*)outp + (row0 + r) * 128 + c8) = ov;
        }
    }
}

// ---------------- fused MFMA FFN (proven): 80 KB LDS, fb=64 chunks ----------------
__global__ __launch_bounds__(256, 2) void kffn_mfma(const float* __restrict__ xs,
                                                    const unsigned short* __restrict__ w1img,
                                                    const unsigned short* __restrict__ w2img,
                                                    float* __restrict__ outp) {
    __shared__ __align__(16) char smem[81920];
    short* xsl = (short*)smem;               // [128][128]  32K
    short* w1t = (short*)(smem + 32768);     // [64][128]   16K
    short* tt  = (short*)(smem + 49152);     // [128][64]   16K
    short* w2t = (short*)(smem + 65536);     // [128][64]   16K
    int tid = threadIdx.x;
    size_t row0 = (size_t)blockIdx.x * 128;
#pragma unroll
    for (int u = 0; u < 8; u++) {
        int g = tid + u * 256;
        int r = g >> 4, cg = g & 15;
        const float* src = xs + (row0 + r) * 128 + cg * 8;
        float4 x = *(const float4*)src, y = *(const float4*)(src + 4);
        short8 v;
        v[0] = f2b(x.x); v[1] = f2b(x.y); v[2] = f2b(x.z); v[3] = f2b(x.w);
        v[4] = f2b(y.x); v[5] = f2b(y.y); v[6] = f2b(y.z); v[7] = f2b(y.w);
        *(short8*)(xsl + r * 128 + ((cg ^ (r & 7)) << 3)) = v;
    }
    int l = tid & 63; int w = tid >> 6; int wm = w >> 1, wn = w & 1;
    f32x4 acc2[4][4];
#pragma unroll
    for (int i = 0; i < 4; i++)
#pragma unroll
        for (int j = 0; j < 4; j++) acc2[i][j] = (f32x4){0.f, 0.f, 0.f, 0.f};
    for (int fb = 0; fb < 8; fb++) {
        __syncthreads();                       // BAR_A
#pragma unroll
        for (int u = 0; u < 4; u++) {
            int task = tid + u * 256;
            int r = task >> 4, cg = task & 15;
            *(short8*)(w1t + r * 128 + cg * 8) =
                *(const short8*)(w1img + ((size_t)(fb * 64 + r)) * 128 + cg * 8);
            int r2 = task >> 3, cg2 = task & 7;
            *(short8*)(w2t + r2 * 64 + cg2 * 8) =
                *(const short8*)(w2img + ((size_t)(fb * 128 + r2)) * 64 + cg2 * 8);
        }
        __syncthreads();                       // BAR_B
        f32x4 a1[4][2];
#pragma unroll
        for (int i = 0; i < 4; i++)
#pragma unroll
            for (int j = 0; j < 2; j++) a1[i][j] = (f32x4){0.f, 0.f, 0.f, 0.f};
#pragma unroll
        for (int ks = 0; ks < 4; ks++) {
            int cg = ks * 4 + (l >> 4);
            short8 af[4], bf[2];
#pragma unroll
            for (int mi = 0; mi < 4; mi++) {
                int rm = wm * 64 + mi * 16 + (l & 15);
                af[mi] = *(short8*)(xsl + rm * 128 + ((cg ^ (rm & 7)) << 3));
            }
#pragma unroll
            for (int ni = 0; ni < 2; ni++) {
                int rn = wn * 32 + ni * 16 + (l & 15);
                bf[ni] = *(short8*)(w1t + rn * 128 + ((cg ^ (rn & 7)) << 3));
            }
#pragma unroll
            for (int mi = 0; mi < 4; mi++)
#pragma unroll
                for (int ni = 0; ni < 2; ni++)
                    a1[mi][ni] = __builtin_amdgcn_mfma_f32_16x16x32_bf16(af[mi], bf[ni], a1[mi][ni], 0, 0, 0);
        }
#pragma unroll
        for (int mi = 0; mi < 4; mi++)
#pragma unroll
            for (int ni = 0; ni < 2; ni++)
#pragma unroll
                for (int rr = 0; rr < 4; rr++) {
                    int m = wm * 64 + mi * 16 + (l >> 4) * 4 + rr;
                    int f = wn * 32 + ni * 16 + (l & 15);
                    tt[m * 64 + (((f >> 3) ^ (m & 7)) << 3) + (f & 7)] = (short)f2b(gelu_fast(a1[mi][ni][rr]));
                }
        __syncthreads();                       // BAR_C
#pragma unroll
        for (int ks = 0; ks < 2; ks++) {
            int cg = ks * 4 + (l >> 4);
            short8 af[4], bf[4];
#pragma unroll
            for (int mi = 0; mi < 4; mi++) {
                int rm = wm * 64 + mi * 16 + (l & 15);
                af[mi] = *(short8*)(tt + rm * 64 + ((cg ^ (rm & 7)) << 3));
            }
#pragma unroll
            for (int ni = 0; ni < 4; ni++) {
                int rn = wn * 64 + ni * 16 + (l & 15);
                bf[ni] = *(short8*)(w2t + rn * 64 + ((cg ^ (rn & 7)) << 3));
            }
#pragma unroll
            for (int mi = 0; mi < 4; mi++)
#pragma unroll
                for (int ni = 0; ni < 4; ni++)
                    acc2[mi][ni] = __builtin_amdgcn_mfma_f32_16x16x32_bf16(af[mi], bf[ni], acc2[mi][ni], 0, 0, 0);
        }
    }
    __syncthreads();
    float* Dsh = (float*)smem;
#pragma unroll
    for (int mi = 0; mi < 4; mi++)
#pragma unroll
        for (int ni = 0; ni < 4; ni++)
#pragma unroll
            for (int rr = 0; rr < 4; rr++)
                Dsh[(wm * 64 + mi * 16 + (l >> 4) * 4 + rr) * 128 + wn * 64 + ni * 16 + (l & 15)] = acc2[mi][ni][rr];
    __syncthreads();
#pragma unroll
    for (int u = 0; u < 8; u++) {
        int g = tid + u * 256;
        int r = g >> 4, c8 = (g & 15) * 8;
        const float* rp = xs + (row0 + r) * 128 + c8;
        float* op = outp + (row0 + r) * 128 + c8;
        float4 o0, o1;
        o0.x = Dsh[r * 128 + c8 + 0] + rp[0]; o0.y = Dsh[r * 128 + c8 + 1] + rp[1];
        o0.z = Dsh[r * 128 + c8 + 2] + rp[2]; o0.w = Dsh[r * 128 + c8 + 3] + rp[3];
        o1.x = Dsh[r * 128 + c8 + 4] + rp[4]; o1.y = Dsh[r * 128 + c8 + 5] + rp[5];
        o1.z = Dsh[r * 128 + c8 + 6] + rp[6]; o1.w = Dsh[r * 128 + c8 + 7] + rp[7];
        *(float4*)op = o0; *(float4*)(op + 4) = o1;
    }
}

// ---------------- radix-4 Stockham FFT-4096, 1024 threads ----------------
#define FIDX(a) ((a) + ((a) >> 4))

__device__ __forceinline__ float2 twget(const float2* __restrict__ tw, int a, float sgn) {
    float2 T = tw[a & 1023];
    int hi = (a >> 10) & 3;
    float cs = (hi & 1) ? ((hi & 2) ? T.y : -T.y) : ((hi & 2) ? -T.x : T.x);
    float sn = (hi & 1) ? ((hi & 2) ? -T.x : T.x) : ((hi & 2) ? -T.y : T.y);
    return make_float2(cs, sn * sgn);
}

__device__ void fft4096_r4(float2* __restrict__ b0, float2* __restrict__ b1,
                           const float2* __restrict__ tw, float sgn, int tid) {
    float2* cur = b0; float2* nxt = b1;
#pragma unroll
    for (int t = 0; t < 6; t++) {
        int s = 1 << (t << 1);
        int q = tid & (s - 1);
        int ps = tid - q;
        float2 a0 = cur[FIDX(tid)];
        float2 a1 = cur[FIDX(tid + 1024)];
        float2 a2 = cur[FIDX(tid + 2048)];
        float2 a3 = cur[FIDX(tid + 3072)];
        float t0x = a0.x + a2.x, t0y = a0.y + a2.y;
        float t1x = a0.x - a2.x, t1y = a0.y - a2.y;
        float t2x = a1.x + a3.x, t2y = a1.y + a3.y;
        float t3x = a1.x - a3.x, t3y = a1.y - a3.y;
        float it3x = -sgn * t3y, it3y = sgn * t3x;
        float2 A0 = make_float2(t0x + t2x, t0y + t2y);
        float2 A1 = make_float2(t1x + it3x, t1y + it3y);
        float2 A2 = make_float2(t0x - t2x, t0y - t2y);
        float2 A3 = make_float2(t1x - it3x, t1y - it3y);
        int ob = q + (ps << 2);
        nxt[FIDX(ob)] = A0;
        float2 w1 = twget(tw, ps, sgn);
        float2 w2 = twget(tw, ps * 2, sgn);
        float2 w3 = twget(tw, ps * 3, sgn);
        nxt[FIDX(ob + s)] = make_float2(A1.x * w1.x - A1.y * w1.y, A1.x * w1.y + A1.y * w1.x);
        nxt[FIDX(ob + 2 * s)] = make_float2(A2.x * w2.x - A2.y * w2.y, A2.x * w2.y + A2.y * w2.x);
        nxt[FIDX(ob + 3 * s)] = make_float2(A3.x * w3.x - A3.y * w3.y, A3.x * w3.y + A3.y * w3.x);
        __syncthreads();
        float2* tp = cur; cur = nxt; nxt = tp;
    }
}

// 4 channels/block, grid 512 (b x 16 groups) -> 2 blocks/CU; half 1 accumulates into P.
__global__ __launch_bounds__(1024) void kfft_fwd(const float* __restrict__ qkT,
                                                 float* __restrict__ Pws, int ghalf) {
    __shared__ float2 bufA[4352];
    __shared__ float2 bufB[4352];
    __shared__ float2 tw[1024];
    int tid = threadIdx.x;
    {
        float sn, cs;
        sincosf(1.5339807878856412e-3f * (float)tid, &sn, &cs);
        tw[tid] = make_float2(cs, sn);
    }
    int b = blockIdx.x >> 4;
    int g = blockIdx.x & 15;
    float2 pacc[4];
#pragma unroll
    for (int j = 0; j < 4; j++) pacc[j] = make_float2(0.f, 0.f);
    for (int c4 = 0; c4 < 4; c4++) {
        int c = g * 4 + c4;
        const float* qrow = qkT + ((size_t)(b * 128 + c)) * 4096;
        const float* krow = qkT + ((size_t)(b * 128 + 64 + c)) * 4096;
        __syncthreads();
        int i0 = tid * 4;
        float4 qv = *(const float4*)(qrow + i0);
        float4 kv = *(const float4*)(krow + i0);
        bufA[FIDX(i0)]     = make_float2(qv.x, kv.x);
        bufA[FIDX(i0 + 1)] = make_float2(qv.y, kv.y);
        bufA[FIDX(i0 + 2)] = make_float2(qv.z, kv.z);
        bufA[FIDX(i0 + 3)] = make_float2(qv.w, kv.w);
        __syncthreads();
        fft4096_r4(bufA, bufB, tw, -1.f, tid);
#pragma unroll
        for (int j = 0; j < 4; j++) {
            int f = tid + j * 1024;
            float2 Zf = bufA[FIDX(f)];
            float2 Zm = bufA[FIDX((4096 - f) & 4095)];
            float Qre = 0.5f * (Zf.x + Zm.x), Qim = 0.5f * (Zf.y - Zm.y);
            float Kre = 0.5f * (Zf.y + Zm.y), Kim = -0.5f * (Zf.x - Zm.x);
            pacc[j].x += Qre * Kre + Qim * Kim;
            pacc[j].y += Qim * Kre - Qre * Kim;
        }
    }
    float2* P = (float2*)Pws + (size_t)(b * 16 + g) * 4096;
    if (ghalf == 0) {
#pragma unroll
        for (int j = 0; j < 4; j++) { int f = tid + j * 1024; P[f] = pacc[j]; }
    } else {
#pragma unroll
        for (int j = 0; j < 4; j++) {
            int f = tid + j * 1024;
            float2 r = P[f];
            P[f] = make_float2(r.x + pacc[j].x, r.y + pacc[j].y);
        }
    }
}

__global__ __launch_bounds__(1024) void kfft_inv(const float* __restrict__ Pws,
                                                 float* __restrict__ meanv) {
    __shared__ float2 bufA[4352];
    __shared__ float2 bufB[4352];
    __shared__ float2 tw[1024];
    int tid = threadIdx.x;
    {
        float sn, cs;
        sincosf(1.5339807878856412e-3f * (float)tid, &sn, &cs);
        tw[tid] = make_float2(cs, sn);
    }
    int b = blockIdx.x;
    const float2* P = (const float2*)Pws + (size_t)b * 16 * 4096;
#pragma unroll
    for (int j = 0; j < 4; j++) {
        int i = tid + j * 1024;
        float2 s = make_float2(0.f, 0.f);
#pragma unroll
        for (int gg = 0; gg < 16; gg++) { float2 v = P[gg * 4096 + i]; s.x += v.x; s.y += v.y; }
        bufA[FIDX(i)] = s;
    }
    __syncthreads();
    fft4096_r4(bufA, bufB, tw, 1.f, tid);
    const float scale = 1.0f / (4096.0f * 128.0f);
#pragma unroll
    for (int j = 0; j < 4; j++) {
        int i = tid + j * 1024;
        meanv[b * 4096 + i] = bufA[FIDX(i)].x * scale;
    }
}

// ---------------- parallel column sum over batches (b ascending, bit-identical) ----------------
__global__ __launch_bounds__(256) void kcolsum(const float* __restrict__ meanv,
                                               float* __restrict__ cmg) {
    int c = blockIdx.x * 256 + threadIdx.x;
    float s = 0.f;
    for (int b = 0; b < 32; b++) s += meanv[b * 4096 + c];
    cmg[c] = s;
}

// ---------------- top-8 on presummed vector + per-batch softmax ----------------
__global__ __launch_bounds__(256) void ktopk2(const float* __restrict__ cmg,
                                              const float* __restrict__ meanv,
                                              int* __restrict__ idxout,
                                              float* __restrict__ tc) {
    __shared__ float cm[4096];
    __shared__ float rv[256];
    __shared__ int ri[256];
    __shared__ int sidx[8];
    for (int c = threadIdx.x; c < 4096; c += 256) cm[c] = cmg[c];
    __syncthreads();
    for (int it = 0; it < 8; it++) {
        float bv = -1e30f; int bi = 0;
        for (int c = threadIdx.x; c < 4096; c += 256) {
            float v = cm[c];
            if (v > bv) { bv = v; bi = c; }
        }
        rv[threadIdx.x] = bv; ri[threadIdx.x] = bi;
        __syncthreads();
        for (int off = 128; off > 0; off >>= 1) {
            if (threadIdx.x < off) {
                float v2 = rv[threadIdx.x + off]; int i2 = ri[threadIdx.x + off];
                if (v2 > rv[threadIdx.x] || (v2 == rv[threadIdx.x] && i2 < ri[threadIdx.x])) {
                    rv[threadIdx.x] = v2; ri[threadIdx.x] = i2;
                }
            }
            __syncthreads();
        }
        if (threadIdx.x == 0) { sidx[it] = ri[0]; idxout[it] = ri[0]; cm[ri[0]] = -1e30f; }
        __syncthreads();
    }
    if (threadIdx.x < 32) {
        int b = threadIdx.x;
        float w[8]; float mx = -1e30f;
#pragma unroll
        for (int i = 0; i < 8; i++) { w[i] = meanv[b * 4096 + sidx[i]]; mx = fmaxf(mx, w[i]); }
        float s = 0.f;
#pragma unroll
        for (int i = 0; i < 8; i++) { w[i] = expf(w[i] - mx); s += w[i]; }
#pragma unroll
        for (int i = 0; i < 8; i++) tc[b * 8 + i] = w[i] / s;
    }
}

// ---------------- series decomp: float4 rolling windows ----------------
__global__ __launch_bounds__(256) void kdecomp(const float* __restrict__ in,
                                               float* __restrict__ outp) {
    int b = blockIdx.x >> 4; int lc = blockIdx.x & 15;
    int dg = threadIdx.x & 31; int ls = threadIdx.x >> 5;
    int l0 = lc * 256 + ls * 32;
    const float* base = in + (size_t)b * 524288 + dg * 4;
    float* ob = outp + (size_t)b * 524288 + dg * 4;
    float sx = 0.f, sy = 0.f, sz = 0.f, sw = 0.f;
#pragma unroll
    for (int j = -12; j <= 12; j++) {
        int lj = l0 + j;
        lj = lj < 0 ? 0 : (lj > 4095 ? 4095 : lj);
        float4 v = *(const float4*)(base + (size_t)lj * 128);
        sx += v.x; sy += v.y; sz += v.z; sw += v.w;
    }
    for (int st = 0; st < 32; st++) {
        int l = l0 + st;
        float4 c = *(const float4*)(base + (size_t)l * 128);
        float4 o = make_float4(c.x - sx * (1.0f / 25.0f), c.y - sy * (1.0f / 25.0f),
                               c.z - sz * (1.0f / 25.0f), c.w - sw * (1.0f / 25.0f));
        *(float4*)(ob + (size_t)l * 128) = o;
        int ln = l + 13 > 4095 ? 4095 : l + 13;
        int lo2 = l - 12 < 0 ? 0 : l - 12;
        float4 vn = *(const float4*)(base + (size_t)ln * 128);
        float4 vo = *(const float4*)(base + (size_t)lo2 * 128);
        sx += vn.x - vo.x; sy += vn.y - vo.y; sz += vn.z - vo.z; sw += vn.w - vo.w;
    }
}

// ---------------- fused LayerNorm + column partial sums ----------------
__global__ __launch_bounds__(256) void kln_part1(float* __restrict__ h,
                                                 const float* __restrict__ g,
                                                 const float* __restrict__ bb,
                                                 float* __restrict__ part) {
    __shared__ float sh[4][128];
    int b = blockIdx.x >> 5;
    int sl = blockIdx.x & 31;
    int w = threadIdx.x >> 6;
    int lane = threadIdx.x & 63;
    float2 gv = *(const float2*)(g + lane * 2);
    float2 bv = *(const float2*)(bb + lane * 2);
    size_t r0 = (size_t)b * 4096 + sl * 128 + w * 32;
    float c0 = 0.f, c1 = 0.f;
    for (int i = 0; i < 32; i++) {
        float* p = h + (r0 + i) * 128 + lane * 2;
        float2 v = *(float2*)p;
        float s = v.x + v.y, s2 = v.x * v.x + v.y * v.y;
#pragma unroll
        for (int off = 32; off; off >>= 1) { s += __shfl_down(s, off); s2 += __shfl_down(s2, off); }
        s = __shfl(s, 0); s2 = __shfl(s2, 0);
        float mu = s * (1.f / 128.f);
        float var = s2 * (1.f / 128.f) - mu * mu;
        float inv = rsqrtf(var + 1e-5f);
        float o0 = (v.x - mu) * inv * gv.x + bv.x;
        float o1 = (v.y - mu) * inv * gv.y + bv.y;
        *(float2*)p = make_float2(o0, o1);
        c0 += o0; c1 += o1;
    }
    sh[w][lane * 2] = c0; sh[w][lane * 2 + 1] = c1;
    __syncthreads();
    if (threadIdx.x < 128) {
        int d = threadIdx.x;
        part[(size_t)(b * 32 + sl) * 128 + d] = sh[0][d] + sh[1][d] + sh[2][d] + sh[3][d];
    }
}

__global__ __launch_bounds__(128) void kpart2(const float* __restrict__ part,
                                              float* __restrict__ outm, int nq) {
    int b = blockIdx.x; int d = threadIdx.x;
    float s = 0.f;
    for (int q = 0; q < nq; q++) s += part[(size_t)(b * nq + q) * 128 + d];
    outm[b * 128 + d] = s * (1.f / 4096.f);
}

__global__ __launch_bounds__(256) void kgpart1(const float* __restrict__ h,
                                               const float* __restrict__ msum,
                                               float* __restrict__ part) {
    int b = blockIdx.x >> 3, sl = blockIdx.x & 7;
    int d = threadIdx.x & 127, p = threadIdx.x >> 7;
    const float* base = h + ((size_t)b * 4096 + sl * 512) * 128;
    float m = msum[b * 128 + d];
    float acc = 0.f;
    for (int l = p; l < 512; l += 2) acc += gelu_f(base[(size_t)l * 128 + d] - m);
    __shared__ float sh[256];
    sh[threadIdx.x] = acc; __syncthreads();
    if (p == 0) part[(size_t)(b * 8 + sl) * 128 + d] = acc + sh[128 + d];
}

__global__ __launch_bounds__(256) void khead(const float* __restrict__ gmean,
                                             const float* __restrict__ fc1w,
                                             const float* __restrict__ fc1b,
                                             const float* __restrict__ fc2w,
                                             const float* __restrict__ fc2b,
                                             float* __restrict__ outp) {
    __shared__ float h0[32][128];
    __shared__ float h1[32][128];
    int tid = threadIdx.x;
#pragma unroll
    for (int i = 0; i < 16; i++) {
        int e = tid + i * 256;
        h0[e >> 7][e & 127] = gmean[e];
    }
    __syncthreads();
#pragma unroll
    for (int i = 0; i < 16; i++) {
        int e = tid + i * 256; int b = e >> 7, j = e & 127;
        float s = fc1b[j];
        for (int d = 0; d < 128; d++) s += h0[b][d] * fc1w[j * 128 + d];
        h1[b][j] = fmaxf(s, 0.f);
    }
    __syncthreads();
    if (tid < 160) {
        int b = tid / 5, c2 = tid % 5;
        float s = fc2b[c2];
        for (int j = 0; j < 128; j++) s += h1[b][j] * fc2w[c2 * 128 + j];
        outp[b * 5 + c2] = s;
    }
}

extern "C" void kernel_launch(void* const* d_in, const int* in_sizes, int n_in,
                              void* d_out, int out_size, void* d_ws, size_t ws_size,
                              hipStream_t stream) {
    const float* x_enc  = (const float*)d_in[0];
    const float* emb_w  = (const float*)d_in[1];
    const float* attn_w = (const float*)d_in[2];
    const float* attn_b = (const float*)d_in[3];
    const float* ffn_w1 = (const float*)d_in[4];
    const float* ffn_w2 = (const float*)d_in[5];
    const float* norm_g = (const float*)d_in[6];
    const float* norm_b = (const float*)d_in[7];
    const float* fc1_w  = (const float*)d_in[8];
    const float* fc1_b  = (const float*)d_in[9];
    const float* fc2_w  = (const float*)d_in[10];
    const float* fc2_b  = (const float*)d_in[11];
    float* outp = (float*)d_out;

    float* W = (float*)d_ws;
    const size_t RD = (size_t)BATCH * L_SEQ * DM;       // 16,777,216
    float* buf0  = W;
    float* buf1  = W + RD;
    float* Pws   = W + 2 * RD;                          // 4,194,304 f
    float* meanv = Pws + (size_t)4194304;               // 131,072 (reused as LN partials in tail)
    float* tcb   = meanv + (size_t)131072;              // 256
    int*   idxb  = (int*)(tcb + 256);                   // 64 slots
    float* part  = tcb + 256 + 64;                      // 32,768
    float* msum  = part + 32768;                        // 4,096
    float* gsum  = msum + 4096;                         // 4,096
    unsigned short* w1img = (unsigned short*)(gsum + 4096);   // 2*65536
    unsigned short* w2img = w1img + (size_t)2 * 65536;        // 2*65536
    unsigned short* qkh   = w2img + (size_t)2 * 65536;        // 65536
    unsigned short* qkl   = qkh + (size_t)65536;              // 65536
    unsigned short* voimg = qkl + (size_t)65536;              // 65536
    float* cmg   = (float*)(voimg + (size_t)65536);           // 4,096

    kembed<<<1024, 256, 0, stream>>>(x_enc, emb_w, buf0);
    kprepw<<<1536, 256, 0, stream>>>(ffn_w1, ffn_w2, attn_w, w1img, w2img, qkh, qkl, voimg);

    float* H = buf0;
    float* S = buf1;
    for (int l = 0; l < 2; l++) {
        const float* ab = attn_b + (size_t)l * 4 * 128;
        for (int half = 0; half < 2; half++) {
            kgemm_qk3<<<dim3(2048, 2), 256, 0, stream>>>(H, qkh + (size_t)l * 32768,
                                                         qkl + (size_t)l * 32768, ab, half, S);
            kfft_fwd<<<512, 1024, 0, stream>>>(S, Pws, half);
        }
        kfft_inv<<<32, 1024, 0, stream>>>(Pws, meanv);
        kcolsum<<<16, 256, 0, stream>>>(meanv, cmg);
        ktopk2<<<1, 256, 0, stream>>>(cmg, meanv, idxb, tcb);
        unsigned short* Vb = (unsigned short*)S;
        kgemm_mfma<0, 0><<<1024, 256, 0, stream>>>(H, voimg + (size_t)l * 32768, ab + 256,
                                                   nullptr, nullptr, nullptr, Vb);
        kgemm_mfma<2, 1><<<1024, 256, 0, stream>>>(Vb, voimg + (size_t)l * 32768 + 16384, ab + 384,
                                                   H, tcb, idxb, H);
        kdecomp<<<512, 256, 0, stream>>>(H, S);
        kffn_mfma<<<1024, 256, 0, stream>>>(S, w1img + (size_t)l * 65536,
                                            w2img + (size_t)l * 65536, H);
        kdecomp<<<512, 256, 0, stream>>>(H, S);
        float* t = H; H = S; S = t;
    }

    kln_part1<<<1024, 256, 0, stream>>>(H, norm_g, norm_b, meanv);
    kpart2<<<32, 128, 0, stream>>>(meanv, msum, 32);
    kgpart1<<<256, 256, 0, stream>>>(H, msum, part);
    kpart2<<<32, 128, 0, stream>>>(part, gsum, 8);
    khead<<<1, 256, 0, stream>>>(gsum, fc1_w, fc1_b, fc2_w, fc2_b, outp);
}

// Round 9
// 1009.590 us; speedup vs baseline: 1.0478x; 1.0478x over previous
//
#include <hip/hip_runtime.h>
#include <math.h>

#define L_SEQ 4096
#define BATCH 32
#define DM 128

typedef short short8 __attribute__((ext_vector_type(8)));
typedef short short4v __attribute__((ext_vector_type(4)));
typedef float f32x4 __attribute__((ext_vector_type(4)));

__device__ __forceinline__ float gelu_f(float x) {
    return 0.5f * x * (1.0f + erff(x * 0.70710678118654752f));
}
__device__ __forceinline__ float gelu_fast(float x) {
    float ax = fabsf(x);
    if (ax < 1.0f) {
        float z = x * 0.70710678118654752f;
        float z2 = z * z;
        float p = 1.0f + z2 * (-0.333333333f + z2 * (0.1f + z2 * (-0.0238095238f +
                  z2 * (4.62962963e-3f + z2 * (-7.57575758e-4f)))));
        return 0.5f * x * (1.0f + 1.1283791670955126f * z * p);
    }
    return 0.5f * x * (1.0f + erff(x * 0.70710678118654752f));
}
__device__ __forceinline__ unsigned short f2b(float f) {
    unsigned u = __float_as_uint(f);
    u += 0x7fffu + ((u >> 16) & 1u);
    return (unsigned short)(u >> 16);
}
__device__ __forceinline__ float b2f(unsigned short h) {
    return __uint_as_float(((unsigned)h) << 16);
}

// ---------------- conv1d embedding: LDS-staged, weight-in-register ----------------
__global__ __launch_bounds__(256) void kembed(const float* __restrict__ x,
                                              const float* __restrict__ w,
                                              float* __restrict__ h) {
    __shared__ float xs[130][12];
    __shared__ float wsm[128][37];
    int b = blockIdx.x >> 5;
    int lt = blockIdx.x & 31;
    int l0 = lt * 128;
    int tid = threadIdx.x;
    for (int i = tid; i < 130 * 12; i += 256) {
        int r = i / 12, c = i - r * 12;
        int gl = (l0 - 1 + r + 4096) & 4095;
        xs[r][c] = x[((size_t)b * 4096 + gl) * 12 + c];
    }
    for (int i = tid; i < 128 * 36; i += 256) {
        int o = i / 36, j = i - o * 36;
        wsm[o][j] = w[i];
    }
    __syncthreads();
    int o = tid & 127, lh = tid >> 7;
    float wr[36];
#pragma unroll
    for (int j = 0; j < 36; j++) wr[j] = wsm[o][j];
    int base_r = lh * 64;
    float ring[4][12];
#pragma unroll
    for (int c = 0; c < 12; c++) { ring[0][c] = xs[base_r][c]; ring[1][c] = xs[base_r + 1][c]; }
    float* hp = h + ((size_t)b * 4096 + l0 + lh * 64) * 128 + o;
#pragma unroll 4
    for (int st = 0; st < 64; st++) {
        int s0 = st & 3, s1 = (st + 1) & 3, s2 = (st + 2) & 3;
#pragma unroll
        for (int c = 0; c < 12; c++) ring[s2][c] = xs[base_r + st + 2][c];
        float s = 0.f;
#pragma unroll
        for (int c = 0; c < 12; c++)
            s += wr[c * 3 + 0] * ring[s0][c] + wr[c * 3 + 1] * ring[s1][c] + wr[c * 3 + 2] * ring[s2][c];
        hp[(size_t)st * 128] = s;
    }
}

// ---------------- weight prep: bf16 pre-swizzled images ----------------
__global__ __launch_bounds__(256) void kprepw(const float* __restrict__ w1,
                                              const float* __restrict__ w2,
                                              const float* __restrict__ attn_w,
                                              unsigned short* __restrict__ w1img,
                                              unsigned short* __restrict__ w2img,
                                              unsigned short* __restrict__ qkh,
                                              unsigned short* __restrict__ qkl,
                                              unsigned short* __restrict__ voimg) {
    int t = blockIdx.x * 256 + threadIdx.x;
    if (t < 262144) {
        int layer = t >> 17; int rem = t & 131071;
        if (rem < 65536) {
            int R = rem >> 7, x = rem & 127;
            int g = x >> 3, j = x & 7;
            int srcc = ((g ^ (R & 7)) << 3) + j;
            w1img[(size_t)layer * 65536 + rem] = f2b(w1[(size_t)layer * 65536 + R * 128 + srcc]);
        } else {
            int r2 = rem - 65536;
            int c = r2 >> 13; int D = (r2 >> 6) & 127; int x = r2 & 63;
            int g = x >> 3, j = x & 7;
            int srcf = c * 64 + ((g ^ (D & 7)) << 3) + j;
            w2img[(size_t)layer * 65536 + r2] = f2b(w2[(size_t)layer * 65536 + D * 512 + srcf]);
        }
    } else if (t < 327680) {
        int t2 = t - 262144;
        int layer = t2 >> 15; int rem = t2 & 32767;
        int y = rem >> 14; int rem2 = rem & 16383;
        int r64 = rem2 >> 7; int x = rem2 & 127;
        int r = r64 & 63;
        int g = x >> 3, j = x & 7;
        int srcc = ((g ^ (r & 7)) << 3) + j;
        float v = attn_w[(size_t)layer * 65536 + y * 16384 + r64 * 128 + srcc];
        unsigned short hh = f2b(v);
        qkh[t2] = hh;
        qkl[t2] = f2b(v - b2f(hh));
    } else {
        int t3 = t - 327680;
        int layer = t3 >> 15; int rem = t3 & 32767;
        int mat = rem >> 14; int rem2 = rem & 16383;
        int r = rem2 >> 7; int x = rem2 & 127;
        int g = x >> 3, j = x & 7;
        int srcc = ((g ^ (r & 7)) << 3) + j;
        voimg[t3] = f2b(attn_w[(size_t)layer * 65536 + (2 + mat) * 16384 + r * 128 + srcc]);
    }
}

// ---- merged q+k projection, bf16x3 MFMA, bf16 transposed output CTb[b][256][4096] ----
// grid dim3(4, 2048): role = blockIdx.x (qk = role>>1, half = role&1), row block = blockIdx.y
__global__ __launch_bounds__(256, 2) void kgemm_qkb(const float* __restrict__ A,
                                                    const unsigned short* __restrict__ qkh,
                                                    const unsigned short* __restrict__ qkl,
                                                    const float* __restrict__ ab,
                                                    unsigned short* __restrict__ CTb) {
    __shared__ __align__(16) char smem[65536];
    short* Ah = (short*)smem;
    short* Al = (short*)(smem + 16384);
    short* Wh = (short*)(smem + 32768);
    short* Wl = (short*)(smem + 49152);
    int role = blockIdx.x;
    int y = role >> 1, half = role & 1;
    const unsigned short* wh = qkh + y * 16384 + half * 8192;
    const unsigned short* wl = qkl + y * 16384 + half * 8192;
    const float* bias = ab + y * 128 + half * 64;
    int row0 = blockIdx.y * 64;
    int tid = threadIdx.x;
#pragma unroll
    for (int u = 0; u < 4; u++) {
        int task = tid + u * 256;
        int r = task >> 4, cg = task & 15;
        int dst = r * 128 + ((cg ^ (r & 7)) << 3);
        const float* src = A + ((size_t)(row0 + r)) * 128 + cg * 8;
        float4 xa = *(const float4*)src, ya = *(const float4*)(src + 4);
        float av[8] = {xa.x, xa.y, xa.z, xa.w, ya.x, ya.y, ya.z, ya.w};
        short8 hi, lo;
#pragma unroll
        for (int j = 0; j < 8; j++) {
            unsigned short h = f2b(av[j]);
            hi[j] = (short)h; lo[j] = (short)f2b(av[j] - b2f(h));
        }
        *(short8*)(Ah + dst) = hi; *(short8*)(Al + dst) = lo;
        int lin = r * 128 + cg * 8;
        *(short8*)(Wh + lin) = *(const short8*)(wh + lin);
        *(short8*)(Wl + lin) = *(const short8*)(wl + lin);
    }
    __syncthreads();
    int l = tid & 63; int w = tid >> 6; int wm = w >> 1, wn = w & 1;
    f32x4 acc[2][2];
#pragma unroll
    for (int i = 0; i < 2; i++)
#pragma unroll
        for (int j = 0; j < 2; j++) acc[i][j] = (f32x4){0.f, 0.f, 0.f, 0.f};
#pragma unroll
    for (int ks = 0; ks < 4; ks++) {
        int cg = ks * 4 + (l >> 4);
        short8 ah[2], al2[2], bh[2], bl[2];
#pragma unroll
        for (int mi = 0; mi < 2; mi++) {
            int rm = wm * 32 + mi * 16 + (l & 15);
            int off = rm * 128 + ((cg ^ (rm & 7)) << 3);
            ah[mi] = *(short8*)(Ah + off); al2[mi] = *(short8*)(Al + off);
        }
#pragma unroll
        for (int ni = 0; ni < 2; ni++) {
            int rn = wn * 32 + ni * 16 + (l & 15);
            int off = rn * 128 + ((cg ^ (rn & 7)) << 3);
            bh[ni] = *(short8*)(Wh + off); bl[ni] = *(short8*)(Wl + off);
        }
#pragma unroll
        for (int mi = 0; mi < 2; mi++)
#pragma unroll
            for (int ni = 0; ni < 2; ni++) {
                acc[mi][ni] = __builtin_amdgcn_mfma_f32_16x16x32_bf16(ah[mi], bh[ni], acc[mi][ni], 0, 0, 0);
                acc[mi][ni] = __builtin_amdgcn_mfma_f32_16x16x32_bf16(ah[mi], bl[ni], acc[mi][ni], 0, 0, 0);
                acc[mi][ni] = __builtin_amdgcn_mfma_f32_16x16x32_bf16(al2[mi], bh[ni], acc[mi][ni], 0, 0, 0);
            }
    }
    __syncthreads();
    float* Dsh = (float*)smem;            // [64][68]
#pragma unroll
    for (int mi = 0; mi < 2; mi++)
#pragma unroll
        for (int ni = 0; ni < 2; ni++)
#pragma unroll
            for (int rr = 0; rr < 4; rr++) {
                int m = wm * 32 + mi * 16 + (l >> 4) * 4 + rr;
                int n = wn * 32 + ni * 16 + (l & 15);
                Dsh[n * 68 + m] = acc[mi][ni][rr] + bias[n];
            }
    __syncthreads();
    int b = row0 >> 12; int l0 = row0 & 4095;
    int cb = y * 128 + half * 64;
#pragma unroll
    for (int u = 0; u < 4; u++) {
        int task = tid + u * 256;
        int c = task >> 4, m4 = (task & 15) * 4;
        float4 v = *(float4*)&Dsh[c * 68 + m4];
        short4v o;
        o[0] = (short)f2b(v.x); o[1] = (short)f2b(v.y);
        o[2] = (short)f2b(v.z); o[3] = (short)f2b(v.w);
        *(short4v*)&CTb[((size_t)(b * 256 + cb + c)) * 4096 + l0 + m4] = o;
    }
}

// ---------------- MFMA bf16 GEMM (v-proj / fused agg+o-proj), W from image ----------------
template <int AT, int EPI>
__global__ __launch_bounds__(256, 2) void kgemm_mfma(const void* __restrict__ Ap,
                                                     const unsigned short* __restrict__ Wimg,
                                                     const float* __restrict__ bias,
                                                     const float* __restrict__ res,
                                                     const float* __restrict__ tcb,
                                                     const int* __restrict__ idxb,
                                                     void* __restrict__ outp) {
    __shared__ __align__(16) char smem[65536];
    short* As = (short*)smem;
    short* Ws = (short*)(smem + 32768);
    int tid = threadIdx.x;
    size_t row0 = (size_t)blockIdx.x * 128;
#pragma unroll
    for (int u = 0; u < 8; u++) {
        int g = tid + u * 256;
        int r = g >> 4, cg = g & 15;
        int dsti = r * 128 + ((cg ^ (r & 7)) << 3);
        short8 v;
        if (AT == 0) {
            const float* src = (const float*)Ap + (row0 + r) * 128 + cg * 8;
            float4 x = *(const float4*)src, y = *(const float4*)(src + 4);
            v[0] = f2b(x.x); v[1] = f2b(x.y); v[2] = f2b(x.z); v[3] = f2b(x.w);
            v[4] = f2b(y.x); v[5] = f2b(y.y); v[6] = f2b(y.z); v[7] = f2b(y.w);
        } else {
            const unsigned short* Vb = (const unsigned short*)Ap;
            int b = (int)(row0 >> 12);
            int l0 = (int)(row0 & 4095);
            float accv[8];
#pragma unroll
            for (int j = 0; j < 8; j++) accv[j] = 0.f;
#pragma unroll
            for (int i = 0; i < 8; i++) {
                float wgt = tcb[b * 8 + i];
                int lr = (l0 + r + idxb[i]) & 4095;
                short8 vv = *(const short8*)(Vb + ((size_t)(b * 4096 + lr)) * 128 + cg * 8);
#pragma unroll
                for (int j = 0; j < 8; j++) accv[j] += wgt * b2f((unsigned short)vv[j]);
            }
#pragma unroll
            for (int j = 0; j < 8; j++) v[j] = (short)f2b(accv[j]);
        }
        *(short8*)(As + dsti) = v;
        int lin = r * 128 + cg * 8;
        *(short8*)(Ws + lin) = *(const short8*)(Wimg + lin);
    }
    __syncthreads();
    int l = tid & 63; int w = tid >> 6; int wm = w >> 1, wn = w & 1;
    f32x4 acc[4][4];
#pragma unroll
    for (int i = 0; i < 4; i++)
#pragma unroll
        for (int j = 0; j < 4; j++) acc[i][j] = (f32x4){0.f, 0.f, 0.f, 0.f};
#pragma unroll
    for (int ks = 0; ks < 4; ks++) {
        int cg = ks * 4 + (l >> 4);
        short8 af[4], bf[4];
#pragma unroll
        for (int mi = 0; mi < 4; mi++) {
            int rm = wm * 64 + mi * 16 + (l & 15);
            af[mi] = *(short8*)(As + rm * 128 + ((cg ^ (rm & 7)) << 3));
        }
#pragma unroll
        for (int ni = 0; ni < 4; ni++) {
            int rn = wn * 64 + ni * 16 + (l & 15);
            bf[ni] = *(short8*)(Ws + rn * 128 + ((cg ^ (rn & 7)) << 3));
        }
#pragma unroll
        for (int mi = 0; mi < 4; mi++)
#pragma unroll
            for (int ni = 0; ni < 4; ni++)
                acc[mi][ni] = __builtin_amdgcn_mfma_f32_16x16x32_bf16(af[mi], bf[ni], acc[mi][ni], 0, 0, 0);
    }
    __syncthreads();
    float* Dsh = (float*)smem;
#pragma unroll
    for (int mi = 0; mi < 4; mi++)
#pragma unroll
        for (int ni = 0; ni < 4; ni++)
#pragma unroll
            for (int rr = 0; rr < 4; rr++)
                Dsh[(wm * 64 + mi * 16 + (l >> 4) * 4 + rr) * 128 + wn * 64 + ni * 16 + (l & 15)] = acc[mi][ni][rr];
    __syncthreads();
#pragma unroll
    for (int u = 0; u < 8; u++) {
        int g = tid + u * 256;
        int r = g >> 4, c8 = (g & 15) * 8;
        float vv[8];
#pragma unroll
        for (int j = 0; j < 8; j++) vv[j] = Dsh[r * 128 + c8 + j] + bias[c8 + j];
        if (EPI == 1) {
            const float* rp = res + (row0 + r) * 128 + c8;
#pragma unroll
            for (int j = 0; j < 8; j++) vv[j] += rp[j];
            float* op = (float*)outp + (row0 + r) * 128 + c8;
            *(float4*)op = make_float4(vv[0], vv[1], vv[2], vv[3]);
            *(float4*)(op + 4) = make_float4(vv[4], vv[5], vv[6], vv[7]);
        } else {
            short8 ov;
#pragma unroll
            for (int j = 0; j < 8; j++) ov[j] = (short)f2b(vv[j]);
            *(short8*)((short*)outp + (row0 + r) * 128 + c8) = ov;
        }
    }
}

// ---------------- fused MFMA FFN: 80 KB LDS, fb=64 chunks, register weight prefetch ----------------
#define LOADW(FB) do { \
    _Pragma("unroll") \
    for (int u = 0; u < 4; u++) { \
        int task = tid + u * 256; \
        int r = task >> 4, cg = task & 15; \
        p1[u] = *(const short8*)(w1img + ((size_t)((FB) * 64 + r)) * 128 + cg * 8); \
        int r2 = task >> 3, cg2 = task & 7; \
        p2[u] = *(const short8*)(w2img + ((size_t)((FB) * 128 + r2)) * 64 + cg2 * 8); \
    } \
} while (0)

__global__ __launch_bounds__(256, 2) void kffn_mfma(const float* __restrict__ xs,
                                                    const unsigned short* __restrict__ w1img,
                                                    const unsigned short* __restrict__ w2img,
                                                    float* __restrict__ outp) {
    __shared__ __align__(16) char smem[81920];
    short* xsl = (short*)smem;               // [128][128]  32K
    short* w1t = (short*)(smem + 32768);     // [64][128]   16K
    short* tt  = (short*)(smem + 49152);     // [128][64]   16K
    short* w2t = (short*)(smem + 65536);     // [128][64]   16K
    int tid = threadIdx.x;
    size_t row0 = (size_t)blockIdx.x * 128;
#pragma unroll
    for (int u = 0; u < 8; u++) {
        int g = tid + u * 256;
        int r = g >> 4, cg = g & 15;
        const float* src = xs + (row0 + r) * 128 + cg * 8;
        float4 x = *(const float4*)src, y = *(const float4*)(src + 4);
        short8 v;
        v[0] = f2b(x.x); v[1] = f2b(x.y); v[2] = f2b(x.z); v[3] = f2b(x.w);
        v[4] = f2b(y.x); v[5] = f2b(y.y); v[6] = f2b(y.z); v[7] = f2b(y.w);
        *(short8*)(xsl + r * 128 + ((cg ^ (r & 7)) << 3)) = v;
    }
    int l = tid & 63; int w = tid >> 6; int wm = w >> 1, wn = w & 1;
    f32x4 acc2[4][4];
#pragma unroll
    for (int i = 0; i < 4; i++)
#pragma unroll
        for (int j = 0; j < 4; j++) acc2[i][j] = (f32x4){0.f, 0.f, 0.f, 0.f};
    short8 p1[4], p2[4];
    LOADW(0);
    for (int fb = 0; fb < 8; fb++) {
        __syncthreads();                       // BAR_A: prior reads of w1t/w2t/tt done
#pragma unroll
        for (int u = 0; u < 4; u++) {
            int task = tid + u * 256;
            int r = task >> 4, cg = task & 15;
            *(short8*)(w1t + r * 128 + cg * 8) = p1[u];
            int r2 = task >> 3, cg2 = task & 7;
            *(short8*)(w2t + r2 * 64 + cg2 * 8) = p2[u];
        }
        __syncthreads();                       // BAR_B: weights staged
        if (fb < 7) LOADW(fb + 1);             // prefetch next chunk (hidden under MFMA)
        f32x4 a1[4][2];
#pragma unroll
        for (int i = 0; i < 4; i++)
#pragma unroll
            for (int j = 0; j < 2; j++) a1[i][j] = (f32x4){0.f, 0.f, 0.f, 0.f};
#pragma unroll
        for (int ks = 0; ks < 4; ks++) {
            int cg = ks * 4 + (l >> 4);
            short8 af[4], bf[2];
#pragma unroll
            for (int mi = 0; mi < 4; mi++) {
                int rm = wm * 64 + mi * 16 + (l & 15);
                af[mi] = *(short8*)(xsl + rm * 128 + ((cg ^ (rm & 7)) << 3));
            }
#pragma unroll
            for (int ni = 0; ni < 2; ni++) {
                int rn = wn * 32 + ni * 16 + (l & 15);
                bf[ni] = *(short8*)(w1t + rn * 128 + ((cg ^ (rn & 7)) << 3));
            }
#pragma unroll
            for (int mi = 0; mi < 4; mi++)
#pragma unroll
                for (int ni = 0; ni < 2; ni++)
                    a1[mi][ni] = __builtin_amdgcn_mfma_f32_16x16x32_bf16(af[mi], bf[ni], a1[mi][ni], 0, 0, 0);
        }
#pragma unroll
        for (int mi = 0; mi < 4; mi++)
#pragma unroll
            for (int ni = 0; ni < 2; ni++)
#pragma unroll
                for (int rr = 0; rr < 4; rr++) {
                    int m = wm * 64 + mi * 16 + (l >> 4) * 4 + rr;
                    int f = wn * 32 + ni * 16 + (l & 15);
                    tt[m * 64 + (((f >> 3) ^ (m & 7)) << 3) + (f & 7)] = (short)f2b(gelu_fast(a1[mi][ni][rr]));
                }
        __syncthreads();                       // BAR_C: t staged
#pragma unroll
        for (int ks = 0; ks < 2; ks++) {
            int cg = ks * 4 + (l >> 4);
            short8 af[4], bf[4];
#pragma unroll
            for (int mi = 0; mi < 4; mi++) {
                int rm = wm * 64 + mi * 16 + (l & 15);
                af[mi] = *(short8*)(tt + rm * 64 + ((cg ^ (rm & 7)) << 3));
            }
#pragma unroll
            for (int ni = 0; ni < 4; ni++) {
                int rn = wn * 64 + ni * 16 + (l & 15);
                bf[ni] = *(short8*)(w2t + rn * 64 + ((cg ^ (rn & 7)) << 3));
            }
#pragma unroll
            for (int mi = 0; mi < 4; mi++)
#pragma unroll
                for (int ni = 0; ni < 4; ni++)
                    acc2[mi][ni] = __builtin_amdgcn_mfma_f32_16x16x32_bf16(af[mi], bf[ni], acc2[mi][ni], 0, 0, 0);
        }
    }
    __syncthreads();
    float* Dsh = (float*)smem;
#pragma unroll
    for (int mi = 0; mi < 4; mi++)
#pragma unroll
        for (int ni = 0; ni < 4; ni++)
#pragma unroll
            for (int rr = 0; rr < 4; rr++)
                Dsh[(wm * 64 + mi * 16 + (l >> 4) * 4 + rr) * 128 + wn * 64 + ni * 16 + (l & 15)] = acc2[mi][ni][rr];
    __syncthreads();
#pragma unroll
    for (int u = 0; u < 8; u++) {
        int g = tid + u * 256;
        int r = g >> 4, c8 = (g & 15) * 8;
        const float* rp = xs + (row0 + r) * 128 + c8;
        float* op = outp + (row0 + r) * 128 + c8;
        float4 o0, o1;
        o0.x = Dsh[r * 128 + c8 + 0] + rp[0]; o0.y = Dsh[r * 128 + c8 + 1] + rp[1];
        o0.z = Dsh[r * 128 + c8 + 2] + rp[2]; o0.w = Dsh[r * 128 + c8 + 3] + rp[3];
        o1.x = Dsh[r * 128 + c8 + 4] + rp[4]; o1.y = Dsh[r * 128 + c8 + 5] + rp[5];
        o1.z = Dsh[r * 128 + c8 + 6] + rp[6]; o1.w = Dsh[r * 128 + c8 + 7] + rp[7];
        *(float4*)op = o0; *(float4*)(op + 4) = o1;
    }
}

// ---------------- radix-4 Stockham FFT-4096, 1024 threads ----------------
#define FIDX(a) ((a) + ((a) >> 4))

__device__ __forceinline__ float2 twget(const float2* __restrict__ tw, int a, float sgn) {
    float2 T = tw[a & 1023];
    int hi = (a >> 10) & 3;
    float cs = (hi & 1) ? ((hi & 2) ? T.y : -T.y) : ((hi & 2) ? -T.x : T.x);
    float sn = (hi & 1) ? ((hi & 2) ? -T.x : T.x) : ((hi & 2) ? -T.y : T.y);
    return make_float2(cs, sn * sgn);
}

__device__ void fft4096_r4(float2* __restrict__ b0, float2* __restrict__ b1,
                           const float2* __restrict__ tw, float sgn, int tid) {
    float2* cur = b0; float2* nxt = b1;
#pragma unroll
    for (int t = 0; t < 6; t++) {
        int s = 1 << (t << 1);
        int q = tid & (s - 1);
        int ps = tid - q;
        float2 a0 = cur[FIDX(tid)];
        float2 a1 = cur[FIDX(tid + 1024)];
        float2 a2 = cur[FIDX(tid + 2048)];
        float2 a3 = cur[FIDX(tid + 3072)];
        float t0x = a0.x + a2.x, t0y = a0.y + a2.y;
        float t1x = a0.x - a2.x, t1y = a0.y - a2.y;
        float t2x = a1.x + a3.x, t2y = a1.y + a3.y;
        float t3x = a1.x - a3.x, t3y = a1.y - a3.y;
        float it3x = -sgn * t3y, it3y = sgn * t3x;
        float2 A0 = make_float2(t0x + t2x, t0y + t2y);
        float2 A1 = make_float2(t1x + it3x, t1y + it3y);
        float2 A2 = make_float2(t0x - t2x, t0y - t2y);
        float2 A3 = make_float2(t1x - it3x, t1y - it3y);
        int ob = q + (ps << 2);
        nxt[FIDX(ob)] = A0;
        float2 w1 = twget(tw, ps, sgn);
        float2 w2 = twget(tw, ps * 2, sgn);
        float2 w3 = twget(tw, ps * 3, sgn);
        nxt[FIDX(ob + s)] = make_float2(A1.x * w1.x - A1.y * w1.y, A1.x * w1.y + A1.y * w1.x);
        nxt[FIDX(ob + 2 * s)] = make_float2(A2.x * w2.x - A2.y * w2.y, A2.x * w2.y + A2.y * w2.x);
        nxt[FIDX(ob + 3 * s)] = make_float2(A3.x * w3.x - A3.y * w3.y, A3.x * w3.y + A3.y * w3.x);
        __syncthreads();
        float2* tp = cur; cur = nxt; nxt = tp;
    }
}

// single pass: 8 channels/block over bf16 CTb[b][256][4096]; grid 512 = (b x 16 groups)
__global__ __launch_bounds__(1024) void kfft_fwd(const unsigned short* __restrict__ qkT,
                                                 float* __restrict__ Pws) {
    __shared__ float2 bufA[4352];
    __shared__ float2 bufB[4352];
    __shared__ float2 tw[1024];
    int tid = threadIdx.x;
    {
        float sn, cs;
        sincosf(1.5339807878856412e-3f * (float)tid, &sn, &cs);
        tw[tid] = make_float2(cs, sn);
    }
    int b = blockIdx.x >> 4;
    int g = blockIdx.x & 15;
    float2 pacc[4];
#pragma unroll
    for (int j = 0; j < 4; j++) pacc[j] = make_float2(0.f, 0.f);
    for (int c8 = 0; c8 < 8; c8++) {
        int c = g * 8 + c8;
        const unsigned short* qrow = qkT + ((size_t)(b * 256 + c)) * 4096;
        const unsigned short* krow = qkT + ((size_t)(b * 256 + 128 + c)) * 4096;
        __syncthreads();
        int i0 = tid * 4;
        short4v qv = *(const short4v*)(qrow + i0);
        short4v kv = *(const short4v*)(krow + i0);
        bufA[FIDX(i0)]     = make_float2(b2f((unsigned short)qv[0]), b2f((unsigned short)kv[0]));
        bufA[FIDX(i0 + 1)] = make_float2(b2f((unsigned short)qv[1]), b2f((unsigned short)kv[1]));
        bufA[FIDX(i0 + 2)] = make_float2(b2f((unsigned short)qv[2]), b2f((unsigned short)kv[2]));
        bufA[FIDX(i0 + 3)] = make_float2(b2f((unsigned short)qv[3]), b2f((unsigned short)kv[3]));
        __syncthreads();
        fft4096_r4(bufA, bufB, tw, -1.f, tid);
#pragma unroll
        for (int j = 0; j < 4; j++) {
            int f = tid + j * 1024;
            float2 Zf = bufA[FIDX(f)];
            float2 Zm = bufA[FIDX((4096 - f) & 4095)];
            float Qre = 0.5f * (Zf.x + Zm.x), Qim = 0.5f * (Zf.y - Zm.y);
            float Kre = 0.5f * (Zf.y + Zm.y), Kim = -0.5f * (Zf.x - Zm.x);
            pacc[j].x += Qre * Kre + Qim * Kim;
            pacc[j].y += Qim * Kre - Qre * Kim;
        }
    }
    float2* P = (float2*)Pws + (size_t)(b * 16 + g) * 4096;
#pragma unroll
    for (int j = 0; j < 4; j++) { int f = tid + j * 1024; P[f] = pacc[j]; }
}

__global__ __launch_bounds__(1024) void kfft_inv(const float* __restrict__ Pws,
                                                 float* __restrict__ meanv) {
    __shared__ float2 bufA[4352];
    __shared__ float2 bufB[4352];
    __shared__ float2 tw[1024];
    int tid = threadIdx.x;
    {
        float sn, cs;
        sincosf(1.5339807878856412e-3f * (float)tid, &sn, &cs);
        tw[tid] = make_float2(cs, sn);
    }
    int b = blockIdx.x;
    const float2* P = (const float2*)Pws + (size_t)b * 16 * 4096;
#pragma unroll
    for (int j = 0; j < 4; j++) {
        int i = tid + j * 1024;
        float2 s = make_float2(0.f, 0.f);
#pragma unroll
        for (int gg = 0; gg < 16; gg++) { float2 v = P[gg * 4096 + i]; s.x += v.x; s.y += v.y; }
        bufA[FIDX(i)] = s;
    }
    __syncthreads();
    fft4096_r4(bufA, bufB, tw, 1.f, tid);
    const float scale = 1.0f / (4096.0f * 128.0f);
#pragma unroll
    for (int j = 0; j < 4; j++) {
        int i = tid + j * 1024;
        meanv[b * 4096 + i] = bufA[FIDX(i)].x * scale;
    }
}

// ---------------- parallel column sum over batches (b ascending, bit-identical) ----------------
__global__ __launch_bounds__(256) void kcolsum(const float* __restrict__ meanv,
                                               float* __restrict__ cmg) {
    int c = blockIdx.x * 256 + threadIdx.x;
    float s = 0.f;
    for (int b = 0; b < 32; b++) s += meanv[b * 4096 + c];
    cmg[c] = s;
}

// ---------------- top-8 on presummed vector + per-batch softmax ----------------
__global__ __launch_bounds__(256) void ktopk2(const float* __restrict__ cmg,
                                              const float* __restrict__ meanv,
                                              int* __restrict__ idxout,
                                              float* __restrict__ tc) {
    __shared__ float cm[4096];
    __shared__ float rv[256];
    __shared__ int ri[256];
    __shared__ int sidx[8];
    for (int c = threadIdx.x; c < 4096; c += 256) cm[c] = cmg[c];
    __syncthreads();
    for (int it = 0; it < 8; it++) {
        float bv = -1e30f; int bi = 0;
        for (int c = threadIdx.x; c < 4096; c += 256) {
            float v = cm[c];
            if (v > bv) { bv = v; bi = c; }
        }
        rv[threadIdx.x] = bv; ri[threadIdx.x] = bi;
        __syncthreads();
        for (int off = 128; off > 0; off >>= 1) {
            if (threadIdx.x < off) {
                float v2 = rv[threadIdx.x + off]; int i2 = ri[threadIdx.x + off];
                if (v2 > rv[threadIdx.x] || (v2 == rv[threadIdx.x] && i2 < ri[threadIdx.x])) {
                    rv[threadIdx.x] = v2; ri[threadIdx.x] = i2;
                }
            }
            __syncthreads();
        }
        if (threadIdx.x == 0) { sidx[it] = ri[0]; idxout[it] = ri[0]; cm[ri[0]] = -1e30f; }
        __syncthreads();
    }
    if (threadIdx.x < 32) {
        int b = threadIdx.x;
        float w[8]; float mx = -1e30f;
#pragma unroll
        for (int i = 0; i < 8; i++) { w[i] = meanv[b * 4096 + sidx[i]]; mx = fmaxf(mx, w[i]); }
        float s = 0.f;
#pragma unroll
        for (int i = 0; i < 8; i++) { w[i] = expf(w[i] - mx); s += w[i]; }
#pragma unroll
        for (int i = 0; i < 8; i++) tc[b * 8 + i] = w[i] / s;
    }
}

// ---------------- series decomp: float4 rolling windows ----------------
__global__ __launch_bounds__(256) void kdecomp(const float* __restrict__ in,
                                               float* __restrict__ outp) {
    int b = blockIdx.x >> 4; int lc = blockIdx.x & 15;
    int dg = threadIdx.x & 31; int ls = threadIdx.x >> 5;
    int l0 = lc * 256 + ls * 32;
    const float* base = in + (size_t)b * 524288 + dg * 4;
    float* ob = outp + (size_t)b * 524288 + dg * 4;
    float sx = 0.f, sy = 0.f, sz = 0.f, sw = 0.f;
#pragma unroll
    for (int j = -12; j <= 12; j++) {
        int lj = l0 + j;
        lj = lj < 0 ? 0 : (lj > 4095 ? 4095 : lj);
        float4 v = *(const float4*)(base + (size_t)lj * 128);
        sx += v.x; sy += v.y; sz += v.z; sw += v.w;
    }
    for (int st = 0; st < 32; st++) {
        int l = l0 + st;
        float4 c = *(const float4*)(base + (size_t)l * 128);
        float4 o = make_float4(c.x - sx * (1.0f / 25.0f), c.y - sy * (1.0f / 25.0f),
                               c.z - sz * (1.0f / 25.0f), c.w - sw * (1.0f / 25.0f));
        *(float4*)(ob + (size_t)l * 128) = o;
        int ln = l + 13 > 4095 ? 4095 : l + 13;
        int lo2 = l - 12 < 0 ? 0 : l - 12;
        float4 vn = *(const float4*)(base + (size_t)ln * 128);
        float4 vo = *(const float4*)(base + (size_t)lo2 * 128);
        sx += vn.x - vo.x; sy += vn.y - vo.y; sz += vn.z - vo.z; sw += vn.w - vo.w;
    }
}

// ---------------- fused LayerNorm + column partial sums ----------------
__global__ __launch_bounds__(256) void kln_part1(float* __restrict__ h,
                                                 const float* __restrict__ g,
                                                 const float* __restrict__ bb,
                                                 float* __restrict__ part) {
    __shared__ float sh[4][128];
    int b = blockIdx.x >> 5;
    int sl = blockIdx.x & 31;
    int w = threadIdx.x >> 6;
    int lane = threadIdx.x & 63;
    float2 gv = *(const float2*)(g + lane * 2);
    float2 bv = *(const float2*)(bb + lane * 2);
    size_t r0 = (size_t)b * 4096 + sl * 128 + w * 32;
    float c0 = 0.f, c1 = 0.f;
    for (int i = 0; i < 32; i++) {
        float* p = h + (r0 + i) * 128 + lane * 2;
        float2 v = *(float2*)p;
        float s = v.x + v.y, s2 = v.x * v.x + v.y * v.y;
#pragma unroll
        for (int off = 32; off; off >>= 1) { s += __shfl_down(s, off); s2 += __shfl_down(s2, off); }
        s = __shfl(s, 0); s2 = __shfl(s2, 0);
        float mu = s * (1.f / 128.f);
        float var = s2 * (1.f / 128.f) - mu * mu;
        float inv = rsqrtf(var + 1e-5f);
        float o0 = (v.x - mu) * inv * gv.x + bv.x;
        float o1 = (v.y - mu) * inv * gv.y + bv.y;
        *(float2*)p = make_float2(o0, o1);
        c0 += o0; c1 += o1;
    }
    sh[w][lane * 2] = c0; sh[w][lane * 2 + 1] = c1;
    __syncthreads();
    if (threadIdx.x < 128) {
        int d = threadIdx.x;
        part[(size_t)(b * 32 + sl) * 128 + d] = sh[0][d] + sh[1][d] + sh[2][d] + sh[3][d];
    }
}

__global__ __launch_bounds__(128) void kpart2(const float* __restrict__ part,
                                              float* __restrict__ outm, int nq) {
    int b = blockIdx.x; int d = threadIdx.x;
    float s = 0.f;
    for (int q = 0; q < nq; q++) s += part[(size_t)(b * nq + q) * 128 + d];
    outm[b * 128 + d] = s * (1.f / 4096.f);
}

__global__ __launch_bounds__(256) void kgpart1(const float* __restrict__ h,
                                               const float* __restrict__ msum,
                                               float* __restrict__ part) {
    int b = blockIdx.x >> 3, sl = blockIdx.x & 7;
    int d = threadIdx.x & 127, p = threadIdx.x >> 7;
    const float* base = h + ((size_t)b * 4096 + sl * 512) * 128;
    float m = msum[b * 128 + d];
    float acc = 0.f;
    for (int l = p; l < 512; l += 2) acc += gelu_f(base[(size_t)l * 128 + d] - m);
    __shared__ float sh[256];
    sh[threadIdx.x] = acc; __syncthreads();
    if (p == 0) part[(size_t)(b * 8 + sl) * 128 + d] = acc + sh[128 + d];
}

__global__ __launch_bounds__(256) void khead(const float* __restrict__ gmean,
                                             const float* __restrict__ fc1w,
                                             const float* __restrict__ fc1b,
                                             const float* __restrict__ fc2w,
                                             const float* __restrict__ fc2b,
                                             float* __restrict__ outp) {
    __shared__ float h0[32][128];
    __shared__ float h1[32][128];
    int tid = threadIdx.x;
#pragma unroll
    for (int i = 0; i < 16; i++) {
        int e = tid + i * 256;
        h0[e >> 7][e & 127] = gmean[e];
    }
    __syncthreads();
#pragma unroll
    for (int i = 0; i < 16; i++) {
        int e = tid + i * 256; int b = e >> 7, j = e & 127;
        float s = fc1b[j];
        for (int d = 0; d < 128; d++) s += h0[b][d] * fc1w[j * 128 + d];
        h1[b][j] = fmaxf(s, 0.f);
    }
    __syncthreads();
    if (tid < 160) {
        int b = tid / 5, c2 = tid % 5;
        float s = fc2b[c2];
        for (int j = 0; j < 128; j++) s += h1[b][j] * fc2w[c2 * 128 + j];
        outp[b * 5 + c2] = s;
    }
}

extern "C" void kernel_launch(void* const* d_in, const int* in_sizes, int n_in,
                              void* d_out, int out_size, void* d_ws, size_t ws_size,
                              hipStream_t stream) {
    const float* x_enc  = (const float*)d_in[0];
    const float* emb_w  = (const float*)d_in[1];
    const float* attn_w = (const float*)d_in[2];
    const float* attn_b = (const float*)d_in[3];
    const float* ffn_w1 = (const float*)d_in[4];
    const float* ffn_w2 = (const float*)d_in[5];
    const float* norm_g = (const float*)d_in[6];
    const float* norm_b = (const float*)d_in[7];
    const float* fc1_w  = (const float*)d_in[8];
    const float* fc1_b  = (const float*)d_in[9];
    const float* fc2_w  = (const float*)d_in[10];
    const float* fc2_b  = (const float*)d_in[11];
    float* outp = (float*)d_out;

    float* W = (float*)d_ws;
    const size_t RD = (size_t)BATCH * L_SEQ * DM;       // 16,777,216
    float* buf0  = W;
    float* buf1  = W + RD;
    float* Pws   = W + 2 * RD;                          // 4,194,304 f
    float* meanv = Pws + (size_t)4194304;               // 131,072 (reused as LN partials in tail)
    float* tcb   = meanv + (size_t)131072;              // 256
    int*   idxb  = (int*)(tcb + 256);                   // 64 slots
    float* part  = tcb + 256 + 64;                      // 32,768
    float* msum  = part + 32768;                        // 4,096
    float* gsum  = msum + 4096;                         // 4,096
    unsigned short* w1img = (unsigned short*)(gsum + 4096);   // 2*65536
    unsigned short* w2img = w1img + (size_t)2 * 65536;        // 2*65536
    unsigned short* qkh   = w2img + (size_t)2 * 65536;        // 65536
    unsigned short* qkl   = qkh + (size_t)65536;              // 65536
    unsigned short* voimg = qkl + (size_t)65536;              // 65536
    float* cmg   = (float*)(voimg + (size_t)65536);           // 4,096

    kembed<<<1024, 256, 0, stream>>>(x_enc, emb_w, buf0);
    kprepw<<<1536, 256, 0, stream>>>(ffn_w1, ffn_w2, attn_w, w1img, w2img, qkh, qkl, voimg);

    float* H = buf0;
    float* S = buf1;
    for (int l = 0; l < 2; l++) {
        const float* ab = attn_b + (size_t)l * 4 * 128;
        unsigned short* CTb = (unsigned short*)S;       // [b][256][4096] bf16
        // merged q+k projection (bf16 out), A read once
        kgemm_qkb<<<dim3(4, 2048), 256, 0, stream>>>(H, qkh + (size_t)l * 32768,
                                                     qkl + (size_t)l * 32768, ab, CTb);
        // packed FFT + Q conj(K) accumulation, single pass
        kfft_fwd<<<512, 1024, 0, stream>>>(CTb, Pws);
        kfft_inv<<<32, 1024, 0, stream>>>(Pws, meanv);
        kcolsum<<<16, 256, 0, stream>>>(meanv, cmg);
        ktopk2<<<1, 256, 0, stream>>>(cmg, meanv, idxb, tcb);
        unsigned short* Vb = (unsigned short*)S;        // overwrites CTb (dead after fft_fwd)
        kgemm_mfma<0, 0><<<1024, 256, 0, stream>>>(H, voimg + (size_t)l * 32768, ab + 256,
                                                   nullptr, nullptr, nullptr, Vb);
        kgemm_mfma<2, 1><<<1024, 256, 0, stream>>>(Vb, voimg + (size_t)l * 32768 + 16384, ab + 384,
                                                   H, tcb, idxb, H);
        kdecomp<<<512, 256, 0, stream>>>(H, S);
        kffn_mfma<<<1024, 256, 0, stream>>>(S, w1img + (size_t)l * 65536,
                                            w2img + (size_t)l * 65536, H);
        kdecomp<<<512, 256, 0, stream>>>(H, S);
        float* t = H; H = S; S = t;
    }

    kln_part1<<<1024, 256, 0, stream>>>(H, norm_g, norm_b, meanv);
    kpart2<<<32, 128, 0, stream>>>(meanv, msum, 32);
    kgpart1<<<256, 256, 0, stream>>>(H, msum, part);
    kpart2<<<32, 128, 0, stream>>>(part, gsum, 8);
    khead<<<1, 256, 0, stream>>>(gsum, fc1_w, fc1_b, fc2_w, fc2_b, outp);
}

// Round 10
// 990.081 us; speedup vs baseline: 1.0685x; 1.0197x over previous
//
#include <hip/hip_runtime.h>
#include <math.h>

#define L_SEQ 4096
#define BATCH 32
#define DM 128

typedef short short8 __attribute__((ext_vector_type(8)));
typedef short short4v __attribute__((ext_vector_type(4)));
typedef float f32x4 __attribute__((ext_vector_type(4)));

__device__ __forceinline__ float gelu_f(float x) {
    return 0.5f * x * (1.0f + erff(x * 0.70710678118654752f));
}
__device__ __forceinline__ float gelu_fast(float x) {
    float ax = fabsf(x);
    if (ax < 1.0f) {
        float z = x * 0.70710678118654752f;
        float z2 = z * z;
        float p = 1.0f + z2 * (-0.333333333f + z2 * (0.1f + z2 * (-0.0238095238f +
                  z2 * (4.62962963e-3f + z2 * (-7.57575758e-4f)))));
        return 0.5f * x * (1.0f + 1.1283791670955126f * z * p);
    }
    return 0.5f * x * (1.0f + erff(x * 0.70710678118654752f));
}
__device__ __forceinline__ unsigned short f2b(float f) {
    unsigned u = __float_as_uint(f);
    u += 0x7fffu + ((u >> 16) & 1u);
    return (unsigned short)(u >> 16);
}
__device__ __forceinline__ float b2f(unsigned short h) {
    return __uint_as_float(((unsigned)h) << 16);
}

// ---------------- conv1d embedding: LDS-staged, weight-in-register ----------------
__global__ __launch_bounds__(256) void kembed(const float* __restrict__ x,
                                              const float* __restrict__ w,
                                              float* __restrict__ h) {
    __shared__ float xs[130][12];
    __shared__ float wsm[128][37];
    int b = blockIdx.x >> 5;
    int lt = blockIdx.x & 31;
    int l0 = lt * 128;
    int tid = threadIdx.x;
    for (int i = tid; i < 130 * 12; i += 256) {
        int r = i / 12, c = i - r * 12;
        int gl = (l0 - 1 + r + 4096) & 4095;
        xs[r][c] = x[((size_t)b * 4096 + gl) * 12 + c];
    }
    for (int i = tid; i < 128 * 36; i += 256) {
        int o = i / 36, j = i - o * 36;
        wsm[o][j] = w[i];
    }
    __syncthreads();
    int o = tid & 127, lh = tid >> 7;
    float wr[36];
#pragma unroll
    for (int j = 0; j < 36; j++) wr[j] = wsm[o][j];
    int base_r = lh * 64;
    float ring[4][12];
#pragma unroll
    for (int c = 0; c < 12; c++) { ring[0][c] = xs[base_r][c]; ring[1][c] = xs[base_r + 1][c]; }
    float* hp = h + ((size_t)b * 4096 + l0 + lh * 64) * 128 + o;
#pragma unroll 4
    for (int st = 0; st < 64; st++) {
        int s0 = st & 3, s1 = (st + 1) & 3, s2 = (st + 2) & 3;
#pragma unroll
        for (int c = 0; c < 12; c++) ring[s2][c] = xs[base_r + st + 2][c];
        float s = 0.f;
#pragma unroll
        for (int c = 0; c < 12; c++)
            s += wr[c * 3 + 0] * ring[s0][c] + wr[c * 3 + 1] * ring[s1][c] + wr[c * 3 + 2] * ring[s2][c];
        hp[(size_t)st * 128] = s;
    }
}

// ---------------- weight prep: bf16 pre-swizzled images ----------------
__global__ __launch_bounds__(256) void kprepw(const float* __restrict__ w1,
                                              const float* __restrict__ w2,
                                              const float* __restrict__ attn_w,
                                              unsigned short* __restrict__ w1img,
                                              unsigned short* __restrict__ w2img,
                                              unsigned short* __restrict__ qkh,
                                              unsigned short* __restrict__ qkl,
                                              unsigned short* __restrict__ voimg) {
    int t = blockIdx.x * 256 + threadIdx.x;
    if (t < 262144) {
        int layer = t >> 17; int rem = t & 131071;
        if (rem < 65536) {
            int R = rem >> 7, x = rem & 127;
            int g = x >> 3, j = x & 7;
            int srcc = ((g ^ (R & 7)) << 3) + j;
            w1img[(size_t)layer * 65536 + rem] = f2b(w1[(size_t)layer * 65536 + R * 128 + srcc]);
        } else {
            int r2 = rem - 65536;
            int c = r2 >> 13; int D = (r2 >> 6) & 127; int x = r2 & 63;
            int g = x >> 3, j = x & 7;
            int srcf = c * 64 + ((g ^ (D & 7)) << 3) + j;
            w2img[(size_t)layer * 65536 + r2] = f2b(w2[(size_t)layer * 65536 + D * 512 + srcf]);
        }
    } else if (t < 327680) {
        int t2 = t - 262144;
        int layer = t2 >> 15; int rem = t2 & 32767;
        int y = rem >> 14; int rem2 = rem & 16383;
        int r64 = rem2 >> 7; int x = rem2 & 127;
        int r = r64 & 63;
        int g = x >> 3, j = x & 7;
        int srcc = ((g ^ (r & 7)) << 3) + j;
        float v = attn_w[(size_t)layer * 65536 + y * 16384 + r64 * 128 + srcc];
        unsigned short hh = f2b(v);
        qkh[t2] = hh;
        qkl[t2] = f2b(v - b2f(hh));
    } else {
        int t3 = t - 327680;
        int layer = t3 >> 15; int rem = t3 & 32767;
        int mat = rem >> 14; int rem2 = rem & 16383;
        int r = rem2 >> 7; int x = rem2 & 127;
        int g = x >> 3, j = x & 7;
        int srcc = ((g ^ (r & 7)) << 3) + j;
        voimg[t3] = f2b(attn_w[(size_t)layer * 65536 + (2 + mat) * 16384 + r * 128 + srcc]);
    }
}

// ---- merged q+k projection: A staged ONCE, 4 roles looped; bf16 out CTb[b][256][4096] ----
__global__ __launch_bounds__(256, 2) void kgemm_qkb(const float* __restrict__ A,
                                                    const unsigned short* __restrict__ qkh,
                                                    const unsigned short* __restrict__ qkl,
                                                    const float* __restrict__ ab,
                                                    unsigned short* __restrict__ CTb) {
    __shared__ __align__(16) char smem[65536];
    short* Ah = (short*)smem;                 // [64][128]
    short* Al = (short*)(smem + 16384);
    short* Wh = (short*)(smem + 32768);
    short* Wl = (short*)(smem + 49152);
    float* Dsh = (float*)(smem + 32768);      // [64][68] overlays Wh/Wl
    int row0i = blockIdx.x * 64;
    int tid = threadIdx.x;
#pragma unroll
    for (int u = 0; u < 4; u++) {
        int task = tid + u * 256;
        int r = task >> 4, cg = task & 15;
        int dst = r * 128 + ((cg ^ (r & 7)) << 3);
        const float* src = A + ((size_t)(row0i + r)) * 128 + cg * 8;
        float4 xa = *(const float4*)src, ya = *(const float4*)(src + 4);
        float av[8] = {xa.x, xa.y, xa.z, xa.w, ya.x, ya.y, ya.z, ya.w};
        short8 hi, lo;
#pragma unroll
        for (int j = 0; j < 8; j++) {
            unsigned short hh = f2b(av[j]);
            hi[j] = (short)hh; lo[j] = (short)f2b(av[j] - b2f(hh));
        }
        *(short8*)(Ah + dst) = hi; *(short8*)(Al + dst) = lo;
    }
    int l = tid & 63; int w = tid >> 6; int wm = w >> 1, wn = w & 1;
    int b = row0i >> 12; int l0 = row0i & 4095;
    for (int role = 0; role < 4; role++) {
        int y = role >> 1, half = role & 1;
        const unsigned short* wh = qkh + y * 16384 + half * 8192;
        const unsigned short* wl = qkl + y * 16384 + half * 8192;
        const float* bias = ab + y * 128 + half * 64;
        __syncthreads();                      // A ready (role 0) / prev Dsh reads done
#pragma unroll
        for (int u = 0; u < 4; u++) {
            int task = tid + u * 256;
            int lin = (task >> 4) * 128 + (task & 15) * 8;
            *(short8*)(Wh + lin) = *(const short8*)(wh + lin);
            *(short8*)(Wl + lin) = *(const short8*)(wl + lin);
        }
        __syncthreads();
        f32x4 acc[2][2];
#pragma unroll
        for (int i = 0; i < 2; i++)
#pragma unroll
            for (int j = 0; j < 2; j++) acc[i][j] = (f32x4){0.f, 0.f, 0.f, 0.f};
#pragma unroll
        for (int ks = 0; ks < 4; ks++) {
            int cg = ks * 4 + (l >> 4);
            short8 ah[2], al2[2], bh[2], bl[2];
#pragma unroll
            for (int mi = 0; mi < 2; mi++) {
                int rm = wm * 32 + mi * 16 + (l & 15);
                int off = rm * 128 + ((cg ^ (rm & 7)) << 3);
                ah[mi] = *(short8*)(Ah + off); al2[mi] = *(short8*)(Al + off);
            }
#pragma unroll
            for (int ni = 0; ni < 2; ni++) {
                int rn = wn * 32 + ni * 16 + (l & 15);
                int off = rn * 128 + ((cg ^ (rn & 7)) << 3);
                bh[ni] = *(short8*)(Wh + off); bl[ni] = *(short8*)(Wl + off);
            }
#pragma unroll
            for (int mi = 0; mi < 2; mi++)
#pragma unroll
                for (int ni = 0; ni < 2; ni++) {
                    acc[mi][ni] = __builtin_amdgcn_mfma_f32_16x16x32_bf16(ah[mi], bh[ni], acc[mi][ni], 0, 0, 0);
                    acc[mi][ni] = __builtin_amdgcn_mfma_f32_16x16x32_bf16(ah[mi], bl[ni], acc[mi][ni], 0, 0, 0);
                    acc[mi][ni] = __builtin_amdgcn_mfma_f32_16x16x32_bf16(al2[mi], bh[ni], acc[mi][ni], 0, 0, 0);
                }
        }
        __syncthreads();                      // W reads done; Dsh region free
#pragma unroll
        for (int mi = 0; mi < 2; mi++)
#pragma unroll
            for (int ni = 0; ni < 2; ni++)
#pragma unroll
                for (int rr = 0; rr < 4; rr++) {
                    int m = wm * 32 + mi * 16 + (l >> 4) * 4 + rr;
                    int n = wn * 32 + ni * 16 + (l & 15);
                    Dsh[n * 68 + m] = acc[mi][ni][rr] + bias[n];
                }
        __syncthreads();
        int cb = y * 128 + half * 64;
#pragma unroll
        for (int u = 0; u < 4; u++) {
            int task = tid + u * 256;
            int c = task >> 4, m4 = (task & 15) * 4;
            float4 v = *(float4*)&Dsh[c * 68 + m4];
            short4v o;
            o[0] = (short)f2b(v.x); o[1] = (short)f2b(v.y);
            o[2] = (short)f2b(v.z); o[3] = (short)f2b(v.w);
            *(short4v*)&CTb[((size_t)(b * 256 + cb + c)) * 4096 + l0 + m4] = o;
        }
    }
}

// ---------------- MFMA bf16 GEMM (v-proj / fused agg+o-proj), W from image ----------------
// AT==2 uses XCD batch-grouping swizzle: all 32 tiles of batch b land on XCD b%8 so the
// batch's Vb slab (1 MB bf16) stays in the per-XCD L2 across the 8 lag reads.
template <int AT, int EPI>
__global__ __launch_bounds__(256, 2) void kgemm_mfma(const void* __restrict__ Ap,
                                                     const unsigned short* __restrict__ Wimg,
                                                     const float* __restrict__ bias,
                                                     const float* __restrict__ res,
                                                     const float* __restrict__ tcb,
                                                     const int* __restrict__ idxb,
                                                     void* __restrict__ outp) {
    __shared__ __align__(16) char smem[65536];
    short* As = (short*)smem;
    short* Ws = (short*)(smem + 32768);
    int tid = threadIdx.x;
    size_t row0;
    if (AT == 2) {
        int B = blockIdx.x;
        int cls = B & 7, j = B >> 3;
        int bq = cls + 8 * (j >> 5);
        int t = j & 31;
        row0 = ((size_t)bq * 32 + t) * 128;
    } else {
        row0 = (size_t)blockIdx.x * 128;
    }
#pragma unroll
    for (int u = 0; u < 8; u++) {
        int g = tid + u * 256;
        int r = g >> 4, cg = g & 15;
        int dsti = r * 128 + ((cg ^ (r & 7)) << 3);
        short8 v;
        if (AT == 0) {
            const float* src = (const float*)Ap + (row0 + r) * 128 + cg * 8;
            float4 x = *(const float4*)src, y = *(const float4*)(src + 4);
            v[0] = f2b(x.x); v[1] = f2b(x.y); v[2] = f2b(x.z); v[3] = f2b(x.w);
            v[4] = f2b(y.x); v[5] = f2b(y.y); v[6] = f2b(y.z); v[7] = f2b(y.w);
        } else {
            const unsigned short* Vb = (const unsigned short*)Ap;
            int b = (int)(row0 >> 12);
            int l0 = (int)(row0 & 4095);
            float accv[8];
#pragma unroll
            for (int j = 0; j < 8; j++) accv[j] = 0.f;
#pragma unroll
            for (int i = 0; i < 8; i++) {
                float wgt = tcb[b * 8 + i];
                int lr = (l0 + r + idxb[i]) & 4095;
                short8 vv = *(const short8*)(Vb + ((size_t)(b * 4096 + lr)) * 128 + cg * 8);
#pragma unroll
                for (int j = 0; j < 8; j++) accv[j] += wgt * b2f((unsigned short)vv[j]);
            }
#pragma unroll
            for (int j = 0; j < 8; j++) v[j] = (short)f2b(accv[j]);
        }
        *(short8*)(As + dsti) = v;
        int lin = r * 128 + cg * 8;
        *(short8*)(Ws + lin) = *(const short8*)(Wimg + lin);
    }
    __syncthreads();
    int l = tid & 63; int w = tid >> 6; int wm = w >> 1, wn = w & 1;
    f32x4 acc[4][4];
#pragma unroll
    for (int i = 0; i < 4; i++)
#pragma unroll
        for (int j = 0; j < 4; j++) acc[i][j] = (f32x4){0.f, 0.f, 0.f, 0.f};
#pragma unroll
    for (int ks = 0; ks < 4; ks++) {
        int cg = ks * 4 + (l >> 4);
        short8 af[4], bf[4];
#pragma unroll
        for (int mi = 0; mi < 4; mi++) {
            int rm = wm * 64 + mi * 16 + (l & 15);
            af[mi] = *(short8*)(As + rm * 128 + ((cg ^ (rm & 7)) << 3));
        }
#pragma unroll
        for (int ni = 0; ni < 4; ni++) {
            int rn = wn * 64 + ni * 16 + (l & 15);
            bf[ni] = *(short8*)(Ws + rn * 128 + ((cg ^ (rn & 7)) << 3));
        }
#pragma unroll
        for (int mi = 0; mi < 4; mi++)
#pragma unroll
            for (int ni = 0; ni < 4; ni++)
                acc[mi][ni] = __builtin_amdgcn_mfma_f32_16x16x32_bf16(af[mi], bf[ni], acc[mi][ni], 0, 0, 0);
    }
    __syncthreads();
    float* Dsh = (float*)smem;
#pragma unroll
    for (int mi = 0; mi < 4; mi++)
#pragma unroll
        for (int ni = 0; ni < 4; ni++)
#pragma unroll
            for (int rr = 0; rr < 4; rr++)
                Dsh[(wm * 64 + mi * 16 + (l >> 4) * 4 + rr) * 128 + wn * 64 + ni * 16 + (l & 15)] = acc[mi][ni][rr];
    __syncthreads();
#pragma unroll
    for (int u = 0; u < 8; u++) {
        int g = tid + u * 256;
        int r = g >> 4, c8 = (g & 15) * 8;
        float vv[8];
#pragma unroll
        for (int j = 0; j < 8; j++) vv[j] = Dsh[r * 128 + c8 + j] + bias[c8 + j];
        if (EPI == 1) {
            const float* rp = res + (row0 + r) * 128 + c8;
#pragma unroll
            for (int j = 0; j < 8; j++) vv[j] += rp[j];
            float* op = (float*)outp + (row0 + r) * 128 + c8;
            *(float4*)op = make_float4(vv[0], vv[1], vv[2], vv[3]);
            *(float4*)(op + 4) = make_float4(vv[4], vv[5], vv[6], vv[7]);
        } else {
            short8 ov;
#pragma unroll
            for (int j = 0; j < 8; j++) ov[j] = (short)f2b(vv[j]);
            *(short8*)((short*)outp + (row0 + r) * 128 + c8) = ov;
        }
    }
}

// ---------------- fused MFMA FFN (round-7 proven): 80 KB LDS, fb=64 chunks ----------------
__global__ __launch_bounds__(256, 2) void kffn_mfma(const float* __restrict__ xs,
                                                    const unsigned short* __restrict__ w1img,
                                                    const unsigned short* __restrict__ w2img,
                                                    float* __restrict__ outp) {
    __shared__ __align__(16) char smem[81920];
    short* xsl = (short*)smem;               // [128][128]  32K
    short* w1t = (short*)(smem + 32768);     // [64][128]   16K
    short* tt  = (short*)(smem + 49152);     // [128][64]   16K
    short* w2t = (short*)(smem + 65536);     // [128][64]   16K
    int tid = threadIdx.x;
    size_t row0 = (size_t)blockIdx.x * 128;
#pragma unroll
    for (int u = 0; u < 8; u++) {
        int g = tid + u * 256;
        int r = g >> 4, cg = g & 15;
        const float* src = xs + (row0 + r) * 128 + cg * 8;
        float4 x = *(const float4*)src, y = *(const float4*)(src + 4);
        short8 v;
        v[0] = f2b(x.x); v[1] = f2b(x.y); v[2] = f2b(x.z); v[3] = f2b(x.w);
        v[4] = f2b(y.x); v[5] = f2b(y.y); v[6] = f2b(y.z); v[7] = f2b(y.w);
        *(short8*)(xsl + r * 128 + ((cg ^ (r & 7)) << 3)) = v;
    }
    int l = tid & 63; int w = tid >> 6; int wm = w >> 1, wn = w & 1;
    f32x4 acc2[4][4];
#pragma unroll
    for (int i = 0; i < 4; i++)
#pragma unroll
        for (int j = 0; j < 4; j++) acc2[i][j] = (f32x4){0.f, 0.f, 0.f, 0.f};
    for (int fb = 0; fb < 8; fb++) {
        __syncthreads();                       // BAR_A
#pragma unroll
        for (int u = 0; u < 4; u++) {
            int task = tid + u * 256;
            int r = task >> 4, cg = task & 15;
            *(short8*)(w1t + r * 128 + cg * 8) =
                *(const short8*)(w1img + ((size_t)(fb * 64 + r)) * 128 + cg * 8);
            int r2 = task >> 3, cg2 = task & 7;
            *(short8*)(w2t + r2 * 64 + cg2 * 8) =
                *(const short8*)(w2img + ((size_t)(fb * 128 + r2)) * 64 + cg2 * 8);
        }
        __syncthreads();                       // BAR_B
        f32x4 a1[4][2];
#pragma unroll
        for (int i = 0; i < 4; i++)
#pragma unroll
            for (int j = 0; j < 2; j++) a1[i][j] = (f32x4){0.f, 0.f, 0.f, 0.f};
#pragma unroll
        for (int ks = 0; ks < 4; ks++) {
            int cg = ks * 4 + (l >> 4);
            short8 af[4], bf[2];
#pragma unroll
            for (int mi = 0; mi < 4; mi++) {
                int rm = wm * 64 + mi * 16 + (l & 15);
                af[mi] = *(short8*)(xsl + rm * 128 + ((cg ^ (rm & 7)) << 3));
            }
#pragma unroll
            for (int ni = 0; ni < 2; ni++) {
                int rn = wn * 32 + ni * 16 + (l & 15);
                bf[ni] = *(short8*)(w1t + rn * 128 + ((cg ^ (rn & 7)) << 3));
            }
#pragma unroll
            for (int mi = 0; mi < 4; mi++)
#pragma unroll
                for (int ni = 0; ni < 2; ni++)
                    a1[mi][ni] = __builtin_amdgcn_mfma_f32_16x16x32_bf16(af[mi], bf[ni], a1[mi][ni], 0, 0, 0);
        }
#pragma unroll
        for (int mi = 0; mi < 4; mi++)
#pragma unroll
            for (int ni = 0; ni < 2; ni++)
#pragma unroll
                for (int rr = 0; rr < 4; rr++) {
                    int m = wm * 64 + mi * 16 + (l >> 4) * 4 + rr;
                    int f = wn * 32 + ni * 16 + (l & 15);
                    tt[m * 64 + (((f >> 3) ^ (m & 7)) << 3) + (f & 7)] = (short)f2b(gelu_fast(a1[mi][ni][rr]));
                }
        __syncthreads();                       // BAR_C
#pragma unroll
        for (int ks = 0; ks < 2; ks++) {
            int cg = ks * 4 + (l >> 4);
            short8 af[4], bf[4];
#pragma unroll
            for (int mi = 0; mi < 4; mi++) {
                int rm = wm * 64 + mi * 16 + (l & 15);
                af[mi] = *(short8*)(tt + rm * 64 + ((cg ^ (rm & 7)) << 3));
            }
#pragma unroll
            for (int ni = 0; ni < 4; ni++) {
                int rn = wn * 64 + ni * 16 + (l & 15);
                bf[ni] = *(short8*)(w2t + rn * 64 + ((cg ^ (rn & 7)) << 3));
            }
#pragma unroll
            for (int mi = 0; mi < 4; mi++)
#pragma unroll
                for (int ni = 0; ni < 4; ni++)
                    acc2[mi][ni] = __builtin_amdgcn_mfma_f32_16x16x32_bf16(af[mi], bf[ni], acc2[mi][ni], 0, 0, 0);
        }
    }
    __syncthreads();
    float* Dsh = (float*)smem;
#pragma unroll
    for (int mi = 0; mi < 4; mi++)
#pragma unroll
        for (int ni = 0; ni < 4; ni++)
#pragma unroll
            for (int rr = 0; rr < 4; rr++)
                Dsh[(wm * 64 + mi * 16 + (l >> 4) * 4 + rr) * 128 + wn * 64 + ni * 16 + (l & 15)] = acc2[mi][ni][rr];
    __syncthreads();
#pragma unroll
    for (int u = 0; u < 8; u++) {
        int g = tid + u * 256;
        int r = g >> 4, c8 = (g & 15) * 8;
        const float* rp = xs + (row0 + r) * 128 + c8;
        float* op = outp + (row0 + r) * 128 + c8;
        float4 o0, o1;
        o0.x = Dsh[r * 128 + c8 + 0] + rp[0]; o0.y = Dsh[r * 128 + c8 + 1] + rp[1];
        o0.z = Dsh[r * 128 + c8 + 2] + rp[2]; o0.w = Dsh[r * 128 + c8 + 3] + rp[3];
        o1.x = Dsh[r * 128 + c8 + 4] + rp[4]; o1.y = Dsh[r * 128 + c8 + 5] + rp[5];
        o1.z = Dsh[r * 128 + c8 + 6] + rp[6]; o1.w = Dsh[r * 128 + c8 + 7] + rp[7];
        *(float4*)op = o0; *(float4*)(op + 4) = o1;
    }
}

// ---------------- radix-4 Stockham FFT-4096, 1024 threads ----------------
#define FIDX(a) ((a) + ((a) >> 4))

__device__ __forceinline__ float2 twget(const float2* __restrict__ tw, int a, float sgn) {
    float2 T = tw[a & 1023];
    int hi = (a >> 10) & 3;
    float cs = (hi & 1) ? ((hi & 2) ? T.y : -T.y) : ((hi & 2) ? -T.x : T.x);
    float sn = (hi & 1) ? ((hi & 2) ? -T.x : T.x) : ((hi & 2) ? -T.y : T.y);
    return make_float2(cs, sn * sgn);
}

__device__ void fft4096_r4(float2* __restrict__ b0, float2* __restrict__ b1,
                           const float2* __restrict__ tw, float sgn, int tid) {
    float2* cur = b0; float2* nxt = b1;
#pragma unroll
    for (int t = 0; t < 6; t++) {
        int s = 1 << (t << 1);
        int q = tid & (s - 1);
        int ps = tid - q;
        float2 a0 = cur[FIDX(tid)];
        float2 a1 = cur[FIDX(tid + 1024)];
        float2 a2 = cur[FIDX(tid + 2048)];
        float2 a3 = cur[FIDX(tid + 3072)];
        float t0x = a0.x + a2.x, t0y = a0.y + a2.y;
        float t1x = a0.x - a2.x, t1y = a0.y - a2.y;
        float t2x = a1.x + a3.x, t2y = a1.y + a3.y;
        float t3x = a1.x - a3.x, t3y = a1.y - a3.y;
        float it3x = -sgn * t3y, it3y = sgn * t3x;
        float2 A0 = make_float2(t0x + t2x, t0y + t2y);
        float2 A1 = make_float2(t1x + it3x, t1y + it3y);
        float2 A2 = make_float2(t0x - t2x, t0y - t2y);
        float2 A3 = make_float2(t1x - it3x, t1y - it3y);
        int ob = q + (ps << 2);
        nxt[FIDX(ob)] = A0;
        float2 w1 = twget(tw, ps, sgn);
        float2 w2 = twget(tw, ps * 2, sgn);
        float2 w3 = twget(tw, ps * 3, sgn);
        nxt[FIDX(ob + s)] = make_float2(A1.x * w1.x - A1.y * w1.y, A1.x * w1.y + A1.y * w1.x);
        nxt[FIDX(ob + 2 * s)] = make_float2(A2.x * w2.x - A2.y * w2.y, A2.x * w2.y + A2.y * w2.x);
        nxt[FIDX(ob + 3 * s)] = make_float2(A3.x * w3.x - A3.y * w3.y, A3.x * w3.y + A3.y * w3.x);
        __syncthreads();
        float2* tp = cur; cur = nxt; nxt = tp;
    }
}

// single pass: 8 channels/block over bf16 CTb[b][256][4096]; grid 512 = (b x 16 groups)
__global__ __launch_bounds__(1024) void kfft_fwd(const unsigned short* __restrict__ qkT,
                                                 float* __restrict__ Pws) {
    __shared__ float2 bufA[4352];
    __shared__ float2 bufB[4352];
    __shared__ float2 tw[1024];
    int tid = threadIdx.x;
    {
        float sn, cs;
        sincosf(1.5339807878856412e-3f * (float)tid, &sn, &cs);
        tw[tid] = make_float2(cs, sn);
    }
    int b = blockIdx.x >> 4;
    int g = blockIdx.x & 15;
    float2 pacc[4];
#pragma unroll
    for (int j = 0; j < 4; j++) pacc[j] = make_float2(0.f, 0.f);
    for (int c8 = 0; c8 < 8; c8++) {
        int c = g * 8 + c8;
        const unsigned short* qrow = qkT + ((size_t)(b * 256 + c)) * 4096;
        const unsigned short* krow = qkT + ((size_t)(b * 256 + 128 + c)) * 4096;
        __syncthreads();
        int i0 = tid * 4;
        short4v qv = *(const short4v*)(qrow + i0);
        short4v kv = *(const short4v*)(krow + i0);
        bufA[FIDX(i0)]     = make_float2(b2f((unsigned short)qv[0]), b2f((unsigned short)kv[0]));
        bufA[FIDX(i0 + 1)] = make_float2(b2f((unsigned short)qv[1]), b2f((unsigned short)kv[1]));
        bufA[FIDX(i0 + 2)] = make_float2(b2f((unsigned short)qv[2]), b2f((unsigned short)kv[2]));
        bufA[FIDX(i0 + 3)] = make_float2(b2f((unsigned short)qv[3]), b2f((unsigned short)kv[3]));
        __syncthreads();
        fft4096_r4(bufA, bufB, tw, -1.f, tid);
#pragma unroll
        for (int j = 0; j < 4; j++) {
            int f = tid + j * 1024;
            float2 Zf = bufA[FIDX(f)];
            float2 Zm = bufA[FIDX((4096 - f) & 4095)];
            float Qre = 0.5f * (Zf.x + Zm.x), Qim = 0.5f * (Zf.y - Zm.y);
            float Kre = 0.5f * (Zf.y + Zm.y), Kim = -0.5f * (Zf.x - Zm.x);
            pacc[j].x += Qre * Kre + Qim * Kim;
            pacc[j].y += Qim * Kre - Qre * Kim;
        }
    }
    float2* P = (float2*)Pws + (size_t)(b * 16 + g) * 4096;
#pragma unroll
    for (int j = 0; j < 4; j++) { int f = tid + j * 1024; P[f] = pacc[j]; }
}

// ---------------- presum the 16 P-slices at full BW (gg ascending, bit-identical) ----------------
__global__ __launch_bounds__(256) void kpsum(const float* __restrict__ Pws,
                                             float* __restrict__ Pr) {
    int t = blockIdx.x * 256 + threadIdx.x;      // 131072 float2 elements
    int b = t >> 12, i = t & 4095;
    const float2* P = (const float2*)Pws;
    float2 s = make_float2(0.f, 0.f);
#pragma unroll
    for (int gg = 0; gg < 16; gg++) {
        float2 v = P[((size_t)(b * 16 + gg)) * 4096 + i];
        s.x += v.x; s.y += v.y;
    }
    ((float2*)Pr)[(size_t)b * 4096 + i] = s;
}

__global__ __launch_bounds__(1024) void kfft_inv(const float* __restrict__ Prs,
                                                 float* __restrict__ meanv) {
    __shared__ float2 bufA[4352];
    __shared__ float2 bufB[4352];
    __shared__ float2 tw[1024];
    int tid = threadIdx.x;
    {
        float sn, cs;
        sincosf(1.5339807878856412e-3f * (float)tid, &sn, &cs);
        tw[tid] = make_float2(cs, sn);
    }
    int b = blockIdx.x;
    const float2* P = (const float2*)Prs + (size_t)b * 4096;
#pragma unroll
    for (int j = 0; j < 4; j++) {
        int i = tid + j * 1024;
        bufA[FIDX(i)] = P[i];
    }
    __syncthreads();
    fft4096_r4(bufA, bufB, tw, 1.f, tid);
    const float scale = 1.0f / (4096.0f * 128.0f);
#pragma unroll
    for (int j = 0; j < 4; j++) {
        int i = tid + j * 1024;
        meanv[b * 4096 + i] = bufA[FIDX(i)].x * scale;
    }
}

// ---------------- parallel column sum over batches (b ascending, bit-identical) ----------------
__global__ __launch_bounds__(256) void kcolsum(const float* __restrict__ meanv,
                                               float* __restrict__ cmg) {
    int c = blockIdx.x * 256 + threadIdx.x;
    float s = 0.f;
    for (int b = 0; b < 32; b++) s += meanv[b * 4096 + c];
    cmg[c] = s;
}

// ---------------- top-8 on presummed vector + per-batch softmax ----------------
__global__ __launch_bounds__(256) void ktopk2(const float* __restrict__ cmg,
                                              const float* __restrict__ meanv,
                                              int* __restrict__ idxout,
                                              float* __restrict__ tc) {
    __shared__ float cm[4096];
    __shared__ float rv[256];
    __shared__ int ri[256];
    __shared__ int sidx[8];
    for (int c = threadIdx.x; c < 4096; c += 256) cm[c] = cmg[c];
    __syncthreads();
    for (int it = 0; it < 8; it++) {
        float bv = -1e30f; int bi = 0;
        for (int c = threadIdx.x; c < 4096; c += 256) {
            float v = cm[c];
            if (v > bv) { bv = v; bi = c; }
        }
        rv[threadIdx.x] = bv; ri[threadIdx.x] = bi;
        __syncthreads();
        for (int off = 128; off > 0; off >>= 1) {
            if (threadIdx.x < off) {
                float v2 = rv[threadIdx.x + off]; int i2 = ri[threadIdx.x + off];
                if (v2 > rv[threadIdx.x] || (v2 == rv[threadIdx.x] && i2 < ri[threadIdx.x])) {
                    rv[threadIdx.x] = v2; ri[threadIdx.x] = i2;
                }
            }
            __syncthreads();
        }
        if (threadIdx.x == 0) { sidx[it] = ri[0]; idxout[it] = ri[0]; cm[ri[0]] = -1e30f; }
        __syncthreads();
    }
    if (threadIdx.x < 32) {
        int b = threadIdx.x;
        float w[8]; float mx = -1e30f;
#pragma unroll
        for (int i = 0; i < 8; i++) { w[i] = meanv[b * 4096 + sidx[i]]; mx = fmaxf(mx, w[i]); }
        float s = 0.f;
#pragma unroll
        for (int i = 0; i < 8; i++) { w[i] = expf(w[i] - mx); s += w[i]; }
#pragma unroll
        for (int i = 0; i < 8; i++) tc[b * 8 + i] = w[i] / s;
    }
}

// ---------------- series decomp: float4 rolling windows ----------------
__global__ __launch_bounds__(256) void kdecomp(const float* __restrict__ in,
                                               float* __restrict__ outp) {
    int b = blockIdx.x >> 4; int lc = blockIdx.x & 15;
    int dg = threadIdx.x & 31; int ls = threadIdx.x >> 5;
    int l0 = lc * 256 + ls * 32;
    const float* base = in + (size_t)b * 524288 + dg * 4;
    float* ob = outp + (size_t)b * 524288 + dg * 4;
    float sx = 0.f, sy = 0.f, sz = 0.f, sw = 0.f;
#pragma unroll
    for (int j = -12; j <= 12; j++) {
        int lj = l0 + j;
        lj = lj < 0 ? 0 : (lj > 4095 ? 4095 : lj);
        float4 v = *(const float4*)(base + (size_t)lj * 128);
        sx += v.x; sy += v.y; sz += v.z; sw += v.w;
    }
    for (int st = 0; st < 32; st++) {
        int l = l0 + st;
        float4 c = *(const float4*)(base + (size_t)l * 128);
        float4 o = make_float4(c.x - sx * (1.0f / 25.0f), c.y - sy * (1.0f / 25.0f),
                               c.z - sz * (1.0f / 25.0f), c.w - sw * (1.0f / 25.0f));
        *(float4*)(ob + (size_t)l * 128) = o;
        int ln = l + 13 > 4095 ? 4095 : l + 13;
        int lo2 = l - 12 < 0 ? 0 : l - 12;
        float4 vn = *(const float4*)(base + (size_t)ln * 128);
        float4 vo = *(const float4*)(base + (size_t)lo2 * 128);
        sx += vn.x - vo.x; sy += vn.y - vo.y; sz += vn.z - vo.z; sw += vn.w - vo.w;
    }
}

// ---------------- fused LayerNorm + column partial sums ----------------
__global__ __launch_bounds__(256) void kln_part1(float* __restrict__ h,
                                                 const float* __restrict__ g,
                                                 const float* __restrict__ bb,
                                                 float* __restrict__ part) {
    __shared__ float sh[4][128];
    int b = blockIdx.x >> 5;
    int sl = blockIdx.x & 31;
    int w = threadIdx.x >> 6;
    int lane = threadIdx.x & 63;
    float2 gv = *(const float2*)(g + lane * 2);
    float2 bv = *(const float2*)(bb + lane * 2);
    size_t r0 = (size_t)b * 4096 + sl * 128 + w * 32;
    float c0 = 0.f, c1 = 0.f;
    for (int i = 0; i < 32; i++) {
        float* p = h + (r0 + i) * 128 + lane * 2;
        float2 v = *(float2*)p;
        float s = v.x + v.y, s2 = v.x * v.x + v.y * v.y;
#pragma unroll
        for (int off = 32; off; off >>= 1) { s += __shfl_down(s, off); s2 += __shfl_down(s2, off); }
        s = __shfl(s, 0); s2 = __shfl(s2, 0);
        float mu = s * (1.f / 128.f);
        float var = s2 * (1.f / 128.f) - mu * mu;
        float inv = rsqrtf(var + 1e-5f);
        float o0 = (v.x - mu) * inv * gv.x + bv.x;
        float o1 = (v.y - mu) * inv * gv.y + bv.y;
        *(float2*)p = make_float2(o0, o1);
        c0 += o0; c1 += o1;
    }
    sh[w][lane * 2] = c0; sh[w][lane * 2 + 1] = c1;
    __syncthreads();
    if (threadIdx.x < 128) {
        int d = threadIdx.x;
        part[(size_t)(b * 32 + sl) * 128 + d] = sh[0][d] + sh[1][d] + sh[2][d] + sh[3][d];
    }
}

__global__ __launch_bounds__(128) void kpart2(const float* __restrict__ part,
                                              float* __restrict__ outm, int nq) {
    int b = blockIdx.x; int d = threadIdx.x;
    float s = 0.f;
    for (int q = 0; q < nq; q++) s += part[(size_t)(b * nq + q) * 128 + d];
    outm[b * 128 + d] = s * (1.f / 4096.f);
}

__global__ __launch_bounds__(256) void kgpart1(const float* __restrict__ h,
                                               const float* __restrict__ msum,
                                               float* __restrict__ part) {
    int b = blockIdx.x >> 3, sl = blockIdx.x & 7;
    int d = threadIdx.x & 127, p = threadIdx.x >> 7;
    const float* base = h + ((size_t)b * 4096 + sl * 512) * 128;
    float m = msum[b * 128 + d];
    float acc = 0.f;
    for (int l = p; l < 512; l += 2) acc += gelu_f(base[(size_t)l * 128 + d] - m);
    __shared__ float sh[256];
    sh[threadIdx.x] = acc; __syncthreads();
    if (p == 0) part[(size_t)(b * 8 + sl) * 128 + d] = acc + sh[128 + d];
}

__global__ __launch_bounds__(256) void khead(const float* __restrict__ gmean,
                                             const float* __restrict__ fc1w,
                                             const float* __restrict__ fc1b,
                                             const float* __restrict__ fc2w,
                                             const float* __restrict__ fc2b,
                                             float* __restrict__ outp) {
    __shared__ float h0[32][128];
    __shared__ float h1[32][128];
    int tid = threadIdx.x;
#pragma unroll
    for (int i = 0; i < 16; i++) {
        int e = tid + i * 256;
        h0[e >> 7][e & 127] = gmean[e];
    }
    __syncthreads();
#pragma unroll
    for (int i = 0; i < 16; i++) {
        int e = tid + i * 256; int b = e >> 7, j = e & 127;
        float s = fc1b[j];
        for (int d = 0; d < 128; d++) s += h0[b][d] * fc1w[j * 128 + d];
        h1[b][j] = fmaxf(s, 0.f);
    }
    __syncthreads();
    if (tid < 160) {
        int b = tid / 5, c2 = tid % 5;
        float s = fc2b[c2];
        for (int j = 0; j < 128; j++) s += h1[b][j] * fc2w[c2 * 128 + j];
        outp[b * 5 + c2] = s;
    }
}

extern "C" void kernel_launch(void* const* d_in, const int* in_sizes, int n_in,
                              void* d_out, int out_size, void* d_ws, size_t ws_size,
                              hipStream_t stream) {
    const float* x_enc  = (const float*)d_in[0];
    const float* emb_w  = (const float*)d_in[1];
    const float* attn_w = (const float*)d_in[2];
    const float* attn_b = (const float*)d_in[3];
    const float* ffn_w1 = (const float*)d_in[4];
    const float* ffn_w2 = (const float*)d_in[5];
    const float* norm_g = (const float*)d_in[6];
    const float* norm_b = (const float*)d_in[7];
    const float* fc1_w  = (const float*)d_in[8];
    const float* fc1_b  = (const float*)d_in[9];
    const float* fc2_w  = (const float*)d_in[10];
    const float* fc2_b  = (const float*)d_in[11];
    float* outp = (float*)d_out;

    float* W = (float*)d_ws;
    const size_t RD = (size_t)BATCH * L_SEQ * DM;       // 16,777,216
    float* buf0  = W;
    float* buf1  = W + RD;
    float* Pws   = W + 2 * RD;                          // 4,194,304 f
    float* meanv = Pws + (size_t)4194304;               // 131,072 (reused as LN partials in tail)
    float* tcb   = meanv + (size_t)131072;              // 256
    int*   idxb  = (int*)(tcb + 256);                   // 64 slots
    float* part  = tcb + 256 + 64;                      // 32,768
    float* msum  = part + 32768;                        // 4,096
    float* gsum  = msum + 4096;                         // 4,096
    unsigned short* w1img = (unsigned short*)(gsum + 4096);   // 2*65536
    unsigned short* w2img = w1img + (size_t)2 * 65536;        // 2*65536
    unsigned short* qkh   = w2img + (size_t)2 * 65536;        // 65536
    unsigned short* qkl   = qkh + (size_t)65536;              // 65536
    unsigned short* voimg = qkl + (size_t)65536;              // 65536
    float* cmg   = (float*)(voimg + (size_t)65536);           // 4,096
    float* Pr    = cmg + 4096;                                // 262,144 (presummed P)

    kembed<<<1024, 256, 0, stream>>>(x_enc, emb_w, buf0);
    kprepw<<<1536, 256, 0, stream>>>(ffn_w1, ffn_w2, attn_w, w1img, w2img, qkh, qkl, voimg);

    float* H = buf0;
    float* S = buf1;
    for (int l = 0; l < 2; l++) {
        const float* ab = attn_b + (size_t)l * 4 * 128;
        unsigned short* CTb = (unsigned short*)S;       // [b][256][4096] bf16
        // merged q+k projection (A staged once, 4 roles looped)
        kgemm_qkb<<<2048, 256, 0, stream>>>(H, qkh + (size_t)l * 32768,
                                            qkl + (size_t)l * 32768, ab, CTb);
        // packed FFT + Q conj(K) accumulation
        kfft_fwd<<<512, 1024, 0, stream>>>(CTb, Pws);
        kpsum<<<512, 256, 0, stream>>>(Pws, Pr);
        kfft_inv<<<32, 1024, 0, stream>>>(Pr, meanv);
        kcolsum<<<16, 256, 0, stream>>>(meanv, cmg);
        ktopk2<<<1, 256, 0, stream>>>(cmg, meanv, idxb, tcb);
        unsigned short* Vb = (unsigned short*)S;        // overwrites CTb (dead after fft_fwd)
        kgemm_mfma<0, 0><<<1024, 256, 0, stream>>>(H, voimg + (size_t)l * 32768, ab + 256,
                                                   nullptr, nullptr, nullptr, Vb);
        kgemm_mfma<2, 1><<<1024, 256, 0, stream>>>(Vb, voimg + (size_t)l * 32768 + 16384, ab + 384,
                                                   H, tcb, idxb, H);
        kdecomp<<<512, 256, 0, stream>>>(H, S);
        kffn_mfma<<<1024, 256, 0, stream>>>(S, w1img + (size_t)l * 65536,
                                            w2img + (size_t)l * 65536, H);
        kdecomp<<<512, 256, 0, stream>>>(H, S);
        float* t = H; H = S; S = t;
    }

    kln_part1<<<1024, 256, 0, stream>>>(H, norm_g, norm_b, meanv);
    kpart2<<<32, 128, 0, stream>>>(meanv, msum, 32);
    kgpart1<<<256, 256, 0, stream>>>(H, msum, part);
    kpart2<<<32, 128, 0, stream>>>(part, gsum, 8);
    khead<<<1, 256, 0, stream>>>(gsum, fc1_w, fc1_b, fc2_w, fc2_b, outp);
}

// Round 11
// 971.702 us; speedup vs baseline: 1.0887x; 1.0189x over previous
//
#include <hip/hip_runtime.h>
#include <math.h>

#define L_SEQ 4096
#define BATCH 32
#define DM 128

typedef short short8 __attribute__((ext_vector_type(8)));
typedef short short4v __attribute__((ext_vector_type(4)));
typedef float f32x4 __attribute__((ext_vector_type(4)));

__device__ __forceinline__ float gelu_f(float x) {
    return 0.5f * x * (1.0f + erff(x * 0.70710678118654752f));
}
__device__ __forceinline__ float gelu_fast(float x) {
    float ax = fabsf(x);
    if (ax < 1.0f) {
        float z = x * 0.70710678118654752f;
        float z2 = z * z;
        float p = 1.0f + z2 * (-0.333333333f + z2 * (0.1f + z2 * (-0.0238095238f +
                  z2 * (4.62962963e-3f + z2 * (-7.57575758e-4f)))));
        return 0.5f * x * (1.0f + 1.1283791670955126f * z * p);
    }
    return 0.5f * x * (1.0f + erff(x * 0.70710678118654752f));
}
__device__ __forceinline__ unsigned short f2b(float f) {
    unsigned u = __float_as_uint(f);
    u += 0x7fffu + ((u >> 16) & 1u);
    return (unsigned short)(u >> 16);
}
__device__ __forceinline__ float b2f(unsigned short h) {
    return __uint_as_float(((unsigned)h) << 16);
}

// ---------------- conv1d embedding: LDS-staged, weight-in-register ----------------
__global__ __launch_bounds__(256) void kembed(const float* __restrict__ x,
                                              const float* __restrict__ w,
                                              float* __restrict__ h) {
    __shared__ float xs[130][12];
    __shared__ float wsm[128][37];
    int b = blockIdx.x >> 5;
    int lt = blockIdx.x & 31;
    int l0 = lt * 128;
    int tid = threadIdx.x;
    for (int i = tid; i < 130 * 12; i += 256) {
        int r = i / 12, c = i - r * 12;
        int gl = (l0 - 1 + r + 4096) & 4095;
        xs[r][c] = x[((size_t)b * 4096 + gl) * 12 + c];
    }
    for (int i = tid; i < 128 * 36; i += 256) {
        int o = i / 36, j = i - o * 36;
        wsm[o][j] = w[i];
    }
    __syncthreads();
    int o = tid & 127, lh = tid >> 7;
    float wr[36];
#pragma unroll
    for (int j = 0; j < 36; j++) wr[j] = wsm[o][j];
    int base_r = lh * 64;
    float ring[4][12];
#pragma unroll
    for (int c = 0; c < 12; c++) { ring[0][c] = xs[base_r][c]; ring[1][c] = xs[base_r + 1][c]; }
    float* hp = h + ((size_t)b * 4096 + l0 + lh * 64) * 128 + o;
#pragma unroll 4
    for (int st = 0; st < 64; st++) {
        int s0 = st & 3, s1 = (st + 1) & 3, s2 = (st + 2) & 3;
#pragma unroll
        for (int c = 0; c < 12; c++) ring[s2][c] = xs[base_r + st + 2][c];
        float s = 0.f;
#pragma unroll
        for (int c = 0; c < 12; c++)
            s += wr[c * 3 + 0] * ring[s0][c] + wr[c * 3 + 1] * ring[s1][c] + wr[c * 3 + 2] * ring[s2][c];
        hp[(size_t)st * 128] = s;
    }
}

// ---------------- weight prep: bf16 pre-swizzled images ----------------
__global__ __launch_bounds__(256) void kprepw(const float* __restrict__ w1,
                                              const float* __restrict__ w2,
                                              const float* __restrict__ attn_w,
                                              unsigned short* __restrict__ w1img,
                                              unsigned short* __restrict__ w2img,
                                              unsigned short* __restrict__ qkh,
                                              unsigned short* __restrict__ qkl,
                                              unsigned short* __restrict__ voimg) {
    int t = blockIdx.x * 256 + threadIdx.x;
    if (t < 262144) {
        int layer = t >> 17; int rem = t & 131071;
        if (rem < 65536) {
            int R = rem >> 7, x = rem & 127;
            int g = x >> 3, j = x & 7;
            int srcc = ((g ^ (R & 7)) << 3) + j;
            w1img[(size_t)layer * 65536 + rem] = f2b(w1[(size_t)layer * 65536 + R * 128 + srcc]);
        } else {
            int r2 = rem - 65536;
            int c = r2 >> 13; int D = (r2 >> 6) & 127; int x = r2 & 63;
            int g = x >> 3, j = x & 7;
            int srcf = c * 64 + ((g ^ (D & 7)) << 3) + j;
            w2img[(size_t)layer * 65536 + r2] = f2b(w2[(size_t)layer * 65536 + D * 512 + srcf]);
        }
    } else if (t < 327680) {
        int t2 = t - 262144;
        int layer = t2 >> 15; int rem = t2 & 32767;
        int y = rem >> 14; int rem2 = rem & 16383;
        int r64 = rem2 >> 7; int x = rem2 & 127;
        int r = r64 & 63;
        int g = x >> 3, j = x & 7;
        int srcc = ((g ^ (r & 7)) << 3) + j;
        float v = attn_w[(size_t)layer * 65536 + y * 16384 + r64 * 128 + srcc];
        unsigned short hh = f2b(v);
        qkh[t2] = hh;
        qkl[t2] = f2b(v - b2f(hh));
    } else {
        int t3 = t - 327680;
        int layer = t3 >> 15; int rem = t3 & 32767;
        int mat = rem >> 14; int rem2 = rem & 16383;
        int r = rem2 >> 7; int x = rem2 & 127;
        int g = x >> 3, j = x & 7;
        int srcc = ((g ^ (r & 7)) << 3) + j;
        voimg[t3] = f2b(attn_w[(size_t)layer * 65536 + (2 + mat) * 16384 + r * 128 + srcc]);
    }
}

// ---- merged q+k projection: A staged ONCE, 4 roles looped; bf16 out CTb[b][256][4096] ----
__global__ __launch_bounds__(256, 2) void kgemm_qkb(const float* __restrict__ A,
                                                    const unsigned short* __restrict__ qkh,
                                                    const unsigned short* __restrict__ qkl,
                                                    const float* __restrict__ ab,
                                                    unsigned short* __restrict__ CTb) {
    __shared__ __align__(16) char smem[65536];
    short* Ah = (short*)smem;                 // [64][128]
    short* Al = (short*)(smem + 16384);
    short* Wh = (short*)(smem + 32768);
    short* Wl = (short*)(smem + 49152);
    float* Dsh = (float*)(smem + 32768);      // [64][68] overlays Wh/Wl
    int row0i = blockIdx.x * 64;
    int tid = threadIdx.x;
#pragma unroll
    for (int u = 0; u < 4; u++) {
        int task = tid + u * 256;
        int r = task >> 4, cg = task & 15;
        int dst = r * 128 + ((cg ^ (r & 7)) << 3);
        const float* src = A + ((size_t)(row0i + r)) * 128 + cg * 8;
        float4 xa = *(const float4*)src, ya = *(const float4*)(src + 4);
        float av[8] = {xa.x, xa.y, xa.z, xa.w, ya.x, ya.y, ya.z, ya.w};
        short8 hi, lo;
#pragma unroll
        for (int j = 0; j < 8; j++) {
            unsigned short hh = f2b(av[j]);
            hi[j] = (short)hh; lo[j] = (short)f2b(av[j] - b2f(hh));
        }
        *(short8*)(Ah + dst) = hi; *(short8*)(Al + dst) = lo;
    }
    int l = tid & 63; int w = tid >> 6; int wm = w >> 1, wn = w & 1;
    int b = row0i >> 12; int l0 = row0i & 4095;
    for (int role = 0; role < 4; role++) {
        int y = role >> 1, half = role & 1;
        const unsigned short* wh = qkh + y * 16384 + half * 8192;
        const unsigned short* wl = qkl + y * 16384 + half * 8192;
        const float* bias = ab + y * 128 + half * 64;
        __syncthreads();                      // A ready (role 0) / prev Dsh reads done
#pragma unroll
        for (int u = 0; u < 4; u++) {
            int task = tid + u * 256;
            int lin = (task >> 4) * 128 + (task & 15) * 8;
            *(short8*)(Wh + lin) = *(const short8*)(wh + lin);
            *(short8*)(Wl + lin) = *(const short8*)(wl + lin);
        }
        __syncthreads();
        f32x4 acc[2][2];
#pragma unroll
        for (int i = 0; i < 2; i++)
#pragma unroll
            for (int j = 0; j < 2; j++) acc[i][j] = (f32x4){0.f, 0.f, 0.f, 0.f};
#pragma unroll
        for (int ks = 0; ks < 4; ks++) {
            int cg = ks * 4 + (l >> 4);
            short8 ah[2], al2[2], bh[2], bl[2];
#pragma unroll
            for (int mi = 0; mi < 2; mi++) {
                int rm = wm * 32 + mi * 16 + (l & 15);
                int off = rm * 128 + ((cg ^ (rm & 7)) << 3);
                ah[mi] = *(short8*)(Ah + off); al2[mi] = *(short8*)(Al + off);
            }
#pragma unroll
            for (int ni = 0; ni < 2; ni++) {
                int rn = wn * 32 + ni * 16 + (l & 15);
                int off = rn * 128 + ((cg ^ (rn & 7)) << 3);
                bh[ni] = *(short8*)(Wh + off); bl[ni] = *(short8*)(Wl + off);
            }
#pragma unroll
            for (int mi = 0; mi < 2; mi++)
#pragma unroll
                for (int ni = 0; ni < 2; ni++) {
                    acc[mi][ni] = __builtin_amdgcn_mfma_f32_16x16x32_bf16(ah[mi], bh[ni], acc[mi][ni], 0, 0, 0);
                    acc[mi][ni] = __builtin_amdgcn_mfma_f32_16x16x32_bf16(ah[mi], bl[ni], acc[mi][ni], 0, 0, 0);
                    acc[mi][ni] = __builtin_amdgcn_mfma_f32_16x16x32_bf16(al2[mi], bh[ni], acc[mi][ni], 0, 0, 0);
                }
        }
        __syncthreads();                      // W reads done; Dsh region free
#pragma unroll
        for (int mi = 0; mi < 2; mi++)
#pragma unroll
            for (int ni = 0; ni < 2; ni++)
#pragma unroll
                for (int rr = 0; rr < 4; rr++) {
                    int m = wm * 32 + mi * 16 + (l >> 4) * 4 + rr;
                    int n = wn * 32 + ni * 16 + (l & 15);
                    Dsh[n * 68 + m] = acc[mi][ni][rr] + bias[n];
                }
        __syncthreads();
        int cb = y * 128 + half * 64;
#pragma unroll
        for (int u = 0; u < 4; u++) {
            int task = tid + u * 256;
            int c = task >> 4, m4 = (task & 15) * 4;
            float4 v = *(float4*)&Dsh[c * 68 + m4];
            short4v o;
            o[0] = (short)f2b(v.x); o[1] = (short)f2b(v.y);
            o[2] = (short)f2b(v.z); o[3] = (short)f2b(v.w);
            *(short4v*)&CTb[((size_t)(b * 256 + cb + c)) * 4096 + l0 + m4] = o;
        }
    }
}

// ---------------- MFMA bf16 GEMM (v-proj / fused agg+o-proj), W from image ----------------
template <int AT, int EPI>
__global__ __launch_bounds__(256, 2) void kgemm_mfma(const void* __restrict__ Ap,
                                                     const unsigned short* __restrict__ Wimg,
                                                     const float* __restrict__ bias,
                                                     const float* __restrict__ res,
                                                     const float* __restrict__ tcb,
                                                     const int* __restrict__ idxb,
                                                     void* __restrict__ outp) {
    __shared__ __align__(16) char smem[65536];
    short* As = (short*)smem;
    short* Ws = (short*)(smem + 32768);
    int tid = threadIdx.x;
    size_t row0;
    if (AT == 2) {
        int B = blockIdx.x;
        int cls = B & 7, j = B >> 3;
        int bq = cls + 8 * (j >> 5);
        int t = j & 31;
        row0 = ((size_t)bq * 32 + t) * 128;
    } else {
        row0 = (size_t)blockIdx.x * 128;
    }
#pragma unroll
    for (int u = 0; u < 8; u++) {
        int g = tid + u * 256;
        int r = g >> 4, cg = g & 15;
        int dsti = r * 128 + ((cg ^ (r & 7)) << 3);
        short8 v;
        if (AT == 0) {
            const float* src = (const float*)Ap + (row0 + r) * 128 + cg * 8;
            float4 x = *(const float4*)src, y = *(const float4*)(src + 4);
            v[0] = f2b(x.x); v[1] = f2b(x.y); v[2] = f2b(x.z); v[3] = f2b(x.w);
            v[4] = f2b(y.x); v[5] = f2b(y.y); v[6] = f2b(y.z); v[7] = f2b(y.w);
        } else {
            const unsigned short* Vb = (const unsigned short*)Ap;
            int b = (int)(row0 >> 12);
            int l0 = (int)(row0 & 4095);
            float accv[8];
#pragma unroll
            for (int j = 0; j < 8; j++) accv[j] = 0.f;
#pragma unroll
            for (int i = 0; i < 8; i++) {
                float wgt = tcb[b * 8 + i];
                int lr = (l0 + r + idxb[i]) & 4095;
                short8 vv = *(const short8*)(Vb + ((size_t)(b * 4096 + lr)) * 128 + cg * 8);
#pragma unroll
                for (int j = 0; j < 8; j++) accv[j] += wgt * b2f((unsigned short)vv[j]);
            }
#pragma unroll
            for (int j = 0; j < 8; j++) v[j] = (short)f2b(accv[j]);
        }
        *(short8*)(As + dsti) = v;
        int lin = r * 128 + cg * 8;
        *(short8*)(Ws + lin) = *(const short8*)(Wimg + lin);
    }
    __syncthreads();
    int l = tid & 63; int w = tid >> 6; int wm = w >> 1, wn = w & 1;
    f32x4 acc[4][4];
#pragma unroll
    for (int i = 0; i < 4; i++)
#pragma unroll
        for (int j = 0; j < 4; j++) acc[i][j] = (f32x4){0.f, 0.f, 0.f, 0.f};
#pragma unroll
    for (int ks = 0; ks < 4; ks++) {
        int cg = ks * 4 + (l >> 4);
        short8 af[4], bf[4];
#pragma unroll
        for (int mi = 0; mi < 4; mi++) {
            int rm = wm * 64 + mi * 16 + (l & 15);
            af[mi] = *(short8*)(As + rm * 128 + ((cg ^ (rm & 7)) << 3));
        }
#pragma unroll
        for (int ni = 0; ni < 4; ni++) {
            int rn = wn * 64 + ni * 16 + (l & 15);
            bf[ni] = *(short8*)(Ws + rn * 128 + ((cg ^ (rn & 7)) << 3));
        }
#pragma unroll
        for (int mi = 0; mi < 4; mi++)
#pragma unroll
            for (int ni = 0; ni < 4; ni++)
                acc[mi][ni] = __builtin_amdgcn_mfma_f32_16x16x32_bf16(af[mi], bf[ni], acc[mi][ni], 0, 0, 0);
    }
    __syncthreads();
    float* Dsh = (float*)smem;
#pragma unroll
    for (int mi = 0; mi < 4; mi++)
#pragma unroll
        for (int ni = 0; ni < 4; ni++)
#pragma unroll
            for (int rr = 0; rr < 4; rr++)
                Dsh[(wm * 64 + mi * 16 + (l >> 4) * 4 + rr) * 128 + wn * 64 + ni * 16 + (l & 15)] = acc[mi][ni][rr];
    __syncthreads();
#pragma unroll
    for (int u = 0; u < 8; u++) {
        int g = tid + u * 256;
        int r = g >> 4, c8 = (g & 15) * 8;
        float vv[8];
#pragma unroll
        for (int j = 0; j < 8; j++) vv[j] = Dsh[r * 128 + c8 + j] + bias[c8 + j];
        if (EPI == 1) {
            const float* rp = res + (row0 + r) * 128 + c8;
#pragma unroll
            for (int j = 0; j < 8; j++) vv[j] += rp[j];
            float* op = (float*)outp + (row0 + r) * 128 + c8;
            *(float4*)op = make_float4(vv[0], vv[1], vv[2], vv[3]);
            *(float4*)(op + 4) = make_float4(vv[4], vv[5], vv[6], vv[7]);
        } else {
            short8 ov;
#pragma unroll
            for (int j = 0; j < 8; j++) ov[j] = (short)f2b(vv[j]);
            *(short8*)((short*)outp + (row0 + r) * 128 + c8) = ov;
        }
    }
}

// ---------------- fused MFMA FFN: 512 threads (8 waves 2x4), 80 KB LDS, fb=64 chunks ----------------
__global__ __launch_bounds__(512, 4) void kffn_mfma(const float* __restrict__ xs,
                                                    const unsigned short* __restrict__ w1img,
                                                    const unsigned short* __restrict__ w2img,
                                                    float* __restrict__ outp) {
    __shared__ __align__(16) char smem[81920];
    short* xsl = (short*)smem;               // [128][128]  32K
    short* w1t = (short*)(smem + 32768);     // [64][128]   16K
    short* tt  = (short*)(smem + 49152);     // [128][64]   16K
    short* w2t = (short*)(smem + 65536);     // [128][64]   16K
    int tid = threadIdx.x;
    size_t row0 = (size_t)blockIdx.x * 128;
#pragma unroll
    for (int u = 0; u < 4; u++) {
        int g = tid + u * 512;
        int r = g >> 4, cg = g & 15;
        const float* src = xs + (row0 + r) * 128 + cg * 8;
        float4 x = *(const float4*)src, y = *(const float4*)(src + 4);
        short8 v;
        v[0] = f2b(x.x); v[1] = f2b(x.y); v[2] = f2b(x.z); v[3] = f2b(x.w);
        v[4] = f2b(y.x); v[5] = f2b(y.y); v[6] = f2b(y.z); v[7] = f2b(y.w);
        *(short8*)(xsl + r * 128 + ((cg ^ (r & 7)) << 3)) = v;
    }
    int l = tid & 63; int w = tid >> 6;      // 8 waves
    int wm = w >> 2, wn = w & 3;             // 2 x 4
    f32x4 acc2[4][2];
#pragma unroll
    for (int i = 0; i < 4; i++)
#pragma unroll
        for (int j = 0; j < 2; j++) acc2[i][j] = (f32x4){0.f, 0.f, 0.f, 0.f};
    for (int fb = 0; fb < 8; fb++) {
        __syncthreads();                       // BAR_A (first iter: xsl ready)
#pragma unroll
        for (int u = 0; u < 2; u++) {
            int task = tid + u * 512;
            int r = task >> 4, cg = task & 15;
            *(short8*)(w1t + r * 128 + cg * 8) =
                *(const short8*)(w1img + ((size_t)(fb * 64 + r)) * 128 + cg * 8);
            int r2 = task >> 3, cg2 = task & 7;
            *(short8*)(w2t + r2 * 64 + cg2 * 8) =
                *(const short8*)(w2img + ((size_t)(fb * 128 + r2)) * 64 + cg2 * 8);
        }
        __syncthreads();                       // BAR_B
        // stage 1: t[128][64] = gelu(xsl @ w1_chunk^T); per wave 64 rows x 16 cols
        f32x4 a1[4];
#pragma unroll
        for (int i = 0; i < 4; i++) a1[i] = (f32x4){0.f, 0.f, 0.f, 0.f};
#pragma unroll
        for (int ks = 0; ks < 4; ks++) {
            int cg = ks * 4 + (l >> 4);
            short8 af[4], bf;
#pragma unroll
            for (int mi = 0; mi < 4; mi++) {
                int rm = wm * 64 + mi * 16 + (l & 15);
                af[mi] = *(short8*)(xsl + rm * 128 + ((cg ^ (rm & 7)) << 3));
            }
            {
                int rn = wn * 16 + (l & 15);
                bf = *(short8*)(w1t + rn * 128 + ((cg ^ (rn & 7)) << 3));
            }
#pragma unroll
            for (int mi = 0; mi < 4; mi++)
                a1[mi] = __builtin_amdgcn_mfma_f32_16x16x32_bf16(af[mi], bf, a1[mi], 0, 0, 0);
        }
#pragma unroll
        for (int mi = 0; mi < 4; mi++)
#pragma unroll
            for (int rr = 0; rr < 4; rr++) {
                int m = wm * 64 + mi * 16 + (l >> 4) * 4 + rr;
                int f = wn * 16 + (l & 15);
                tt[m * 64 + (((f >> 3) ^ (m & 7)) << 3) + (f & 7)] = (short)f2b(gelu_fast(a1[mi][rr]));
            }
        __syncthreads();                       // BAR_C
        // stage 2: acc2 += t @ w2_chunk^T (K=64); per wave 64 rows x 32 cols
#pragma unroll
        for (int ks = 0; ks < 2; ks++) {
            int cg = ks * 4 + (l >> 4);
            short8 af[4], bf[2];
#pragma unroll
            for (int mi = 0; mi < 4; mi++) {
                int rm = wm * 64 + mi * 16 + (l & 15);
                af[mi] = *(short8*)(tt + rm * 64 + ((cg ^ (rm & 7)) << 3));
            }
#pragma unroll
            for (int ni = 0; ni < 2; ni++) {
                int rn = wn * 32 + ni * 16 + (l & 15);
                bf[ni] = *(short8*)(w2t + rn * 64 + ((cg ^ (rn & 7)) << 3));
            }
#pragma unroll
            for (int mi = 0; mi < 4; mi++)
#pragma unroll
                for (int ni = 0; ni < 2; ni++)
                    acc2[mi][ni] = __builtin_amdgcn_mfma_f32_16x16x32_bf16(af[mi], bf[ni], acc2[mi][ni], 0, 0, 0);
        }
    }
    __syncthreads();
    float* Dsh = (float*)smem;                 // [128][128] f32 over first 64KB
#pragma unroll
    for (int mi = 0; mi < 4; mi++)
#pragma unroll
        for (int ni = 0; ni < 2; ni++)
#pragma unroll
            for (int rr = 0; rr < 4; rr++)
                Dsh[(wm * 64 + mi * 16 + (l >> 4) * 4 + rr) * 128 + wn * 32 + ni * 16 + (l & 15)] = acc2[mi][ni][rr];
    __syncthreads();
#pragma unroll
    for (int u = 0; u < 4; u++) {
        int g = tid + u * 512;
        int r = g >> 4, c8 = (g & 15) * 8;
        const float* rp = xs + (row0 + r) * 128 + c8;
        float* op = outp + (row0 + r) * 128 + c8;
        float4 o0, o1;
        o0.x = Dsh[r * 128 + c8 + 0] + rp[0]; o0.y = Dsh[r * 128 + c8 + 1] + rp[1];
        o0.z = Dsh[r * 128 + c8 + 2] + rp[2]; o0.w = Dsh[r * 128 + c8 + 3] + rp[3];
        o1.x = Dsh[r * 128 + c8 + 4] + rp[4]; o1.y = Dsh[r * 128 + c8 + 5] + rp[5];
        o1.z = Dsh[r * 128 + c8 + 6] + rp[6]; o1.w = Dsh[r * 128 + c8 + 7] + rp[7];
        *(float4*)op = o0; *(float4*)(op + 4) = o1;
    }
}

// ---------------- radix-4 Stockham FFT-4096, 1024 threads ----------------
#define FIDX(a) ((a) + ((a) >> 4))

__device__ __forceinline__ float2 twget(const float2* __restrict__ tw, int a, float sgn) {
    float2 T = tw[a & 1023];
    int hi = (a >> 10) & 3;
    float cs = (hi & 1) ? ((hi & 2) ? T.y : -T.y) : ((hi & 2) ? -T.x : T.x);
    float sn = (hi & 1) ? ((hi & 2) ? -T.x : T.x) : ((hi & 2) ? -T.y : T.y);
    return make_float2(cs, sn * sgn);
}

__device__ void fft4096_r4(float2* __restrict__ b0, float2* __restrict__ b1,
                           const float2* __restrict__ tw, float sgn, int tid) {
    float2* cur = b0; float2* nxt = b1;
#pragma unroll
    for (int t = 0; t < 6; t++) {
        int s = 1 << (t << 1);
        int q = tid & (s - 1);
        int ps = tid - q;
        float2 a0 = cur[FIDX(tid)];
        float2 a1 = cur[FIDX(tid + 1024)];
        float2 a2 = cur[FIDX(tid + 2048)];
        float2 a3 = cur[FIDX(tid + 3072)];
        float t0x = a0.x + a2.x, t0y = a0.y + a2.y;
        float t1x = a0.x - a2.x, t1y = a0.y - a2.y;
        float t2x = a1.x + a3.x, t2y = a1.y + a3.y;
        float t3x = a1.x - a3.x, t3y = a1.y - a3.y;
        float it3x = -sgn * t3y, it3y = sgn * t3x;
        float2 A0 = make_float2(t0x + t2x, t0y + t2y);
        float2 A1 = make_float2(t1x + it3x, t1y + it3y);
        float2 A2 = make_float2(t0x - t2x, t0y - t2y);
        float2 A3 = make_float2(t1x - it3x, t1y - it3y);
        int ob = q + (ps << 2);
        nxt[FIDX(ob)] = A0;
        float2 w1 = twget(tw, ps, sgn);
        float2 w2 = twget(tw, ps * 2, sgn);
        float2 w3 = twget(tw, ps * 3, sgn);
        nxt[FIDX(ob + s)] = make_float2(A1.x * w1.x - A1.y * w1.y, A1.x * w1.y + A1.y * w1.x);
        nxt[FIDX(ob + 2 * s)] = make_float2(A2.x * w2.x - A2.y * w2.y, A2.x * w2.y + A2.y * w2.x);
        nxt[FIDX(ob + 3 * s)] = make_float2(A3.x * w3.x - A3.y * w3.y, A3.x * w3.y + A3.y * w3.x);
        __syncthreads();
        float2* tp = cur; cur = nxt; nxt = tp;
    }
}

// single pass: 8 channels/block over bf16 CTb[b][256][4096]; grid 512 = (b x 16 groups)
__global__ __launch_bounds__(1024) void kfft_fwd(const unsigned short* __restrict__ qkT,
                                                 float* __restrict__ Pws) {
    __shared__ float2 bufA[4352];
    __shared__ float2 bufB[4352];
    __shared__ float2 tw[1024];
    int tid = threadIdx.x;
    {
        float sn, cs;
        sincosf(1.5339807878856412e-3f * (float)tid, &sn, &cs);
        tw[tid] = make_float2(cs, sn);
    }
    int b = blockIdx.x >> 4;
    int g = blockIdx.x & 15;
    float2 pacc[4];
#pragma unroll
    for (int j = 0; j < 4; j++) pacc[j] = make_float2(0.f, 0.f);
    for (int c8 = 0; c8 < 8; c8++) {
        int c = g * 8 + c8;
        const unsigned short* qrow = qkT + ((size_t)(b * 256 + c)) * 4096;
        const unsigned short* krow = qkT + ((size_t)(b * 256 + 128 + c)) * 4096;
        __syncthreads();
        int i0 = tid * 4;
        short4v qv = *(const short4v*)(qrow + i0);
        short4v kv = *(const short4v*)(krow + i0);
        bufA[FIDX(i0)]     = make_float2(b2f((unsigned short)qv[0]), b2f((unsigned short)kv[0]));
        bufA[FIDX(i0 + 1)] = make_float2(b2f((unsigned short)qv[1]), b2f((unsigned short)kv[1]));
        bufA[FIDX(i0 + 2)] = make_float2(b2f((unsigned short)qv[2]), b2f((unsigned short)kv[2]));
        bufA[FIDX(i0 + 3)] = make_float2(b2f((unsigned short)qv[3]), b2f((unsigned short)kv[3]));
        __syncthreads();
        fft4096_r4(bufA, bufB, tw, -1.f, tid);
#pragma unroll
        for (int j = 0; j < 4; j++) {
            int f = tid + j * 1024;
            float2 Zf = bufA[FIDX(f)];
            float2 Zm = bufA[FIDX((4096 - f) & 4095)];
            float Qre = 0.5f * (Zf.x + Zm.x), Qim = 0.5f * (Zf.y - Zm.y);
            float Kre = 0.5f * (Zf.y + Zm.y), Kim = -0.5f * (Zf.x - Zm.x);
            pacc[j].x += Qre * Kre + Qim * Kim;
            pacc[j].y += Qim * Kre - Qre * Kim;
        }
    }
    float2* P = (float2*)Pws + (size_t)(b * 16 + g) * 4096;
#pragma unroll
    for (int j = 0; j < 4; j++) { int f = tid + j * 1024; P[f] = pacc[j]; }
}

// ---------------- presum the 16 P-slices at full BW (gg ascending, bit-identical) ----------------
__global__ __launch_bounds__(256) void kpsum(const float* __restrict__ Pws,
                                             float* __restrict__ Pr) {
    int t = blockIdx.x * 256 + threadIdx.x;      // 131072 float2 elements
    int b = t >> 12, i = t & 4095;
    const float2* P = (const float2*)Pws;
    float2 s = make_float2(0.f, 0.f);
#pragma unroll
    for (int gg = 0; gg < 16; gg++) {
        float2 v = P[((size_t)(b * 16 + gg)) * 4096 + i];
        s.x += v.x; s.y += v.y;
    }
    ((float2*)Pr)[(size_t)b * 4096 + i] = s;
}

__global__ __launch_bounds__(1024) void kfft_inv(const float* __restrict__ Prs,
                                                 float* __restrict__ meanv) {
    __shared__ float2 bufA[4352];
    __shared__ float2 bufB[4352];
    __shared__ float2 tw[1024];
    int tid = threadIdx.x;
    {
        float sn, cs;
        sincosf(1.5339807878856412e-3f * (float)tid, &sn, &cs);
        tw[tid] = make_float2(cs, sn);
    }
    int b = blockIdx.x;
    const float2* P = (const float2*)Prs + (size_t)b * 4096;
#pragma unroll
    for (int j = 0; j < 4; j++) {
        int i = tid + j * 1024;
        bufA[FIDX(i)] = P[i];
    }
    __syncthreads();
    fft4096_r4(bufA, bufB, tw, 1.f, tid);
    const float scale = 1.0f / (4096.0f * 128.0f);
#pragma unroll
    for (int j = 0; j < 4; j++) {
        int i = tid + j * 1024;
        meanv[b * 4096 + i] = bufA[FIDX(i)].x * scale;
    }
}

// ---------------- parallel column sum over batches (b ascending, bit-identical) ----------------
__global__ __launch_bounds__(256) void kcolsum(const float* __restrict__ meanv,
                                               float* __restrict__ cmg) {
    int c = blockIdx.x * 256 + threadIdx.x;
    float s = 0.f;
    for (int b = 0; b < 32; b++) s += meanv[b * 4096 + c];
    cmg[c] = s;
}

// ---------------- top-8 on presummed vector + per-batch softmax ----------------
__global__ __launch_bounds__(256) void ktopk2(const float* __restrict__ cmg,
                                              const float* __restrict__ meanv,
                                              int* __restrict__ idxout,
                                              float* __restrict__ tc) {
    __shared__ float cm[4096];
    __shared__ float rv[256];
    __shared__ int ri[256];
    __shared__ int sidx[8];
    for (int c = threadIdx.x; c < 4096; c += 256) cm[c] = cmg[c];
    __syncthreads();
    for (int it = 0; it < 8; it++) {
        float bv = -1e30f; int bi = 0;
        for (int c = threadIdx.x; c < 4096; c += 256) {
            float v = cm[c];
            if (v > bv) { bv = v; bi = c; }
        }
        rv[threadIdx.x] = bv; ri[threadIdx.x] = bi;
        __syncthreads();
        for (int off = 128; off > 0; off >>= 1) {
            if (threadIdx.x < off) {
                float v2 = rv[threadIdx.x + off]; int i2 = ri[threadIdx.x + off];
                if (v2 > rv[threadIdx.x] || (v2 == rv[threadIdx.x] && i2 < ri[threadIdx.x])) {
                    rv[threadIdx.x] = v2; ri[threadIdx.x] = i2;
                }
            }
            __syncthreads();
        }
        if (threadIdx.x == 0) { sidx[it] = ri[0]; idxout[it] = ri[0]; cm[ri[0]] = -1e30f; }
        __syncthreads();
    }
    if (threadIdx.x < 32) {
        int b = threadIdx.x;
        float w[8]; float mx = -1e30f;
#pragma unroll
        for (int i = 0; i < 8; i++) { w[i] = meanv[b * 4096 + sidx[i]]; mx = fmaxf(mx, w[i]); }
        float s = 0.f;
#pragma unroll
        for (int i = 0; i < 8; i++) { w[i] = expf(w[i] - mx); s += w[i]; }
#pragma unroll
        for (int i = 0; i < 8; i++) tc[b * 8 + i] = w[i] / s;
    }
}

// ---------------- series decomp: float4 rolling windows ----------------
__global__ __launch_bounds__(256) void kdecomp(const float* __restrict__ in,
                                               float* __restrict__ outp) {
    int b = blockIdx.x >> 4; int lc = blockIdx.x & 15;
    int dg = threadIdx.x & 31; int ls = threadIdx.x >> 5;
    int l0 = lc * 256 + ls * 32;
    const float* base = in + (size_t)b * 524288 + dg * 4;
    float* ob = outp + (size_t)b * 524288 + dg * 4;
    float sx = 0.f, sy = 0.f, sz = 0.f, sw = 0.f;
#pragma unroll
    for (int j = -12; j <= 12; j++) {
        int lj = l0 + j;
        lj = lj < 0 ? 0 : (lj > 4095 ? 4095 : lj);
        float4 v = *(const float4*)(base + (size_t)lj * 128);
        sx += v.x; sy += v.y; sz += v.z; sw += v.w;
    }
    for (int st = 0; st < 32; st++) {
        int l = l0 + st;
        float4 c = *(const float4*)(base + (size_t)l * 128);
        float4 o = make_float4(c.x - sx * (1.0f / 25.0f), c.y - sy * (1.0f / 25.0f),
                               c.z - sz * (1.0f / 25.0f), c.w - sw * (1.0f / 25.0f));
        *(float4*)(ob + (size_t)l * 128) = o;
        int ln = l + 13 > 4095 ? 4095 : l + 13;
        int lo2 = l - 12 < 0 ? 0 : l - 12;
        float4 vn = *(const float4*)(base + (size_t)ln * 128);
        float4 vo = *(const float4*)(base + (size_t)lo2 * 128);
        sx += vn.x - vo.x; sy += vn.y - vo.y; sz += vn.z - vo.z; sw += vn.w - vo.w;
    }
}

// ---------------- fused LayerNorm + column partial sums ----------------
__global__ __launch_bounds__(256) void kln_part1(float* __restrict__ h,
                                                 const float* __restrict__ g,
                                                 const float* __restrict__ bb,
                                                 float* __restrict__ part) {
    __shared__ float sh[4][128];
    int b = blockIdx.x >> 5;
    int sl = blockIdx.x & 31;
    int w = threadIdx.x >> 6;
    int lane = threadIdx.x & 63;
    float2 gv = *(const float2*)(g + lane * 2);
    float2 bv = *(const float2*)(bb + lane * 2);
    size_t r0 = (size_t)b * 4096 + sl * 128 + w * 32;
    float c0 = 0.f, c1 = 0.f;
    for (int i = 0; i < 32; i++) {
        float* p = h + (r0 + i) * 128 + lane * 2;
        float2 v = *(float2*)p;
        float s = v.x + v.y, s2 = v.x * v.x + v.y * v.y;
#pragma unroll
        for (int off = 32; off; off >>= 1) { s += __shfl_down(s, off); s2 += __shfl_down(s2, off); }
        s = __shfl(s, 0); s2 = __shfl(s2, 0);
        float mu = s * (1.f / 128.f);
        float var = s2 * (1.f / 128.f) - mu * mu;
        float inv = rsqrtf(var + 1e-5f);
        float o0 = (v.x - mu) * inv * gv.x + bv.x;
        float o1 = (v.y - mu) * inv * gv.y + bv.y;
        *(float2*)p = make_float2(o0, o1);
        c0 += o0; c1 += o1;
    }
    sh[w][lane * 2] = c0; sh[w][lane * 2 + 1] = c1;
    __syncthreads();
    if (threadIdx.x < 128) {
        int d = threadIdx.x;
        part[(size_t)(b * 32 + sl) * 128 + d] = sh[0][d] + sh[1][d] + sh[2][d] + sh[3][d];
    }
}

__global__ __launch_bounds__(128) void kpart2(const float* __restrict__ part,
                                              float* __restrict__ outm, int nq) {
    int b = blockIdx.x; int d = threadIdx.x;
    float s = 0.f;
    for (int q = 0; q < nq; q++) s += part[(size_t)(b * nq + q) * 128 + d];
    outm[b * 128 + d] = s * (1.f / 4096.f);
}

__global__ __launch_bounds__(256) void kgpart1(const float* __restrict__ h,
                                               const float* __restrict__ msum,
                                               float* __restrict__ part) {
    int b = blockIdx.x >> 3, sl = blockIdx.x & 7;
    int d = threadIdx.x & 127, p = threadIdx.x >> 7;
    const float* base = h + ((size_t)b * 4096 + sl * 512) * 128;
    float m = msum[b * 128 + d];
    float acc = 0.f;
    for (int l = p; l < 512; l += 2) acc += gelu_f(base[(size_t)l * 128 + d] - m);
    __shared__ float sh[256];
    sh[threadIdx.x] = acc; __syncthreads();
    if (p == 0) part[(size_t)(b * 8 + sl) * 128 + d] = acc + sh[128 + d];
}

__global__ __launch_bounds__(256) void khead(const float* __restrict__ gmean,
                                             const float* __restrict__ fc1w,
                                             const float* __restrict__ fc1b,
                                             const float* __restrict__ fc2w,
                                             const float* __restrict__ fc2b,
                                             float* __restrict__ outp) {
    __shared__ float h0[32][128];
    __shared__ float h1[32][128];
    int tid = threadIdx.x;
#pragma unroll
    for (int i = 0; i < 16; i++) {
        int e = tid + i * 256;
        h0[e >> 7][e & 127] = gmean[e];
    }
    __syncthreads();
#pragma unroll
    for (int i = 0; i < 16; i++) {
        int e = tid + i * 256; int b = e >> 7, j = e & 127;
        float s = fc1b[j];
        for (int d = 0; d < 128; d++) s += h0[b][d] * fc1w[j * 128 + d];
        h1[b][j] = fmaxf(s, 0.f);
    }
    __syncthreads();
    if (tid < 160) {
        int b = tid / 5, c2 = tid % 5;
        float s = fc2b[c2];
        for (int j = 0; j < 128; j++) s += h1[b][j] * fc2w[c2 * 128 + j];
        outp[b * 5 + c2] = s;
    }
}

extern "C" void kernel_launch(void* const* d_in, const int* in_sizes, int n_in,
                              void* d_out, int out_size, void* d_ws, size_t ws_size,
                              hipStream_t stream) {
    const float* x_enc  = (const float*)d_in[0];
    const float* emb_w  = (const float*)d_in[1];
    const float* attn_w = (const float*)d_in[2];
    const float* attn_b = (const float*)d_in[3];
    const float* ffn_w1 = (const float*)d_in[4];
    const float* ffn_w2 = (const float*)d_in[5];
    const float* norm_g = (const float*)d_in[6];
    const float* norm_b = (const float*)d_in[7];
    const float* fc1_w  = (const float*)d_in[8];
    const float* fc1_b  = (const float*)d_in[9];
    const float* fc2_w  = (const float*)d_in[10];
    const float* fc2_b  = (const float*)d_in[11];
    float* outp = (float*)d_out;

    float* W = (float*)d_ws;
    const size_t RD = (size_t)BATCH * L_SEQ * DM;       // 16,777,216
    float* buf0  = W;
    float* buf1  = W + RD;
    float* Pws   = W + 2 * RD;                          // 4,194,304 f
    float* meanv = Pws + (size_t)4194304;               // 131,072 (reused as LN partials in tail)
    float* tcb   = meanv + (size_t)131072;              // 256
    int*   idxb  = (int*)(tcb + 256);                   // 64 slots
    float* part  = tcb + 256 + 64;                      // 32,768
    float* msum  = part + 32768;                        // 4,096
    float* gsum  = msum + 4096;                         // 4,096
    unsigned short* w1img = (unsigned short*)(gsum + 4096);   // 2*65536
    unsigned short* w2img = w1img + (size_t)2 * 65536;        // 2*65536
    unsigned short* qkh   = w2img + (size_t)2 * 65536;        // 65536
    unsigned short* qkl   = qkh + (size_t)65536;              // 65536
    unsigned short* voimg = qkl + (size_t)65536;              // 65536
    float* cmg   = (float*)(voimg + (size_t)65536);           // 4,096
    float* Pr    = cmg + 4096;                                // 262,144 (presummed P)

    kembed<<<1024, 256, 0, stream>>>(x_enc, emb_w, buf0);
    kprepw<<<1536, 256, 0, stream>>>(ffn_w1, ffn_w2, attn_w, w1img, w2img, qkh, qkl, voimg);

    float* H = buf0;
    float* S = buf1;
    for (int l = 0; l < 2; l++) {
        const float* ab = attn_b + (size_t)l * 4 * 128;
        unsigned short* CTb = (unsigned short*)S;       // [b][256][4096] bf16
        kgemm_qkb<<<2048, 256, 0, stream>>>(H, qkh + (size_t)l * 32768,
                                            qkl + (size_t)l * 32768, ab, CTb);
        kfft_fwd<<<512, 1024, 0, stream>>>(CTb, Pws);
        kpsum<<<512, 256, 0, stream>>>(Pws, Pr);
        kfft_inv<<<32, 1024, 0, stream>>>(Pr, meanv);
        kcolsum<<<16, 256, 0, stream>>>(meanv, cmg);
        ktopk2<<<1, 256, 0, stream>>>(cmg, meanv, idxb, tcb);
        unsigned short* Vb = (unsigned short*)S;        // overwrites CTb (dead after fft_fwd)
        kgemm_mfma<0, 0><<<1024, 256, 0, stream>>>(H, voimg + (size_t)l * 32768, ab + 256,
                                                   nullptr, nullptr, nullptr, Vb);
        kgemm_mfma<2, 1><<<1024, 256, 0, stream>>>(Vb, voimg + (size_t)l * 32768 + 16384, ab + 384,
                                                   H, tcb, idxb, H);
        kdecomp<<<512, 256, 0, stream>>>(H, S);
        kffn_mfma<<<1024, 512, 0, stream>>>(S, w1img + (size_t)l * 65536,
                                            w2img + (size_t)l * 65536, H);
        kdecomp<<<512, 256, 0, stream>>>(H, S);
        float* t = H; H = S; S = t;
    }

    kln_part1<<<1024, 256, 0, stream>>>(H, norm_g, norm_b, meanv);
    kpart2<<<32, 128, 0, stream>>>(meanv, msum, 32);
    kgpart1<<<256, 256, 0, stream>>>(H, msum, part);
    kpart2<<<32, 128, 0, stream>>>(part, gsum, 8);
    khead<<<1, 256, 0, stream>>>(gsum, fc1_w, fc1_b, fc2_w, fc2_b, outp);
}

// Round 12
// 907.767 us; speedup vs baseline: 1.1654x; 1.0704x over previous
//
#include <hip/hip_runtime.h>
#include <math.h>

#define L_SEQ 4096
#define BATCH 32
#define DM 128

typedef short short8 __attribute__((ext_vector_type(8)));
typedef short short4v __attribute__((ext_vector_type(4)));
typedef float f32x4 __attribute__((ext_vector_type(4)));

__device__ __forceinline__ float gelu_f(float x) {
    return 0.5f * x * (1.0f + erff(x * 0.70710678118654752f));
}
__device__ __forceinline__ float gelu_fast(float x) {
    float ax = fabsf(x);
    if (ax < 1.0f) {
        float z = x * 0.70710678118654752f;
        float z2 = z * z;
        float p = 1.0f + z2 * (-0.333333333f + z2 * (0.1f + z2 * (-0.0238095238f +
                  z2 * (4.62962963e-3f + z2 * (-7.57575758e-4f)))));
        return 0.5f * x * (1.0f + 1.1283791670955126f * z * p);
    }
    return 0.5f * x * (1.0f + erff(x * 0.70710678118654752f));
}
__device__ __forceinline__ unsigned short f2b(float f) {
    unsigned u = __float_as_uint(f);
    u += 0x7fffu + ((u >> 16) & 1u);
    return (unsigned short)(u >> 16);
}
__device__ __forceinline__ float b2f(unsigned short h) {
    return __uint_as_float(((unsigned)h) << 16);
}

// ---------------- conv1d embedding: LDS-staged, weight-in-register ----------------
__global__ __launch_bounds__(256) void kembed(const float* __restrict__ x,
                                              const float* __restrict__ w,
                                              float* __restrict__ h) {
    __shared__ float xs[130][12];
    __shared__ float wsm[128][37];
    int b = blockIdx.x >> 5;
    int lt = blockIdx.x & 31;
    int l0 = lt * 128;
    int tid = threadIdx.x;
    for (int i = tid; i < 130 * 12; i += 256) {
        int r = i / 12, c = i - r * 12;
        int gl = (l0 - 1 + r + 4096) & 4095;
        xs[r][c] = x[((size_t)b * 4096 + gl) * 12 + c];
    }
    for (int i = tid; i < 128 * 36; i += 256) {
        int o = i / 36, j = i - o * 36;
        wsm[o][j] = w[i];
    }
    __syncthreads();
    int o = tid & 127, lh = tid >> 7;
    float wr[36];
#pragma unroll
    for (int j = 0; j < 36; j++) wr[j] = wsm[o][j];
    int base_r = lh * 64;
    float ring[4][12];
#pragma unroll
    for (int c = 0; c < 12; c++) { ring[0][c] = xs[base_r][c]; ring[1][c] = xs[base_r + 1][c]; }
    float* hp = h + ((size_t)b * 4096 + l0 + lh * 64) * 128 + o;
#pragma unroll 4
    for (int st = 0; st < 64; st++) {
        int s0 = st & 3, s1 = (st + 1) & 3, s2 = (st + 2) & 3;
#pragma unroll
        for (int c = 0; c < 12; c++) ring[s2][c] = xs[base_r + st + 2][c];
        float s = 0.f;
#pragma unroll
        for (int c = 0; c < 12; c++)
            s += wr[c * 3 + 0] * ring[s0][c] + wr[c * 3 + 1] * ring[s1][c] + wr[c * 3 + 2] * ring[s2][c];
        hp[(size_t)st * 128] = s;
    }
}

// ---------------- weight prep: bf16 pre-swizzled images ----------------
__global__ __launch_bounds__(256) void kprepw(const float* __restrict__ w1,
                                              const float* __restrict__ w2,
                                              const float* __restrict__ attn_w,
                                              unsigned short* __restrict__ w1img,
                                              unsigned short* __restrict__ w2img,
                                              unsigned short* __restrict__ qkh,
                                              unsigned short* __restrict__ qkl,
                                              unsigned short* __restrict__ voimg) {
    int t = blockIdx.x * 256 + threadIdx.x;
    if (t < 262144) {
        int layer = t >> 17; int rem = t & 131071;
        if (rem < 65536) {
            int R = rem >> 7, x = rem & 127;
            int g = x >> 3, j = x & 7;
            int srcc = ((g ^ (R & 7)) << 3) + j;
            w1img[(size_t)layer * 65536 + rem] = f2b(w1[(size_t)layer * 65536 + R * 128 + srcc]);
        } else {
            int r2 = rem - 65536;
            int c = r2 >> 13; int D = (r2 >> 6) & 127; int x = r2 & 63;
            int g = x >> 3, j = x & 7;
            int srcf = c * 64 + ((g ^ (D & 7)) << 3) + j;
            w2img[(size_t)layer * 65536 + r2] = f2b(w2[(size_t)layer * 65536 + D * 512 + srcf]);
        }
    } else if (t < 327680) {
        int t2 = t - 262144;
        int layer = t2 >> 15; int rem = t2 & 32767;
        int y = rem >> 14; int rem2 = rem & 16383;
        int r64 = rem2 >> 7; int x = rem2 & 127;
        int r = r64 & 63;
        int g = x >> 3, j = x & 7;
        int srcc = ((g ^ (r & 7)) << 3) + j;
        float v = attn_w[(size_t)layer * 65536 + y * 16384 + r64 * 128 + srcc];
        unsigned short hh = f2b(v);
        qkh[t2] = hh;
        qkl[t2] = f2b(v - b2f(hh));
    } else {
        int t3 = t - 327680;
        int layer = t3 >> 15; int rem = t3 & 32767;
        int mat = rem >> 14; int rem2 = rem & 16383;
        int r = rem2 >> 7; int x = rem2 & 127;
        int g = x >> 3, j = x & 7;
        int srcc = ((g ^ (r & 7)) << 3) + j;
        voimg[t3] = f2b(attn_w[(size_t)layer * 65536 + (2 + mat) * 16384 + r * 128 + srcc]);
    }
}

// ---- merged q+k projection: A staged ONCE, 4 roles looped; bf16 out CTb[b][256][4096] ----
__global__ __launch_bounds__(256, 2) void kgemm_qkb(const float* __restrict__ A,
                                                    const unsigned short* __restrict__ qkh,
                                                    const unsigned short* __restrict__ qkl,
                                                    const float* __restrict__ ab,
                                                    unsigned short* __restrict__ CTb) {
    __shared__ __align__(16) char smem[65536];
    short* Ah = (short*)smem;                 // [64][128]
    short* Al = (short*)(smem + 16384);
    short* Wh = (short*)(smem + 32768);
    short* Wl = (short*)(smem + 49152);
    float* Dsh = (float*)(smem + 32768);      // [64][68] overlays Wh/Wl
    int row0i = blockIdx.x * 64;
    int tid = threadIdx.x;
#pragma unroll
    for (int u = 0; u < 4; u++) {
        int task = tid + u * 256;
        int r = task >> 4, cg = task & 15;
        int dst = r * 128 + ((cg ^ (r & 7)) << 3);
        const float* src = A + ((size_t)(row0i + r)) * 128 + cg * 8;
        float4 xa = *(const float4*)src, ya = *(const float4*)(src + 4);
        float av[8] = {xa.x, xa.y, xa.z, xa.w, ya.x, ya.y, ya.z, ya.w};
        short8 hi, lo;
#pragma unroll
        for (int j = 0; j < 8; j++) {
            unsigned short hh = f2b(av[j]);
            hi[j] = (short)hh; lo[j] = (short)f2b(av[j] - b2f(hh));
        }
        *(short8*)(Ah + dst) = hi; *(short8*)(Al + dst) = lo;
    }
    int l = tid & 63; int w = tid >> 6; int wm = w >> 1, wn = w & 1;
    int b = row0i >> 12; int l0 = row0i & 4095;
    for (int role = 0; role < 4; role++) {
        int y = role >> 1, half = role & 1;
        const unsigned short* wh = qkh + y * 16384 + half * 8192;
        const unsigned short* wl = qkl + y * 16384 + half * 8192;
        const float* bias = ab + y * 128 + half * 64;
        __syncthreads();                      // A ready (role 0) / prev Dsh reads done
#pragma unroll
        for (int u = 0; u < 4; u++) {
            int task = tid + u * 256;
            int lin = (task >> 4) * 128 + (task & 15) * 8;
            *(short8*)(Wh + lin) = *(const short8*)(wh + lin);
            *(short8*)(Wl + lin) = *(const short8*)(wl + lin);
        }
        __syncthreads();
        f32x4 acc[2][2];
#pragma unroll
        for (int i = 0; i < 2; i++)
#pragma unroll
            for (int j = 0; j < 2; j++) acc[i][j] = (f32x4){0.f, 0.f, 0.f, 0.f};
#pragma unroll
        for (int ks = 0; ks < 4; ks++) {
            int cg = ks * 4 + (l >> 4);
            short8 ah[2], al2[2], bh[2], bl[2];
#pragma unroll
            for (int mi = 0; mi < 2; mi++) {
                int rm = wm * 32 + mi * 16 + (l & 15);
                int off = rm * 128 + ((cg ^ (rm & 7)) << 3);
                ah[mi] = *(short8*)(Ah + off); al2[mi] = *(short8*)(Al + off);
            }
#pragma unroll
            for (int ni = 0; ni < 2; ni++) {
                int rn = wn * 32 + ni * 16 + (l & 15);
                int off = rn * 128 + ((cg ^ (rn & 7)) << 3);
                bh[ni] = *(short8*)(Wh + off); bl[ni] = *(short8*)(Wl + off);
            }
#pragma unroll
            for (int mi = 0; mi < 2; mi++)
#pragma unroll
                for (int ni = 0; ni < 2; ni++) {
                    acc[mi][ni] = __builtin_amdgcn_mfma_f32_16x16x32_bf16(ah[mi], bh[ni], acc[mi][ni], 0, 0, 0);
                    acc[mi][ni] = __builtin_amdgcn_mfma_f32_16x16x32_bf16(ah[mi], bl[ni], acc[mi][ni], 0, 0, 0);
                    acc[mi][ni] = __builtin_amdgcn_mfma_f32_16x16x32_bf16(al2[mi], bh[ni], acc[mi][ni], 0, 0, 0);
                }
        }
        __syncthreads();                      // W reads done; Dsh region free
#pragma unroll
        for (int mi = 0; mi < 2; mi++)
#pragma unroll
            for (int ni = 0; ni < 2; ni++)
#pragma unroll
                for (int rr = 0; rr < 4; rr++) {
                    int m = wm * 32 + mi * 16 + (l >> 4) * 4 + rr;
                    int n = wn * 32 + ni * 16 + (l & 15);
                    Dsh[n * 68 + m] = acc[mi][ni][rr] + bias[n];
                }
        __syncthreads();
        int cb = y * 128 + half * 64;
#pragma unroll
        for (int u = 0; u < 4; u++) {
            int task = tid + u * 256;
            int c = task >> 4, m4 = (task & 15) * 4;
            float4 v = *(float4*)&Dsh[c * 68 + m4];
            short4v o;
            o[0] = (short)f2b(v.x); o[1] = (short)f2b(v.y);
            o[2] = (short)f2b(v.z); o[3] = (short)f2b(v.w);
            *(short4v*)&CTb[((size_t)(b * 256 + cb + c)) * 4096 + l0 + m4] = o;
        }
    }
}

// ---------------- MFMA bf16 GEMM (v-proj / fused agg+o-proj), W from image ----------------
template <int AT, int EPI>
__global__ __launch_bounds__(256, 2) void kgemm_mfma(const void* __restrict__ Ap,
                                                     const unsigned short* __restrict__ Wimg,
                                                     const float* __restrict__ bias,
                                                     const float* __restrict__ res,
                                                     const float* __restrict__ tcb,
                                                     const int* __restrict__ idxb,
                                                     void* __restrict__ outp) {
    __shared__ __align__(16) char smem[65536];
    short* As = (short*)smem;
    short* Ws = (short*)(smem + 32768);
    int tid = threadIdx.x;
    size_t row0;
    if (AT == 2) {
        int B = blockIdx.x;
        int cls = B & 7, j = B >> 3;
        int bq = cls + 8 * (j >> 5);
        int t = j & 31;
        row0 = ((size_t)bq * 32 + t) * 128;
    } else {
        row0 = (size_t)blockIdx.x * 128;
    }
#pragma unroll
    for (int u = 0; u < 8; u++) {
        int g = tid + u * 256;
        int r = g >> 4, cg = g & 15;
        int dsti = r * 128 + ((cg ^ (r & 7)) << 3);
        short8 v;
        if (AT == 0) {
            const float* src = (const float*)Ap + (row0 + r) * 128 + cg * 8;
            float4 x = *(const float4*)src, y = *(const float4*)(src + 4);
            v[0] = f2b(x.x); v[1] = f2b(x.y); v[2] = f2b(x.z); v[3] = f2b(x.w);
            v[4] = f2b(y.x); v[5] = f2b(y.y); v[6] = f2b(y.z); v[7] = f2b(y.w);
        } else {
            const unsigned short* Vb = (const unsigned short*)Ap;
            int b = (int)(row0 >> 12);
            int l0 = (int)(row0 & 4095);
            float accv[8];
#pragma unroll
            for (int j = 0; j < 8; j++) accv[j] = 0.f;
#pragma unroll
            for (int i = 0; i < 8; i++) {
                float wgt = tcb[b * 8 + i];
                int lr = (l0 + r + idxb[i]) & 4095;
                short8 vv = *(const short8*)(Vb + ((size_t)(b * 4096 + lr)) * 128 + cg * 8);
#pragma unroll
                for (int j = 0; j < 8; j++) accv[j] += wgt * b2f((unsigned short)vv[j]);
            }
#pragma unroll
            for (int j = 0; j < 8; j++) v[j] = (short)f2b(accv[j]);
        }
        *(short8*)(As + dsti) = v;
        int lin = r * 128 + cg * 8;
        *(short8*)(Ws + lin) = *(const short8*)(Wimg + lin);
    }
    __syncthreads();
    int l = tid & 63; int w = tid >> 6; int wm = w >> 1, wn = w & 1;
    f32x4 acc[4][4];
#pragma unroll
    for (int i = 0; i < 4; i++)
#pragma unroll
        for (int j = 0; j < 4; j++) acc[i][j] = (f32x4){0.f, 0.f, 0.f, 0.f};
#pragma unroll
    for (int ks = 0; ks < 4; ks++) {
        int cg = ks * 4 + (l >> 4);
        short8 af[4], bf[4];
#pragma unroll
        for (int mi = 0; mi < 4; mi++) {
            int rm = wm * 64 + mi * 16 + (l & 15);
            af[mi] = *(short8*)(As + rm * 128 + ((cg ^ (rm & 7)) << 3));
        }
#pragma unroll
        for (int ni = 0; ni < 4; ni++) {
            int rn = wn * 64 + ni * 16 + (l & 15);
            bf[ni] = *(short8*)(Ws + rn * 128 + ((cg ^ (rn & 7)) << 3));
        }
#pragma unroll
        for (int mi = 0; mi < 4; mi++)
#pragma unroll
            for (int ni = 0; ni < 4; ni++)
                acc[mi][ni] = __builtin_amdgcn_mfma_f32_16x16x32_bf16(af[mi], bf[ni], acc[mi][ni], 0, 0, 0);
    }
    __syncthreads();
    float* Dsh = (float*)smem;
#pragma unroll
    for (int mi = 0; mi < 4; mi++)
#pragma unroll
        for (int ni = 0; ni < 4; ni++)
#pragma unroll
            for (int rr = 0; rr < 4; rr++)
                Dsh[(wm * 64 + mi * 16 + (l >> 4) * 4 + rr) * 128 + wn * 64 + ni * 16 + (l & 15)] = acc[mi][ni][rr];
    __syncthreads();
#pragma unroll
    for (int u = 0; u < 8; u++) {
        int g = tid + u * 256;
        int r = g >> 4, c8 = (g & 15) * 8;
        float vv[8];
#pragma unroll
        for (int j = 0; j < 8; j++) vv[j] = Dsh[r * 128 + c8 + j] + bias[c8 + j];
        if (EPI == 1) {
            const float* rp = res + (row0 + r) * 128 + c8;
#pragma unroll
            for (int j = 0; j < 8; j++) vv[j] += rp[j];
            float* op = (float*)outp + (row0 + r) * 128 + c8;
            *(float4*)op = make_float4(vv[0], vv[1], vv[2], vv[3]);
            *(float4*)(op + 4) = make_float4(vv[4], vv[5], vv[6], vv[7]);
        } else {
            short8 ov;
#pragma unroll
            for (int j = 0; j < 8; j++) ov[j] = (short)f2b(vv[j]);
            *(short8*)((short*)outp + (row0 + r) * 128 + c8) = ov;
        }
    }
}

// ---------------- fused MFMA FFN: 512 threads (8 waves 2x4), 80 KB LDS, fb=64 chunks ----------------
__global__ __launch_bounds__(512, 4) void kffn_mfma(const float* __restrict__ xs,
                                                    const unsigned short* __restrict__ w1img,
                                                    const unsigned short* __restrict__ w2img,
                                                    float* __restrict__ outp) {
    __shared__ __align__(16) char smem[81920];
    short* xsl = (short*)smem;               // [128][128]  32K
    short* w1t = (short*)(smem + 32768);     // [64][128]   16K
    short* tt  = (short*)(smem + 49152);     // [128][64]   16K
    short* w2t = (short*)(smem + 65536);     // [128][64]   16K
    int tid = threadIdx.x;
    size_t row0 = (size_t)blockIdx.x * 128;
#pragma unroll
    for (int u = 0; u < 4; u++) {
        int g = tid + u * 512;
        int r = g >> 4, cg = g & 15;
        const float* src = xs + (row0 + r) * 128 + cg * 8;
        float4 x = *(const float4*)src, y = *(const float4*)(src + 4);
        short8 v;
        v[0] = f2b(x.x); v[1] = f2b(x.y); v[2] = f2b(x.z); v[3] = f2b(x.w);
        v[4] = f2b(y.x); v[5] = f2b(y.y); v[6] = f2b(y.z); v[7] = f2b(y.w);
        *(short8*)(xsl + r * 128 + ((cg ^ (r & 7)) << 3)) = v;
    }
    int l = tid & 63; int w = tid >> 6;      // 8 waves
    int wm = w >> 2, wn = w & 3;             // 2 x 4
    f32x4 acc2[4][2];
#pragma unroll
    for (int i = 0; i < 4; i++)
#pragma unroll
        for (int j = 0; j < 2; j++) acc2[i][j] = (f32x4){0.f, 0.f, 0.f, 0.f};
    for (int fb = 0; fb < 8; fb++) {
        __syncthreads();                       // BAR_A (first iter: xsl ready)
#pragma unroll
        for (int u = 0; u < 2; u++) {
            int task = tid + u * 512;
            int r = task >> 4, cg = task & 15;
            *(short8*)(w1t + r * 128 + cg * 8) =
                *(const short8*)(w1img + ((size_t)(fb * 64 + r)) * 128 + cg * 8);
            int r2 = task >> 3, cg2 = task & 7;
            *(short8*)(w2t + r2 * 64 + cg2 * 8) =
                *(const short8*)(w2img + ((size_t)(fb * 128 + r2)) * 64 + cg2 * 8);
        }
        __syncthreads();                       // BAR_B
        f32x4 a1[4];
#pragma unroll
        for (int i = 0; i < 4; i++) a1[i] = (f32x4){0.f, 0.f, 0.f, 0.f};
#pragma unroll
        for (int ks = 0; ks < 4; ks++) {
            int cg = ks * 4 + (l >> 4);
            short8 af[4], bf;
#pragma unroll
            for (int mi = 0; mi < 4; mi++) {
                int rm = wm * 64 + mi * 16 + (l & 15);
                af[mi] = *(short8*)(xsl + rm * 128 + ((cg ^ (rm & 7)) << 3));
            }
            {
                int rn = wn * 16 + (l & 15);
                bf = *(short8*)(w1t + rn * 128 + ((cg ^ (rn & 7)) << 3));
            }
#pragma unroll
            for (int mi = 0; mi < 4; mi++)
                a1[mi] = __builtin_amdgcn_mfma_f32_16x16x32_bf16(af[mi], bf, a1[mi], 0, 0, 0);
        }
#pragma unroll
        for (int mi = 0; mi < 4; mi++)
#pragma unroll
            for (int rr = 0; rr < 4; rr++) {
                int m = wm * 64 + mi * 16 + (l >> 4) * 4 + rr;
                int f = wn * 16 + (l & 15);
                tt[m * 64 + (((f >> 3) ^ (m & 7)) << 3) + (f & 7)] = (short)f2b(gelu_fast(a1[mi][rr]));
            }
        __syncthreads();                       // BAR_C
#pragma unroll
        for (int ks = 0; ks < 2; ks++) {
            int cg = ks * 4 + (l >> 4);
            short8 af[4], bf[2];
#pragma unroll
            for (int mi = 0; mi < 4; mi++) {
                int rm = wm * 64 + mi * 16 + (l & 15);
                af[mi] = *(short8*)(tt + rm * 64 + ((cg ^ (rm & 7)) << 3));
            }
#pragma unroll
            for (int ni = 0; ni < 2; ni++) {
                int rn = wn * 32 + ni * 16 + (l & 15);
                bf[ni] = *(short8*)(w2t + rn * 64 + ((cg ^ (rn & 7)) << 3));
            }
#pragma unroll
            for (int mi = 0; mi < 4; mi++)
#pragma unroll
                for (int ni = 0; ni < 2; ni++)
                    acc2[mi][ni] = __builtin_amdgcn_mfma_f32_16x16x32_bf16(af[mi], bf[ni], acc2[mi][ni], 0, 0, 0);
        }
    }
    __syncthreads();
    float* Dsh = (float*)smem;                 // [128][128] f32 over first 64KB
#pragma unroll
    for (int mi = 0; mi < 4; mi++)
#pragma unroll
        for (int ni = 0; ni < 2; ni++)
#pragma unroll
            for (int rr = 0; rr < 4; rr++)
                Dsh[(wm * 64 + mi * 16 + (l >> 4) * 4 + rr) * 128 + wn * 32 + ni * 16 + (l & 15)] = acc2[mi][ni][rr];
    __syncthreads();
#pragma unroll
    for (int u = 0; u < 4; u++) {
        int g = tid + u * 512;
        int r = g >> 4, c8 = (g & 15) * 8;
        const float* rp = xs + (row0 + r) * 128 + c8;
        float* op = outp + (row0 + r) * 128 + c8;
        float4 o0, o1;
        o0.x = Dsh[r * 128 + c8 + 0] + rp[0]; o0.y = Dsh[r * 128 + c8 + 1] + rp[1];
        o0.z = Dsh[r * 128 + c8 + 2] + rp[2]; o0.w = Dsh[r * 128 + c8 + 3] + rp[3];
        o1.x = Dsh[r * 128 + c8 + 4] + rp[4]; o1.y = Dsh[r * 128 + c8 + 5] + rp[5];
        o1.z = Dsh[r * 128 + c8 + 6] + rp[6]; o1.w = Dsh[r * 128 + c8 + 7] + rp[7];
        *(float4*)op = o0; *(float4*)(op + 4) = o1;
    }
}

// ---------------- radix-4 Stockham FFT-4096, 1024 threads ----------------
#define FIDX(a) ((a) + ((a) >> 4))

__device__ __forceinline__ float2 twget(const float2* __restrict__ tw, int a, float sgn) {
    float2 T = tw[a & 1023];
    int hi = (a >> 10) & 3;
    float cs = (hi & 1) ? ((hi & 2) ? T.y : -T.y) : ((hi & 2) ? -T.x : T.x);
    float sn = (hi & 1) ? ((hi & 2) ? -T.x : T.x) : ((hi & 2) ? -T.y : T.y);
    return make_float2(cs, sn * sgn);
}

__device__ void fft4096_r4(float2* __restrict__ b0, float2* __restrict__ b1,
                           const float2* __restrict__ tw, float sgn, int tid) {
    float2* cur = b0; float2* nxt = b1;
#pragma unroll
    for (int t = 0; t < 6; t++) {
        int s = 1 << (t << 1);
        int q = tid & (s - 1);
        int ps = tid - q;
        float2 a0 = cur[FIDX(tid)];
        float2 a1 = cur[FIDX(tid + 1024)];
        float2 a2 = cur[FIDX(tid + 2048)];
        float2 a3 = cur[FIDX(tid + 3072)];
        float t0x = a0.x + a2.x, t0y = a0.y + a2.y;
        float t1x = a0.x - a2.x, t1y = a0.y - a2.y;
        float t2x = a1.x + a3.x, t2y = a1.y + a3.y;
        float t3x = a1.x - a3.x, t3y = a1.y - a3.y;
        float it3x = -sgn * t3y, it3y = sgn * t3x;
        float2 A0 = make_float2(t0x + t2x, t0y + t2y);
        float2 A1 = make_float2(t1x + it3x, t1y + it3y);
        float2 A2 = make_float2(t0x - t2x, t0y - t2y);
        float2 A3 = make_float2(t1x - it3x, t1y - it3y);
        int ob = q + (ps << 2);
        nxt[FIDX(ob)] = A0;
        float2 w1 = twget(tw, ps, sgn);
        float2 w2 = twget(tw, ps * 2, sgn);
        float2 w3 = twget(tw, ps * 3, sgn);
        nxt[FIDX(ob + s)] = make_float2(A1.x * w1.x - A1.y * w1.y, A1.x * w1.y + A1.y * w1.x);
        nxt[FIDX(ob + 2 * s)] = make_float2(A2.x * w2.x - A2.y * w2.y, A2.x * w2.y + A2.y * w2.x);
        nxt[FIDX(ob + 3 * s)] = make_float2(A3.x * w3.x - A3.y * w3.y, A3.x * w3.y + A3.y * w3.x);
        __syncthreads();
        float2* tp = cur; cur = nxt; nxt = tp;
    }
}

// single pass: 8 channels/block over bf16 CTb[b][256][4096]; grid 512 = (b x 16 groups)
__global__ __launch_bounds__(1024) void kfft_fwd(const unsigned short* __restrict__ qkT,
                                                 float* __restrict__ Pws) {
    __shared__ float2 bufA[4352];
    __shared__ float2 bufB[4352];
    __shared__ float2 tw[1024];
    int tid = threadIdx.x;
    {
        float sn, cs;
        sincosf(1.5339807878856412e-3f * (float)tid, &sn, &cs);
        tw[tid] = make_float2(cs, sn);
    }
    int b = blockIdx.x >> 4;
    int g = blockIdx.x & 15;
    float2 pacc[4];
#pragma unroll
    for (int j = 0; j < 4; j++) pacc[j] = make_float2(0.f, 0.f);
    for (int c8 = 0; c8 < 8; c8++) {
        int c = g * 8 + c8;
        const unsigned short* qrow = qkT + ((size_t)(b * 256 + c)) * 4096;
        const unsigned short* krow = qkT + ((size_t)(b * 256 + 128 + c)) * 4096;
        __syncthreads();
        int i0 = tid * 4;
        short4v qv = *(const short4v*)(qrow + i0);
        short4v kv = *(const short4v*)(krow + i0);
        bufA[FIDX(i0)]     = make_float2(b2f((unsigned short)qv[0]), b2f((unsigned short)kv[0]));
        bufA[FIDX(i0 + 1)] = make_float2(b2f((unsigned short)qv[1]), b2f((unsigned short)kv[1]));
        bufA[FIDX(i0 + 2)] = make_float2(b2f((unsigned short)qv[2]), b2f((unsigned short)kv[2]));
        bufA[FIDX(i0 + 3)] = make_float2(b2f((unsigned short)qv[3]), b2f((unsigned short)kv[3]));
        __syncthreads();
        fft4096_r4(bufA, bufB, tw, -1.f, tid);
#pragma unroll
        for (int j = 0; j < 4; j++) {
            int f = tid + j * 1024;
            float2 Zf = bufA[FIDX(f)];
            float2 Zm = bufA[FIDX((4096 - f) & 4095)];
            float Qre = 0.5f * (Zf.x + Zm.x), Qim = 0.5f * (Zf.y - Zm.y);
            float Kre = 0.5f * (Zf.y + Zm.y), Kim = -0.5f * (Zf.x - Zm.x);
            pacc[j].x += Qre * Kre + Qim * Kim;
            pacc[j].y += Qim * Kre - Qre * Kim;
        }
    }
    float2* P = (float2*)Pws + (size_t)(b * 16 + g) * 4096;
#pragma unroll
    for (int j = 0; j < 4; j++) { int f = tid + j * 1024; P[f] = pacc[j]; }
}

// ---------------- presum the 16 P-slices at full BW (gg ascending, bit-identical) ----------------
__global__ __launch_bounds__(256) void kpsum(const float* __restrict__ Pws,
                                             float* __restrict__ Pr) {
    int t = blockIdx.x * 256 + threadIdx.x;      // 131072 float2 elements
    int b = t >> 12, i = t & 4095;
    const float2* P = (const float2*)Pws;
    float2 s = make_float2(0.f, 0.f);
#pragma unroll
    for (int gg = 0; gg < 16; gg++) {
        float2 v = P[((size_t)(b * 16 + gg)) * 4096 + i];
        s.x += v.x; s.y += v.y;
    }
    ((float2*)Pr)[(size_t)b * 4096 + i] = s;
}

__global__ __launch_bounds__(1024) void kfft_inv(const float* __restrict__ Prs,
                                                 float* __restrict__ meanv) {
    __shared__ float2 bufA[4352];
    __shared__ float2 bufB[4352];
    __shared__ float2 tw[1024];
    int tid = threadIdx.x;
    {
        float sn, cs;
        sincosf(1.5339807878856412e-3f * (float)tid, &sn, &cs);
        tw[tid] = make_float2(cs, sn);
    }
    int b = blockIdx.x;
    const float2* P = (const float2*)Prs + (size_t)b * 4096;
#pragma unroll
    for (int j = 0; j < 4; j++) {
        int i = tid + j * 1024;
        bufA[FIDX(i)] = P[i];
    }
    __syncthreads();
    fft4096_r4(bufA, bufB, tw, 1.f, tid);
    const float scale = 1.0f / (4096.0f * 128.0f);
#pragma unroll
    for (int j = 0; j < 4; j++) {
        int i = tid + j * 1024;
        meanv[b * 4096 + i] = bufA[FIDX(i)].x * scale;
    }
}

// ---------------- parallel column sum over batches (b ascending, bit-identical) ----------------
__global__ __launch_bounds__(256) void kcolsum(const float* __restrict__ meanv,
                                               float* __restrict__ cmg) {
    int c = blockIdx.x * 256 + threadIdx.x;
    float s = 0.f;
    for (int b = 0; b < 32; b++) s += meanv[b * 4096 + c];
    cmg[c] = s;
}

// ---------------- top-8 on presummed vector + per-batch softmax ----------------
__global__ __launch_bounds__(256) void ktopk2(const float* __restrict__ cmg,
                                              const float* __restrict__ meanv,
                                              int* __restrict__ idxout,
                                              float* __restrict__ tc) {
    __shared__ float cm[4096];
    __shared__ float rv[256];
    __shared__ int ri[256];
    __shared__ int sidx[8];
    for (int c = threadIdx.x; c < 4096; c += 256) cm[c] = cmg[c];
    __syncthreads();
    for (int it = 0; it < 8; it++) {
        float bv = -1e30f; int bi = 0;
        for (int c = threadIdx.x; c < 4096; c += 256) {
            float v = cm[c];
            if (v > bv) { bv = v; bi = c; }
        }
        rv[threadIdx.x] = bv; ri[threadIdx.x] = bi;
        __syncthreads();
        for (int off = 128; off > 0; off >>= 1) {
            if (threadIdx.x < off) {
                float v2 = rv[threadIdx.x + off]; int i2 = ri[threadIdx.x + off];
                if (v2 > rv[threadIdx.x] || (v2 == rv[threadIdx.x] && i2 < ri[threadIdx.x])) {
                    rv[threadIdx.x] = v2; ri[threadIdx.x] = i2;
                }
            }
            __syncthreads();
        }
        if (threadIdx.x == 0) { sidx[it] = ri[0]; idxout[it] = ri[0]; cm[ri[0]] = -1e30f; }
        __syncthreads();
    }
    if (threadIdx.x < 32) {
        int b = threadIdx.x;
        float w[8]; float mx = -1e30f;
#pragma unroll
        for (int i = 0; i < 8; i++) { w[i] = meanv[b * 4096 + sidx[i]]; mx = fmaxf(mx, w[i]); }
        float s = 0.f;
#pragma unroll
        for (int i = 0; i < 8; i++) { w[i] = expf(w[i] - mx); s += w[i]; }
#pragma unroll
        for (int i = 0; i < 8; i++) tc[b * 8 + i] = w[i] / s;
    }
}

// ---------------- series decomp: float4 rolling windows ----------------
__global__ __launch_bounds__(256) void kdecomp(const float* __restrict__ in,
                                               float* __restrict__ outp) {
    int b = blockIdx.x >> 4; int lc = blockIdx.x & 15;
    int dg = threadIdx.x & 31; int ls = threadIdx.x >> 5;
    int l0 = lc * 256 + ls * 32;
    const float* base = in + (size_t)b * 524288 + dg * 4;
    float* ob = outp + (size_t)b * 524288 + dg * 4;
    float sx = 0.f, sy = 0.f, sz = 0.f, sw = 0.f;
#pragma unroll
    for (int j = -12; j <= 12; j++) {
        int lj = l0 + j;
        lj = lj < 0 ? 0 : (lj > 4095 ? 4095 : lj);
        float4 v = *(const float4*)(base + (size_t)lj * 128);
        sx += v.x; sy += v.y; sz += v.z; sw += v.w;
    }
    for (int st = 0; st < 32; st++) {
        int l = l0 + st;
        float4 c = *(const float4*)(base + (size_t)l * 128);
        float4 o = make_float4(c.x - sx * (1.0f / 25.0f), c.y - sy * (1.0f / 25.0f),
                               c.z - sz * (1.0f / 25.0f), c.w - sw * (1.0f / 25.0f));
        *(float4*)(ob + (size_t)l * 128) = o;
        int ln = l + 13 > 4095 ? 4095 : l + 13;
        int lo2 = l - 12 < 0 ? 0 : l - 12;
        float4 vn = *(const float4*)(base + (size_t)ln * 128);
        float4 vo = *(const float4*)(base + (size_t)lo2 * 128);
        sx += vn.x - vo.x; sy += vn.y - vo.y; sz += vn.z - vo.z; sw += vn.w - vo.w;
    }
}

// ---------------- fused LayerNorm + column partial sums ----------------
__global__ __launch_bounds__(256) void kln_part1(float* __restrict__ h,
                                                 const float* __restrict__ g,
                                                 const float* __restrict__ bb,
                                                 float* __restrict__ part) {
    __shared__ float sh[4][128];
    int b = blockIdx.x >> 5;
    int sl = blockIdx.x & 31;
    int w = threadIdx.x >> 6;
    int lane = threadIdx.x & 63;
    float2 gv = *(const float2*)(g + lane * 2);
    float2 bv = *(const float2*)(bb + lane * 2);
    size_t r0 = (size_t)b * 4096 + sl * 128 + w * 32;
    float c0 = 0.f, c1 = 0.f;
    for (int i = 0; i < 32; i++) {
        float* p = h + (r0 + i) * 128 + lane * 2;
        float2 v = *(float2*)p;
        float s = v.x + v.y, s2 = v.x * v.x + v.y * v.y;
#pragma unroll
        for (int off = 32; off; off >>= 1) { s += __shfl_down(s, off); s2 += __shfl_down(s2, off); }
        s = __shfl(s, 0); s2 = __shfl(s2, 0);
        float mu = s * (1.f / 128.f);
        float var = s2 * (1.f / 128.f) - mu * mu;
        float inv = rsqrtf(var + 1e-5f);
        float o0 = (v.x - mu) * inv * gv.x + bv.x;
        float o1 = (v.y - mu) * inv * gv.y + bv.y;
        *(float2*)p = make_float2(o0, o1);
        c0 += o0; c1 += o1;
    }
    sh[w][lane * 2] = c0; sh[w][lane * 2 + 1] = c1;
    __syncthreads();
    if (threadIdx.x < 128) {
        int d = threadIdx.x;
        part[(size_t)(b * 32 + sl) * 128 + d] = sh[0][d] + sh[1][d] + sh[2][d] + sh[3][d];
    }
}

__global__ __launch_bounds__(128) void kpart2(const float* __restrict__ part,
                                              float* __restrict__ outm, int nq) {
    int b = blockIdx.x; int d = threadIdx.x;
    float s = 0.f;
    for (int q = 0; q < nq; q++) s += part[(size_t)(b * nq + q) * 128 + d];
    outm[b * 128 + d] = s * (1.f / 4096.f);
}

// ---------------- gelu(h - colmean) partials: 2048 blocks, float4, gelu_fast ----------------
__global__ __launch_bounds__(256) void kgpart1(const float* __restrict__ h,
                                               const float* __restrict__ msum,
                                               float* __restrict__ part) {
    __shared__ float sh[8][128];
    int b = blockIdx.x >> 6, sl = blockIdx.x & 63;
    int d4 = threadIdx.x & 31, p = threadIdx.x >> 5;
    const float* base = h + ((size_t)b * 4096 + sl * 64) * 128 + d4 * 4;
    float4 m = *(const float4*)(msum + b * 128 + d4 * 4);
    float ax = 0.f, ay = 0.f, az = 0.f, aw = 0.f;
    for (int l = p; l < 64; l += 8) {
        float4 v = *(const float4*)(base + (size_t)l * 128);
        ax += gelu_fast(v.x - m.x); ay += gelu_fast(v.y - m.y);
        az += gelu_fast(v.z - m.z); aw += gelu_fast(v.w - m.w);
    }
    sh[p][d4 * 4 + 0] = ax; sh[p][d4 * 4 + 1] = ay;
    sh[p][d4 * 4 + 2] = az; sh[p][d4 * 4 + 3] = aw;
    __syncthreads();
    if (threadIdx.x < 128) {
        int d = threadIdx.x;
        float s = 0.f;
#pragma unroll
        for (int q = 0; q < 8; q++) s += sh[q][d];
        part[(size_t)(b * 64 + sl) * 128 + d] = s;
    }
}

__global__ __launch_bounds__(256) void khead(const float* __restrict__ gmean,
                                             const float* __restrict__ fc1w,
                                             const float* __restrict__ fc1b,
                                             const float* __restrict__ fc2w,
                                             const float* __restrict__ fc2b,
                                             float* __restrict__ outp) {
    __shared__ float h0[32][128];
    __shared__ float h1[32][128];
    int tid = threadIdx.x;
#pragma unroll
    for (int i = 0; i < 16; i++) {
        int e = tid + i * 256;
        h0[e >> 7][e & 127] = gmean[e];
    }
    __syncthreads();
#pragma unroll
    for (int i = 0; i < 16; i++) {
        int e = tid + i * 256; int b = e >> 7, j = e & 127;
        float s = fc1b[j];
        for (int d = 0; d < 128; d++) s += h0[b][d] * fc1w[j * 128 + d];
        h1[b][j] = fmaxf(s, 0.f);
    }
    __syncthreads();
    if (tid < 160) {
        int b = tid / 5, c2 = tid % 5;
        float s = fc2b[c2];
        for (int j = 0; j < 128; j++) s += h1[b][j] * fc2w[c2 * 128 + j];
        outp[b * 5 + c2] = s;
    }
}

extern "C" void kernel_launch(void* const* d_in, const int* in_sizes, int n_in,
                              void* d_out, int out_size, void* d_ws, size_t ws_size,
                              hipStream_t stream) {
    const float* x_enc  = (const float*)d_in[0];
    const float* emb_w  = (const float*)d_in[1];
    const float* attn_w = (const float*)d_in[2];
    const float* attn_b = (const float*)d_in[3];
    const float* ffn_w1 = (const float*)d_in[4];
    const float* ffn_w2 = (const float*)d_in[5];
    const float* norm_g = (const float*)d_in[6];
    const float* norm_b = (const float*)d_in[7];
    const float* fc1_w  = (const float*)d_in[8];
    const float* fc1_b  = (const float*)d_in[9];
    const float* fc2_w  = (const float*)d_in[10];
    const float* fc2_b  = (const float*)d_in[11];
    float* outp = (float*)d_out;

    float* W = (float*)d_ws;
    const size_t RD = (size_t)BATCH * L_SEQ * DM;       // 16,777,216
    float* buf0  = W;
    float* buf1  = W + RD;
    float* Pws   = W + 2 * RD;                          // 4,194,304 f
    float* meanv = Pws + (size_t)4194304;               // 131,072 (reused as LN partials in tail)
    float* tcb   = meanv + (size_t)131072;              // 256
    int*   idxb  = (int*)(tcb + 256);                   // 64 slots
    float* part  = tcb + 256 + 64;                      // 32,768
    float* msum  = part + 32768;                        // 4,096
    float* gsum  = msum + 4096;                         // 4,096
    unsigned short* w1img = (unsigned short*)(gsum + 4096);   // 2*65536
    unsigned short* w2img = w1img + (size_t)2 * 65536;        // 2*65536
    unsigned short* qkh   = w2img + (size_t)2 * 65536;        // 65536
    unsigned short* qkl   = qkh + (size_t)65536;              // 65536
    unsigned short* voimg = qkl + (size_t)65536;              // 65536
    float* cmg   = (float*)(voimg + (size_t)65536);           // 4,096
    float* Pr    = cmg + 4096;                                // 262,144 (presummed P / gelu partials)

    kembed<<<1024, 256, 0, stream>>>(x_enc, emb_w, buf0);
    kprepw<<<1536, 256, 0, stream>>>(ffn_w1, ffn_w2, attn_w, w1img, w2img, qkh, qkl, voimg);

    float* H = buf0;
    float* S = buf1;
    for (int l = 0; l < 2; l++) {
        const float* ab = attn_b + (size_t)l * 4 * 128;
        unsigned short* CTb = (unsigned short*)S;       // [b][256][4096] bf16
        kgemm_qkb<<<2048, 256, 0, stream>>>(H, qkh + (size_t)l * 32768,
                                            qkl + (size_t)l * 32768, ab, CTb);
        kfft_fwd<<<512, 1024, 0, stream>>>(CTb, Pws);
        kpsum<<<512, 256, 0, stream>>>(Pws, Pr);
        kfft_inv<<<32, 1024, 0, stream>>>(Pr, meanv);
        kcolsum<<<16, 256, 0, stream>>>(meanv, cmg);
        ktopk2<<<1, 256, 0, stream>>>(cmg, meanv, idxb, tcb);
        unsigned short* Vb = (unsigned short*)S;        // overwrites CTb (dead after fft_fwd)
        kgemm_mfma<0, 0><<<1024, 256, 0, stream>>>(H, voimg + (size_t)l * 32768, ab + 256,
                                                   nullptr, nullptr, nullptr, Vb);
        kgemm_mfma<2, 1><<<1024, 256, 0, stream>>>(Vb, voimg + (size_t)l * 32768 + 16384, ab + 384,
                                                   H, tcb, idxb, H);
        kdecomp<<<512, 256, 0, stream>>>(H, S);
        kffn_mfma<<<1024, 512, 0, stream>>>(S, w1img + (size_t)l * 65536,
                                            w2img + (size_t)l * 65536, H);
        kdecomp<<<512, 256, 0, stream>>>(H, S);
        float* t = H; H = S; S = t;
    }

    kln_part1<<<1024, 256, 0, stream>>>(H, norm_g, norm_b, meanv);
    kpart2<<<32, 128, 0, stream>>>(meanv, msum, 32);
    kgpart1<<<2048, 256, 0, stream>>>(H, msum, Pr);
    kpart2<<<32, 128, 0, stream>>>(Pr, gsum, 64);
    khead<<<1, 256, 0, stream>>>(gsum, fc1_w, fc1_b, fc2_w, fc2_b, outp);
}

// Round 13
// 903.293 us; speedup vs baseline: 1.1711x; 1.0050x over previous
//
#include <hip/hip_runtime.h>
#include <math.h>

#define L_SEQ 4096
#define BATCH 32
#define DM 128

typedef short short8 __attribute__((ext_vector_type(8)));
typedef short short4v __attribute__((ext_vector_type(4)));
typedef float f32x4 __attribute__((ext_vector_type(4)));

__device__ __forceinline__ float gelu_f(float x) {
    return 0.5f * x * (1.0f + erff(x * 0.70710678118654752f));
}
__device__ __forceinline__ float gelu_fast(float x) {
    float ax = fabsf(x);
    if (ax < 1.0f) {
        float z = x * 0.70710678118654752f;
        float z2 = z * z;
        float p = 1.0f + z2 * (-0.333333333f + z2 * (0.1f + z2 * (-0.0238095238f +
                  z2 * (4.62962963e-3f + z2 * (-7.57575758e-4f)))));
        return 0.5f * x * (1.0f + 1.1283791670955126f * z * p);
    }
    return 0.5f * x * (1.0f + erff(x * 0.70710678118654752f));
}
__device__ __forceinline__ unsigned short f2b(float f) {
    unsigned u = __float_as_uint(f);
    u += 0x7fffu + ((u >> 16) & 1u);
    return (unsigned short)(u >> 16);
}
__device__ __forceinline__ float b2f(unsigned short h) {
    return __uint_as_float(((unsigned)h) << 16);
}

// ---------------- conv1d embedding: LDS-staged, weight-in-register ----------------
__global__ __launch_bounds__(256) void kembed(const float* __restrict__ x,
                                              const float* __restrict__ w,
                                              float* __restrict__ h) {
    __shared__ float xs[130][12];
    __shared__ float wsm[128][37];
    int b = blockIdx.x >> 5;
    int lt = blockIdx.x & 31;
    int l0 = lt * 128;
    int tid = threadIdx.x;
    for (int i = tid; i < 130 * 12; i += 256) {
        int r = i / 12, c = i - r * 12;
        int gl = (l0 - 1 + r + 4096) & 4095;
        xs[r][c] = x[((size_t)b * 4096 + gl) * 12 + c];
    }
    for (int i = tid; i < 128 * 36; i += 256) {
        int o = i / 36, j = i - o * 36;
        wsm[o][j] = w[i];
    }
    __syncthreads();
    int o = tid & 127, lh = tid >> 7;
    float wr[36];
#pragma unroll
    for (int j = 0; j < 36; j++) wr[j] = wsm[o][j];
    int base_r = lh * 64;
    float ring[4][12];
#pragma unroll
    for (int c = 0; c < 12; c++) { ring[0][c] = xs[base_r][c]; ring[1][c] = xs[base_r + 1][c]; }
    float* hp = h + ((size_t)b * 4096 + l0 + lh * 64) * 128 + o;
#pragma unroll 4
    for (int st = 0; st < 64; st++) {
        int s0 = st & 3, s1 = (st + 1) & 3, s2 = (st + 2) & 3;
#pragma unroll
        for (int c = 0; c < 12; c++) ring[s2][c] = xs[base_r + st + 2][c];
        float s = 0.f;
#pragma unroll
        for (int c = 0; c < 12; c++)
            s += wr[c * 3 + 0] * ring[s0][c] + wr[c * 3 + 1] * ring[s1][c] + wr[c * 3 + 2] * ring[s2][c];
        hp[(size_t)st * 128] = s;
    }
}

// ---------------- weight prep: bf16 pre-swizzled images ----------------
__global__ __launch_bounds__(256) void kprepw(const float* __restrict__ w1,
                                              const float* __restrict__ w2,
                                              const float* __restrict__ attn_w,
                                              unsigned short* __restrict__ w1img,
                                              unsigned short* __restrict__ w2img,
                                              unsigned short* __restrict__ qkh,
                                              unsigned short* __restrict__ qkl,
                                              unsigned short* __restrict__ voimg) {
    int t = blockIdx.x * 256 + threadIdx.x;
    if (t < 262144) {
        int layer = t >> 17; int rem = t & 131071;
        if (rem < 65536) {
            int R = rem >> 7, x = rem & 127;
            int g = x >> 3, j = x & 7;
            int srcc = ((g ^ (R & 7)) << 3) + j;
            w1img[(size_t)layer * 65536 + rem] = f2b(w1[(size_t)layer * 65536 + R * 128 + srcc]);
        } else {
            int r2 = rem - 65536;
            int c = r2 >> 13; int D = (r2 >> 6) & 127; int x = r2 & 63;
            int g = x >> 3, j = x & 7;
            int srcf = c * 64 + ((g ^ (D & 7)) << 3) + j;
            w2img[(size_t)layer * 65536 + r2] = f2b(w2[(size_t)layer * 65536 + D * 512 + srcf]);
        }
    } else if (t < 327680) {
        int t2 = t - 262144;
        int layer = t2 >> 15; int rem = t2 & 32767;
        int y = rem >> 14; int rem2 = rem & 16383;
        int r64 = rem2 >> 7; int x = rem2 & 127;
        int r = r64 & 63;
        int g = x >> 3, j = x & 7;
        int srcc = ((g ^ (r & 7)) << 3) + j;
        float v = attn_w[(size_t)layer * 65536 + y * 16384 + r64 * 128 + srcc];
        unsigned short hh = f2b(v);
        qkh[t2] = hh;
        qkl[t2] = f2b(v - b2f(hh));
    } else {
        int t3 = t - 327680;
        int layer = t3 >> 15; int rem = t3 & 32767;
        int mat = rem >> 14; int rem2 = rem & 16383;
        int r = rem2 >> 7; int x = rem2 & 127;
        int g = x >> 3, j = x & 7;
        int srcc = ((g ^ (r & 7)) << 3) + j;
        voimg[t3] = f2b(attn_w[(size_t)layer * 65536 + (2 + mat) * 16384 + r * 128 + srcc]);
    }
}

// ---- merged q+k projection: A staged ONCE, 4 roles looped; bf16 out CTb[b][256][4096] ----
__global__ __launch_bounds__(256, 2) void kgemm_qkb(const float* __restrict__ A,
                                                    const unsigned short* __restrict__ qkh,
                                                    const unsigned short* __restrict__ qkl,
                                                    const float* __restrict__ ab,
                                                    unsigned short* __restrict__ CTb) {
    __shared__ __align__(16) char smem[65536];
    short* Ah = (short*)smem;                 // [64][128]
    short* Al = (short*)(smem + 16384);
    short* Wh = (short*)(smem + 32768);
    short* Wl = (short*)(smem + 49152);
    float* Dsh = (float*)(smem + 32768);      // [64][68] overlays Wh/Wl
    int row0i = blockIdx.x * 64;
    int tid = threadIdx.x;
#pragma unroll
    for (int u = 0; u < 4; u++) {
        int task = tid + u * 256;
        int r = task >> 4, cg = task & 15;
        int dst = r * 128 + ((cg ^ (r & 7)) << 3);
        const float* src = A + ((size_t)(row0i + r)) * 128 + cg * 8;
        float4 xa = *(const float4*)src, ya = *(const float4*)(src + 4);
        float av[8] = {xa.x, xa.y, xa.z, xa.w, ya.x, ya.y, ya.z, ya.w};
        short8 hi, lo;
#pragma unroll
        for (int j = 0; j < 8; j++) {
            unsigned short hh = f2b(av[j]);
            hi[j] = (short)hh; lo[j] = (short)f2b(av[j] - b2f(hh));
        }
        *(short8*)(Ah + dst) = hi; *(short8*)(Al + dst) = lo;
    }
    int l = tid & 63; int w = tid >> 6; int wm = w >> 1, wn = w & 1;
    int b = row0i >> 12; int l0 = row0i & 4095;
    for (int role = 0; role < 4; role++) {
        int y = role >> 1, half = role & 1;
        const unsigned short* wh = qkh + y * 16384 + half * 8192;
        const unsigned short* wl = qkl + y * 16384 + half * 8192;
        const float* bias = ab + y * 128 + half * 64;
        __syncthreads();                      // A ready (role 0) / prev Dsh reads done
#pragma unroll
        for (int u = 0; u < 4; u++) {
            int task = tid + u * 256;
            int lin = (task >> 4) * 128 + (task & 15) * 8;
            *(short8*)(Wh + lin) = *(const short8*)(wh + lin);
            *(short8*)(Wl + lin) = *(const short8*)(wl + lin);
        }
        __syncthreads();
        f32x4 acc[2][2];
#pragma unroll
        for (int i = 0; i < 2; i++)
#pragma unroll
            for (int j = 0; j < 2; j++) acc[i][j] = (f32x4){0.f, 0.f, 0.f, 0.f};
#pragma unroll
        for (int ks = 0; ks < 4; ks++) {
            int cg = ks * 4 + (l >> 4);
            short8 ah[2], al2[2], bh[2], bl[2];
#pragma unroll
            for (int mi = 0; mi < 2; mi++) {
                int rm = wm * 32 + mi * 16 + (l & 15);
                int off = rm * 128 + ((cg ^ (rm & 7)) << 3);
                ah[mi] = *(short8*)(Ah + off); al2[mi] = *(short8*)(Al + off);
            }
#pragma unroll
            for (int ni = 0; ni < 2; ni++) {
                int rn = wn * 32 + ni * 16 + (l & 15);
                int off = rn * 128 + ((cg ^ (rn & 7)) << 3);
                bh[ni] = *(short8*)(Wh + off); bl[ni] = *(short8*)(Wl + off);
            }
#pragma unroll
            for (int mi = 0; mi < 2; mi++)
#pragma unroll
                for (int ni = 0; ni < 2; ni++) {
                    acc[mi][ni] = __builtin_amdgcn_mfma_f32_16x16x32_bf16(ah[mi], bh[ni], acc[mi][ni], 0, 0, 0);
                    acc[mi][ni] = __builtin_amdgcn_mfma_f32_16x16x32_bf16(ah[mi], bl[ni], acc[mi][ni], 0, 0, 0);
                    acc[mi][ni] = __builtin_amdgcn_mfma_f32_16x16x32_bf16(al2[mi], bh[ni], acc[mi][ni], 0, 0, 0);
                }
        }
        __syncthreads();                      // W reads done; Dsh region free
#pragma unroll
        for (int mi = 0; mi < 2; mi++)
#pragma unroll
            for (int ni = 0; ni < 2; ni++)
#pragma unroll
                for (int rr = 0; rr < 4; rr++) {
                    int m = wm * 32 + mi * 16 + (l >> 4) * 4 + rr;
                    int n = wn * 32 + ni * 16 + (l & 15);
                    Dsh[n * 68 + m] = acc[mi][ni][rr] + bias[n];
                }
        __syncthreads();
        int cb = y * 128 + half * 64;
#pragma unroll
        for (int u = 0; u < 4; u++) {
            int task = tid + u * 256;
            int c = task >> 4, m4 = (task & 15) * 4;
            float4 v = *(float4*)&Dsh[c * 68 + m4];
            short4v o;
            o[0] = (short)f2b(v.x); o[1] = (short)f2b(v.y);
            o[2] = (short)f2b(v.z); o[3] = (short)f2b(v.w);
            *(short4v*)&CTb[((size_t)(b * 256 + cb + c)) * 4096 + l0 + m4] = o;
        }
    }
}

// ---------------- MFMA bf16 GEMM (v-proj / fused agg+o-proj), W from image ----------------
template <int AT, int EPI>
__global__ __launch_bounds__(256, 2) void kgemm_mfma(const void* __restrict__ Ap,
                                                     const unsigned short* __restrict__ Wimg,
                                                     const float* __restrict__ bias,
                                                     const float* __restrict__ res,
                                                     const float* __restrict__ tcb,
                                                     const int* __restrict__ idxb,
                                                     void* __restrict__ outp) {
    __shared__ __align__(16) char smem[65536];
    short* As = (short*)smem;
    short* Ws = (short*)(smem + 32768);
    int tid = threadIdx.x;
    size_t row0;
    if (AT == 2) {
        int B = blockIdx.x;
        int cls = B & 7, j = B >> 3;
        int bq = cls + 8 * (j >> 5);
        int t = j & 31;
        row0 = ((size_t)bq * 32 + t) * 128;
    } else {
        row0 = (size_t)blockIdx.x * 128;
    }
#pragma unroll
    for (int u = 0; u < 8; u++) {
        int g = tid + u * 256;
        int r = g >> 4, cg = g & 15;
        int dsti = r * 128 + ((cg ^ (r & 7)) << 3);
        short8 v;
        if (AT == 0) {
            const float* src = (const float*)Ap + (row0 + r) * 128 + cg * 8;
            float4 x = *(const float4*)src, y = *(const float4*)(src + 4);
            v[0] = f2b(x.x); v[1] = f2b(x.y); v[2] = f2b(x.z); v[3] = f2b(x.w);
            v[4] = f2b(y.x); v[5] = f2b(y.y); v[6] = f2b(y.z); v[7] = f2b(y.w);
        } else {
            const unsigned short* Vb = (const unsigned short*)Ap;
            int b = (int)(row0 >> 12);
            int l0 = (int)(row0 & 4095);
            float accv[8];
#pragma unroll
            for (int j = 0; j < 8; j++) accv[j] = 0.f;
#pragma unroll
            for (int i = 0; i < 8; i++) {
                float wgt = tcb[b * 8 + i];
                int lr = (l0 + r + idxb[i]) & 4095;
                short8 vv = *(const short8*)(Vb + ((size_t)(b * 4096 + lr)) * 128 + cg * 8);
#pragma unroll
                for (int j = 0; j < 8; j++) accv[j] += wgt * b2f((unsigned short)vv[j]);
            }
#pragma unroll
            for (int j = 0; j < 8; j++) v[j] = (short)f2b(accv[j]);
        }
        *(short8*)(As + dsti) = v;
        int lin = r * 128 + cg * 8;
        *(short8*)(Ws + lin) = *(const short8*)(Wimg + lin);
    }
    __syncthreads();
    int l = tid & 63; int w = tid >> 6; int wm = w >> 1, wn = w & 1;
    f32x4 acc[4][4];
#pragma unroll
    for (int i = 0; i < 4; i++)
#pragma unroll
        for (int j = 0; j < 4; j++) acc[i][j] = (f32x4){0.f, 0.f, 0.f, 0.f};
#pragma unroll
    for (int ks = 0; ks < 4; ks++) {
        int cg = ks * 4 + (l >> 4);
        short8 af[4], bf[4];
#pragma unroll
        for (int mi = 0; mi < 4; mi++) {
            int rm = wm * 64 + mi * 16 + (l & 15);
            af[mi] = *(short8*)(As + rm * 128 + ((cg ^ (rm & 7)) << 3));
        }
#pragma unroll
        for (int ni = 0; ni < 4; ni++) {
            int rn = wn * 64 + ni * 16 + (l & 15);
            bf[ni] = *(short8*)(Ws + rn * 128 + ((cg ^ (rn & 7)) << 3));
        }
#pragma unroll
        for (int mi = 0; mi < 4; mi++)
#pragma unroll
            for (int ni = 0; ni < 4; ni++)
                acc[mi][ni] = __builtin_amdgcn_mfma_f32_16x16x32_bf16(af[mi], bf[ni], acc[mi][ni], 0, 0, 0);
    }
    __syncthreads();
    float* Dsh = (float*)smem;
#pragma unroll
    for (int mi = 0; mi < 4; mi++)
#pragma unroll
        for (int ni = 0; ni < 4; ni++)
#pragma unroll
            for (int rr = 0; rr < 4; rr++)
                Dsh[(wm * 64 + mi * 16 + (l >> 4) * 4 + rr) * 128 + wn * 64 + ni * 16 + (l & 15)] = acc[mi][ni][rr];
    __syncthreads();
#pragma unroll
    for (int u = 0; u < 8; u++) {
        int g = tid + u * 256;
        int r = g >> 4, c8 = (g & 15) * 8;
        float vv[8];
#pragma unroll
        for (int j = 0; j < 8; j++) vv[j] = Dsh[r * 128 + c8 + j] + bias[c8 + j];
        if (EPI == 1) {
            const float* rp = res + (row0 + r) * 128 + c8;
#pragma unroll
            for (int j = 0; j < 8; j++) vv[j] += rp[j];
            float* op = (float*)outp + (row0 + r) * 128 + c8;
            *(float4*)op = make_float4(vv[0], vv[1], vv[2], vv[3]);
            *(float4*)(op + 4) = make_float4(vv[4], vv[5], vv[6], vv[7]);
        } else {
            short8 ov;
#pragma unroll
            for (int j = 0; j < 8; j++) ov[j] = (short)f2b(vv[j]);
            *(short8*)((short*)outp + (row0 + r) * 128 + c8) = ov;
        }
    }
}

// ---------------- fused MFMA FFN: 512 threads (8 waves 2x4), 80 KB LDS, fb=64 chunks ----------------
__global__ __launch_bounds__(512, 4) void kffn_mfma(const float* __restrict__ xs,
                                                    const unsigned short* __restrict__ w1img,
                                                    const unsigned short* __restrict__ w2img,
                                                    float* __restrict__ outp) {
    __shared__ __align__(16) char smem[81920];
    short* xsl = (short*)smem;               // [128][128]  32K
    short* w1t = (short*)(smem + 32768);     // [64][128]   16K
    short* tt  = (short*)(smem + 49152);     // [128][64]   16K
    short* w2t = (short*)(smem + 65536);     // [128][64]   16K
    int tid = threadIdx.x;
    size_t row0 = (size_t)blockIdx.x * 128;
#pragma unroll
    for (int u = 0; u < 4; u++) {
        int g = tid + u * 512;
        int r = g >> 4, cg = g & 15;
        const float* src = xs + (row0 + r) * 128 + cg * 8;
        float4 x = *(const float4*)src, y = *(const float4*)(src + 4);
        short8 v;
        v[0] = f2b(x.x); v[1] = f2b(x.y); v[2] = f2b(x.z); v[3] = f2b(x.w);
        v[4] = f2b(y.x); v[5] = f2b(y.y); v[6] = f2b(y.z); v[7] = f2b(y.w);
        *(short8*)(xsl + r * 128 + ((cg ^ (r & 7)) << 3)) = v;
    }
    int l = tid & 63; int w = tid >> 6;      // 8 waves
    int wm = w >> 2, wn = w & 3;             // 2 x 4
    f32x4 acc2[4][2];
#pragma unroll
    for (int i = 0; i < 4; i++)
#pragma unroll
        for (int j = 0; j < 2; j++) acc2[i][j] = (f32x4){0.f, 0.f, 0.f, 0.f};
    for (int fb = 0; fb < 8; fb++) {
        __syncthreads();                       // BAR_A (first iter: xsl ready)
#pragma unroll
        for (int u = 0; u < 2; u++) {
            int task = tid + u * 512;
            int r = task >> 4, cg = task & 15;
            *(short8*)(w1t + r * 128 + cg * 8) =
                *(const short8*)(w1img + ((size_t)(fb * 64 + r)) * 128 + cg * 8);
            int r2 = task >> 3, cg2 = task & 7;
            *(short8*)(w2t + r2 * 64 + cg2 * 8) =
                *(const short8*)(w2img + ((size_t)(fb * 128 + r2)) * 64 + cg2 * 8);
        }
        __syncthreads();                       // BAR_B
        f32x4 a1[4];
#pragma unroll
        for (int i = 0; i < 4; i++) a1[i] = (f32x4){0.f, 0.f, 0.f, 0.f};
#pragma unroll
        for (int ks = 0; ks < 4; ks++) {
            int cg = ks * 4 + (l >> 4);
            short8 af[4], bf;
#pragma unroll
            for (int mi = 0; mi < 4; mi++) {
                int rm = wm * 64 + mi * 16 + (l & 15);
                af[mi] = *(short8*)(xsl + rm * 128 + ((cg ^ (rm & 7)) << 3));
            }
            {
                int rn = wn * 16 + (l & 15);
                bf = *(short8*)(w1t + rn * 128 + ((cg ^ (rn & 7)) << 3));
            }
#pragma unroll
            for (int mi = 0; mi < 4; mi++)
                a1[mi] = __builtin_amdgcn_mfma_f32_16x16x32_bf16(af[mi], bf, a1[mi], 0, 0, 0);
        }
#pragma unroll
        for (int mi = 0; mi < 4; mi++)
#pragma unroll
            for (int rr = 0; rr < 4; rr++) {
                int m = wm * 64 + mi * 16 + (l >> 4) * 4 + rr;
                int f = wn * 16 + (l & 15);
                tt[m * 64 + (((f >> 3) ^ (m & 7)) << 3) + (f & 7)] = (short)f2b(gelu_fast(a1[mi][rr]));
            }
        __syncthreads();                       // BAR_C
#pragma unroll
        for (int ks = 0; ks < 2; ks++) {
            int cg = ks * 4 + (l >> 4);
            short8 af[4], bf[2];
#pragma unroll
            for (int mi = 0; mi < 4; mi++) {
                int rm = wm * 64 + mi * 16 + (l & 15);
                af[mi] = *(short8*)(tt + rm * 64 + ((cg ^ (rm & 7)) << 3));
            }
#pragma unroll
            for (int ni = 0; ni < 2; ni++) {
                int rn = wn * 32 + ni * 16 + (l & 15);
                bf[ni] = *(short8*)(w2t + rn * 64 + ((cg ^ (rn & 7)) << 3));
            }
#pragma unroll
            for (int mi = 0; mi < 4; mi++)
#pragma unroll
                for (int ni = 0; ni < 2; ni++)
                    acc2[mi][ni] = __builtin_amdgcn_mfma_f32_16x16x32_bf16(af[mi], bf[ni], acc2[mi][ni], 0, 0, 0);
        }
    }
    __syncthreads();
    float* Dsh = (float*)smem;                 // [128][128] f32 over first 64KB
#pragma unroll
    for (int mi = 0; mi < 4; mi++)
#pragma unroll
        for (int ni = 0; ni < 2; ni++)
#pragma unroll
            for (int rr = 0; rr < 4; rr++)
                Dsh[(wm * 64 + mi * 16 + (l >> 4) * 4 + rr) * 128 + wn * 32 + ni * 16 + (l & 15)] = acc2[mi][ni][rr];
    __syncthreads();
#pragma unroll
    for (int u = 0; u < 4; u++) {
        int g = tid + u * 512;
        int r = g >> 4, c8 = (g & 15) * 8;
        const float* rp = xs + (row0 + r) * 128 + c8;
        float* op = outp + (row0 + r) * 128 + c8;
        float4 o0, o1;
        o0.x = Dsh[r * 128 + c8 + 0] + rp[0]; o0.y = Dsh[r * 128 + c8 + 1] + rp[1];
        o0.z = Dsh[r * 128 + c8 + 2] + rp[2]; o0.w = Dsh[r * 128 + c8 + 3] + rp[3];
        o1.x = Dsh[r * 128 + c8 + 4] + rp[4]; o1.y = Dsh[r * 128 + c8 + 5] + rp[5];
        o1.z = Dsh[r * 128 + c8 + 6] + rp[6]; o1.w = Dsh[r * 128 + c8 + 7] + rp[7];
        *(float4*)op = o0; *(float4*)(op + 4) = o1;
    }
}

// ---------------- radix-4 Stockham FFT-4096 ----------------
#define FIDX(a) ((a) + ((a) >> 4))

__device__ __forceinline__ float2 twget(const float2* __restrict__ tw, int a, float sgn) {
    float2 T = tw[a & 1023];
    int hi = (a >> 10) & 3;
    float cs = (hi & 1) ? ((hi & 2) ? T.y : -T.y) : ((hi & 2) ? -T.x : T.x);
    float sn = (hi & 1) ? ((hi & 2) ? -T.x : T.x) : ((hi & 2) ? -T.y : T.y);
    return make_float2(cs, sn * sgn);
}

#define BFLY(cur, nxt) do { \
    float2 a0 = cur[FIDX(tid)]; \
    float2 a1 = cur[FIDX(tid + 1024)]; \
    float2 a2 = cur[FIDX(tid + 2048)]; \
    float2 a3 = cur[FIDX(tid + 3072)]; \
    float t0x = a0.x + a2.x, t0y = a0.y + a2.y; \
    float t1x = a0.x - a2.x, t1y = a0.y - a2.y; \
    float t2x = a1.x + a3.x, t2y = a1.y + a3.y; \
    float t3x = a1.x - a3.x, t3y = a1.y - a3.y; \
    float it3x = -sgn * t3y, it3y = sgn * t3x; \
    float2 A0 = make_float2(t0x + t2x, t0y + t2y); \
    float2 A1 = make_float2(t1x + it3x, t1y + it3y); \
    float2 A2 = make_float2(t0x - t2x, t0y - t2y); \
    float2 A3 = make_float2(t1x - it3x, t1y - it3y); \
    nxt[FIDX(ob)] = A0; \
    nxt[FIDX(ob + s)] = make_float2(A1.x * w1.x - A1.y * w1.y, A1.x * w1.y + A1.y * w1.x); \
    nxt[FIDX(ob + 2 * s)] = make_float2(A2.x * w2.x - A2.y * w2.y, A2.x * w2.y + A2.y * w2.x); \
    nxt[FIDX(ob + 3 * s)] = make_float2(A3.x * w3.x - A3.y * w3.y, A3.x * w3.y + A3.y * w3.x); \
} while (0)

__device__ void fft4096_r4(float2* __restrict__ b0, float2* __restrict__ b1,
                           const float2* __restrict__ tw, float sgn, int tid) {
    float2* cur = b0; float2* nxt = b1;
#pragma unroll
    for (int t = 0; t < 6; t++) {
        int s = 1 << (t << 1);
        int q = tid & (s - 1);
        int ps = tid - q;
        float2 w1 = twget(tw, ps, sgn);
        float2 w2 = twget(tw, ps * 2, sgn);
        float2 w3 = twget(tw, ps * 3, sgn);
        int ob = q + (ps << 2);
        BFLY(cur, nxt);
        __syncthreads();
        float2* tp = cur; cur = nxt; nxt = tp;
    }
}

// two independent FFT chains per barrier: A/B and C/D ping-pong, shared twiddles
__device__ void fft4096_r4x2(float2* __restrict__ bA, float2* __restrict__ bB,
                             float2* __restrict__ bC, float2* __restrict__ bD,
                             const float2* __restrict__ tw, float sgn, int tid) {
    float2* curA = bA; float2* nxtA = bB;
    float2* curC = bC; float2* nxtC = bD;
#pragma unroll
    for (int t = 0; t < 6; t++) {
        int s = 1 << (t << 1);
        int q = tid & (s - 1);
        int ps = tid - q;
        float2 w1 = twget(tw, ps, sgn);
        float2 w2 = twget(tw, ps * 2, sgn);
        float2 w3 = twget(tw, ps * 3, sgn);
        int ob = q + (ps << 2);
        BFLY(curA, nxtA);
        BFLY(curC, nxtC);
        __syncthreads();
        float2* tp = curA; curA = nxtA; nxtA = tp;
        tp = curC; curC = nxtC; nxtC = tp;
    }
}

// 4 channel-PAIRS per block over bf16 CTb[b][256][4096]; grid 512 = (b x 16 groups)
__global__ __launch_bounds__(1024) void kfft_fwd(const unsigned short* __restrict__ qkT,
                                                 float* __restrict__ Pws) {
    __shared__ float2 bufA[4352];
    __shared__ float2 bufB[4352];
    __shared__ float2 bufC[4352];
    __shared__ float2 bufD[4352];
    __shared__ float2 tw[1024];
    int tid = threadIdx.x;
    {
        float sn, cs;
        sincosf(1.5339807878856412e-3f * (float)tid, &sn, &cs);
        tw[tid] = make_float2(cs, sn);
    }
    int b = blockIdx.x >> 4;
    int g = blockIdx.x & 15;
    float2 pacc[4];
#pragma unroll
    for (int j = 0; j < 4; j++) pacc[j] = make_float2(0.f, 0.f);
    for (int cp = 0; cp < 4; cp++) {
        int c0 = g * 8 + cp * 2;
        const unsigned short* q0 = qkT + ((size_t)(b * 256 + c0)) * 4096;
        const unsigned short* k0 = qkT + ((size_t)(b * 256 + 128 + c0)) * 4096;
        __syncthreads();                      // prior unpack reads done
        int i0 = tid * 4;
        {
            short4v qv = *(const short4v*)(q0 + i0);
            short4v kv = *(const short4v*)(k0 + i0);
            bufA[FIDX(i0)]     = make_float2(b2f((unsigned short)qv[0]), b2f((unsigned short)kv[0]));
            bufA[FIDX(i0 + 1)] = make_float2(b2f((unsigned short)qv[1]), b2f((unsigned short)kv[1]));
            bufA[FIDX(i0 + 2)] = make_float2(b2f((unsigned short)qv[2]), b2f((unsigned short)kv[2]));
            bufA[FIDX(i0 + 3)] = make_float2(b2f((unsigned short)qv[3]), b2f((unsigned short)kv[3]));
        }
        {
            short4v qv = *(const short4v*)(q0 + 4096 + i0);
            short4v kv = *(const short4v*)(k0 + 4096 + i0);
            bufC[FIDX(i0)]     = make_float2(b2f((unsigned short)qv[0]), b2f((unsigned short)kv[0]));
            bufC[FIDX(i0 + 1)] = make_float2(b2f((unsigned short)qv[1]), b2f((unsigned short)kv[1]));
            bufC[FIDX(i0 + 2)] = make_float2(b2f((unsigned short)qv[2]), b2f((unsigned short)kv[2]));
            bufC[FIDX(i0 + 3)] = make_float2(b2f((unsigned short)qv[3]), b2f((unsigned short)kv[3]));
        }
        __syncthreads();
        fft4096_r4x2(bufA, bufB, bufC, bufD, tw, -1.f, tid);
        // unpack c0 then c0+1: same accumulation order as the serial version
#pragma unroll
        for (int j = 0; j < 4; j++) {
            int f = tid + j * 1024;
            float2 Zf = bufA[FIDX(f)];
            float2 Zm = bufA[FIDX((4096 - f) & 4095)];
            float Qre = 0.5f * (Zf.x + Zm.x), Qim = 0.5f * (Zf.y - Zm.y);
            float Kre = 0.5f * (Zf.y + Zm.y), Kim = -0.5f * (Zf.x - Zm.x);
            pacc[j].x += Qre * Kre + Qim * Kim;
            pacc[j].y += Qim * Kre - Qre * Kim;
        }
#pragma unroll
        for (int j = 0; j < 4; j++) {
            int f = tid + j * 1024;
            float2 Zf = bufC[FIDX(f)];
            float2 Zm = bufC[FIDX((4096 - f) & 4095)];
            float Qre = 0.5f * (Zf.x + Zm.x), Qim = 0.5f * (Zf.y - Zm.y);
            float Kre = 0.5f * (Zf.y + Zm.y), Kim = -0.5f * (Zf.x - Zm.x);
            pacc[j].x += Qre * Kre + Qim * Kim;
            pacc[j].y += Qim * Kre - Qre * Kim;
        }
    }
    float2* P = (float2*)Pws + (size_t)(b * 16 + g) * 4096;
#pragma unroll
    for (int j = 0; j < 4; j++) { int f = tid + j * 1024; P[f] = pacc[j]; }
}

// ---------------- presum the 16 P-slices at full BW (gg ascending, bit-identical) ----------------
__global__ __launch_bounds__(256) void kpsum(const float* __restrict__ Pws,
                                             float* __restrict__ Pr) {
    int t = blockIdx.x * 256 + threadIdx.x;      // 131072 float2 elements
    int b = t >> 12, i = t & 4095;
    const float2* P = (const float2*)Pws;
    float2 s = make_float2(0.f, 0.f);
#pragma unroll
    for (int gg = 0; gg < 16; gg++) {
        float2 v = P[((size_t)(b * 16 + gg)) * 4096 + i];
        s.x += v.x; s.y += v.y;
    }
    ((float2*)Pr)[(size_t)b * 4096 + i] = s;
}

__global__ __launch_bounds__(1024) void kfft_inv(const float* __restrict__ Prs,
                                                 float* __restrict__ meanv) {
    __shared__ float2 bufA[4352];
    __shared__ float2 bufB[4352];
    __shared__ float2 tw[1024];
    int tid = threadIdx.x;
    {
        float sn, cs;
        sincosf(1.5339807878856412e-3f * (float)tid, &sn, &cs);
        tw[tid] = make_float2(cs, sn);
    }
    int b = blockIdx.x;
    const float2* P = (const float2*)Prs + (size_t)b * 4096;
#pragma unroll
    for (int j = 0; j < 4; j++) {
        int i = tid + j * 1024;
        bufA[FIDX(i)] = P[i];
    }
    __syncthreads();
    fft4096_r4(bufA, bufB, tw, 1.f, tid);
    const float scale = 1.0f / (4096.0f * 128.0f);
#pragma unroll
    for (int j = 0; j < 4; j++) {
        int i = tid + j * 1024;
        meanv[b * 4096 + i] = bufA[FIDX(i)].x * scale;
    }
}

// ---------------- parallel column sum over batches (b ascending, bit-identical) ----------------
__global__ __launch_bounds__(256) void kcolsum(const float* __restrict__ meanv,
                                               float* __restrict__ cmg) {
    int c = blockIdx.x * 256 + threadIdx.x;
    float s = 0.f;
    for (int b = 0; b < 32; b++) s += meanv[b * 4096 + c];
    cmg[c] = s;
}

// ---------------- top-8 on presummed vector + per-batch softmax ----------------
__global__ __launch_bounds__(256) void ktopk2(const float* __restrict__ cmg,
                                              const float* __restrict__ meanv,
                                              int* __restrict__ idxout,
                                              float* __restrict__ tc) {
    __shared__ float cm[4096];
    __shared__ float rv[256];
    __shared__ int ri[256];
    __shared__ int sidx[8];
    for (int c = threadIdx.x; c < 4096; c += 256) cm[c] = cmg[c];
    __syncthreads();
    for (int it = 0; it < 8; it++) {
        float bv = -1e30f; int bi = 0;
        for (int c = threadIdx.x; c < 4096; c += 256) {
            float v = cm[c];
            if (v > bv) { bv = v; bi = c; }
        }
        rv[threadIdx.x] = bv; ri[threadIdx.x] = bi;
        __syncthreads();
        for (int off = 128; off > 0; off >>= 1) {
            if (threadIdx.x < off) {
                float v2 = rv[threadIdx.x + off]; int i2 = ri[threadIdx.x + off];
                if (v2 > rv[threadIdx.x] || (v2 == rv[threadIdx.x] && i2 < ri[threadIdx.x])) {
                    rv[threadIdx.x] = v2; ri[threadIdx.x] = i2;
                }
            }
            __syncthreads();
        }
        if (threadIdx.x == 0) { sidx[it] = ri[0]; idxout[it] = ri[0]; cm[ri[0]] = -1e30f; }
        __syncthreads();
    }
    if (threadIdx.x < 32) {
        int b = threadIdx.x;
        float w[8]; float mx = -1e30f;
#pragma unroll
        for (int i = 0; i < 8; i++) { w[i] = meanv[b * 4096 + sidx[i]]; mx = fmaxf(mx, w[i]); }
        float s = 0.f;
#pragma unroll
        for (int i = 0; i < 8; i++) { w[i] = expf(w[i] - mx); s += w[i]; }
#pragma unroll
        for (int i = 0; i < 8; i++) tc[b * 8 + i] = w[i] / s;
    }
}

// ---------------- series decomp: float4 rolling windows ----------------
__global__ __launch_bounds__(256) void kdecomp(const float* __restrict__ in,
                                               float* __restrict__ outp) {
    int b = blockIdx.x >> 4; int lc = blockIdx.x & 15;
    int dg = threadIdx.x & 31; int ls = threadIdx.x >> 5;
    int l0 = lc * 256 + ls * 32;
    const float* base = in + (size_t)b * 524288 + dg * 4;
    float* ob = outp + (size_t)b * 524288 + dg * 4;
    float sx = 0.f, sy = 0.f, sz = 0.f, sw = 0.f;
#pragma unroll
    for (int j = -12; j <= 12; j++) {
        int lj = l0 + j;
        lj = lj < 0 ? 0 : (lj > 4095 ? 4095 : lj);
        float4 v = *(const float4*)(base + (size_t)lj * 128);
        sx += v.x; sy += v.y; sz += v.z; sw += v.w;
    }
    for (int st = 0; st < 32; st++) {
        int l = l0 + st;
        float4 c = *(const float4*)(base + (size_t)l * 128);
        float4 o = make_float4(c.x - sx * (1.0f / 25.0f), c.y - sy * (1.0f / 25.0f),
                               c.z - sz * (1.0f / 25.0f), c.w - sw * (1.0f / 25.0f));
        *(float4*)(ob + (size_t)l * 128) = o;
        int ln = l + 13 > 4095 ? 4095 : l + 13;
        int lo2 = l - 12 < 0 ? 0 : l - 12;
        float4 vn = *(const float4*)(base + (size_t)ln * 128);
        float4 vo = *(const float4*)(base + (size_t)lo2 * 128);
        sx += vn.x - vo.x; sy += vn.y - vo.y; sz += vn.z - vo.z; sw += vn.w - vo.w;
    }
}

// ---------------- fused LayerNorm + column partial sums ----------------
__global__ __launch_bounds__(256) void kln_part1(float* __restrict__ h,
                                                 const float* __restrict__ g,
                                                 const float* __restrict__ bb,
                                                 float* __restrict__ part) {
    __shared__ float sh[4][128];
    int b = blockIdx.x >> 5;
    int sl = blockIdx.x & 31;
    int w = threadIdx.x >> 6;
    int lane = threadIdx.x & 63;
    float2 gv = *(const float2*)(g + lane * 2);
    float2 bv = *(const float2*)(bb + lane * 2);
    size_t r0 = (size_t)b * 4096 + sl * 128 + w * 32;
    float c0 = 0.f, c1 = 0.f;
    for (int i = 0; i < 32; i++) {
        float* p = h + (r0 + i) * 128 + lane * 2;
        float2 v = *(float2*)p;
        float s = v.x + v.y, s2 = v.x * v.x + v.y * v.y;
#pragma unroll
        for (int off = 32; off; off >>= 1) { s += __shfl_down(s, off); s2 += __shfl_down(s2, off); }
        s = __shfl(s, 0); s2 = __shfl(s2, 0);
        float mu = s * (1.f / 128.f);
        float var = s2 * (1.f / 128.f) - mu * mu;
        float inv = rsqrtf(var + 1e-5f);
        float o0 = (v.x - mu) * inv * gv.x + bv.x;
        float o1 = (v.y - mu) * inv * gv.y + bv.y;
        *(float2*)p = make_float2(o0, o1);
        c0 += o0; c1 += o1;
    }
    sh[w][lane * 2] = c0; sh[w][lane * 2 + 1] = c1;
    __syncthreads();
    if (threadIdx.x < 128) {
        int d = threadIdx.x;
        part[(size_t)(b * 32 + sl) * 128 + d] = sh[0][d] + sh[1][d] + sh[2][d] + sh[3][d];
    }
}

__global__ __launch_bounds__(128) void kpart2(const float* __restrict__ part,
                                              float* __restrict__ outm, int nq) {
    int b = blockIdx.x; int d = threadIdx.x;
    float s = 0.f;
    for (int q = 0; q < nq; q++) s += part[(size_t)(b * nq + q) * 128 + d];
    outm[b * 128 + d] = s * (1.f / 4096.f);
}

// ---------------- gelu(h - colmean) partials: 2048 blocks, float4, gelu_fast ----------------
__global__ __launch_bounds__(256) void kgpart1(const float* __restrict__ h,
                                               const float* __restrict__ msum,
                                               float* __restrict__ part) {
    __shared__ float sh[8][128];
    int b = blockIdx.x >> 6, sl = blockIdx.x & 63;
    int d4 = threadIdx.x & 31, p = threadIdx.x >> 5;
    const float* base = h + ((size_t)b * 4096 + sl * 64) * 128 + d4 * 4;
    float4 m = *(const float4*)(msum + b * 128 + d4 * 4);
    float ax = 0.f, ay = 0.f, az = 0.f, aw = 0.f;
    for (int l = p; l < 64; l += 8) {
        float4 v = *(const float4*)(base + (size_t)l * 128);
        ax += gelu_fast(v.x - m.x); ay += gelu_fast(v.y - m.y);
        az += gelu_fast(v.z - m.z); aw += gelu_fast(v.w - m.w);
    }
    sh[p][d4 * 4 + 0] = ax; sh[p][d4 * 4 + 1] = ay;
    sh[p][d4 * 4 + 2] = az; sh[p][d4 * 4 + 3] = aw;
    __syncthreads();
    if (threadIdx.x < 128) {
        int d = threadIdx.x;
        float s = 0.f;
#pragma unroll
        for (int q = 0; q < 8; q++) s += sh[q][d];
        part[(size_t)(b * 64 + sl) * 128 + d] = s;
    }
}

__global__ __launch_bounds__(256) void khead(const float* __restrict__ gmean,
                                             const float* __restrict__ fc1w,
                                             const float* __restrict__ fc1b,
                                             const float* __restrict__ fc2w,
                                             const float* __restrict__ fc2b,
                                             float* __restrict__ outp) {
    __shared__ float h0[32][128];
    __shared__ float h1[32][128];
    int tid = threadIdx.x;
#pragma unroll
    for (int i = 0; i < 16; i++) {
        int e = tid + i * 256;
        h0[e >> 7][e & 127] = gmean[e];
    }
    __syncthreads();
#pragma unroll
    for (int i = 0; i < 16; i++) {
        int e = tid + i * 256; int b = e >> 7, j = e & 127;
        float s = fc1b[j];
        for (int d = 0; d < 128; d++) s += h0[b][d] * fc1w[j * 128 + d];
        h1[b][j] = fmaxf(s, 0.f);
    }
    __syncthreads();
    if (tid < 160) {
        int b = tid / 5, c2 = tid % 5;
        float s = fc2b[c2];
        for (int j = 0; j < 128; j++) s += h1[b][j] * fc2w[c2 * 128 + j];
        outp[b * 5 + c2] = s;
    }
}

extern "C" void kernel_launch(void* const* d_in, const int* in_sizes, int n_in,
                              void* d_out, int out_size, void* d_ws, size_t ws_size,
                              hipStream_t stream) {
    const float* x_enc  = (const float*)d_in[0];
    const float* emb_w  = (const float*)d_in[1];
    const float* attn_w = (const float*)d_in[2];
    const float* attn_b = (const float*)d_in[3];
    const float* ffn_w1 = (const float*)d_in[4];
    const float* ffn_w2 = (const float*)d_in[5];
    const float* norm_g = (const float*)d_in[6];
    const float* norm_b = (const float*)d_in[7];
    const float* fc1_w  = (const float*)d_in[8];
    const float* fc1_b  = (const float*)d_in[9];
    const float* fc2_w  = (const float*)d_in[10];
    const float* fc2_b  = (const float*)d_in[11];
    float* outp = (float*)d_out;

    float* W = (float*)d_ws;
    const size_t RD = (size_t)BATCH * L_SEQ * DM;       // 16,777,216
    float* buf0  = W;
    float* buf1  = W + RD;
    float* Pws   = W + 2 * RD;                          // 4,194,304 f
    float* meanv = Pws + (size_t)4194304;               // 131,072 (reused as LN partials in tail)
    float* tcb   = meanv + (size_t)131072;              // 256
    int*   idxb  = (int*)(tcb + 256);                   // 64 slots
    float* part  = tcb + 256 + 64;                      // 32,768
    float* msum  = part + 32768;                        // 4,096
    float* gsum  = msum + 4096;                         // 4,096
    unsigned short* w1img = (unsigned short*)(gsum + 4096);   // 2*65536
    unsigned short* w2img = w1img + (size_t)2 * 65536;        // 2*65536
    unsigned short* qkh   = w2img + (size_t)2 * 65536;        // 65536
    unsigned short* qkl   = qkh + (size_t)65536;              // 65536
    unsigned short* voimg = qkl + (size_t)65536;              // 65536
    float* cmg   = (float*)(voimg + (size_t)65536);           // 4,096
    float* Pr    = cmg + 4096;                                // 262,144 (presummed P / gelu partials)

    kembed<<<1024, 256, 0, stream>>>(x_enc, emb_w, buf0);
    kprepw<<<1536, 256, 0, stream>>>(ffn_w1, ffn_w2, attn_w, w1img, w2img, qkh, qkl, voimg);

    float* H = buf0;
    float* S = buf1;
    for (int l = 0; l < 2; l++) {
        const float* ab = attn_b + (size_t)l * 4 * 128;
        unsigned short* CTb = (unsigned short*)S;       // [b][256][4096] bf16
        kgemm_qkb<<<2048, 256, 0, stream>>>(H, qkh + (size_t)l * 32768,
                                            qkl + (size_t)l * 32768, ab, CTb);
        kfft_fwd<<<512, 1024, 0, stream>>>(CTb, Pws);
        kpsum<<<512, 256, 0, stream>>>(Pws, Pr);
        kfft_inv<<<32, 1024, 0, stream>>>(Pr, meanv);
        kcolsum<<<16, 256, 0, stream>>>(meanv, cmg);
        ktopk2<<<1, 256, 0, stream>>>(cmg, meanv, idxb, tcb);
        unsigned short* Vb = (unsigned short*)S;        // overwrites CTb (dead after fft_fwd)
        kgemm_mfma<0, 0><<<1024, 256, 0, stream>>>(H, voimg + (size_t)l * 32768, ab + 256,
                                                   nullptr, nullptr, nullptr, Vb);
        kgemm_mfma<2, 1><<<1024, 256, 0, stream>>>(Vb, voimg + (size_t)l * 32768 + 16384, ab + 384,
                                                   H, tcb, idxb, H);
        kdecomp<<<512, 256, 0, stream>>>(H, S);
        kffn_mfma<<<1024, 512, 0, stream>>>(S, w1img + (size_t)l * 65536,
                                            w2img + (size_t)l * 65536, H);
        kdecomp<<<512, 256, 0, stream>>>(H, S);
        float* t = H; H = S; S = t;
    }

    kln_part1<<<1024, 256, 0, stream>>>(H, norm_g, norm_b, meanv);
    kpart2<<<32, 128, 0, stream>>>(meanv, msum, 32);
    kgpart1<<<2048, 256, 0, stream>>>(H, msum, Pr);
    kpart2<<<32, 128, 0, stream>>>(Pr, gsum, 64);
    khead<<<1, 256, 0, stream>>>(gsum, fc1_w, fc1_b, fc2_w, fc2_b, outp);
}